// Round 1
// baseline (25707.791 us; speedup 1.0000x reference)
//
#include <hip/hip_runtime.h>
#include <math.h>

// DCRNN on MI355X — round 1: correct fp32 baseline.
// Layouts: node-major. h buffer is (NB=16384 rows) x (LDH=640 cols), holding the
// 5 graph-conv feature blocks at col k*Dp (Dp = padded per-block width).
// spmm: out[m,(b,d)] = sum_n S[m,n] * h[n,(b,d)] — strided f32 GEMM, 64x64 tiles.
// Pad columns carry garbage but are multiplied by zeroed Wp rows -> harmless.

#define NN 1024
#define BB 16
#define TT 12
#define HH 64
#define NB (NN*BB)      // 16384
#define LDH 640         // h row length (floats)
#define RSTR (BB*LDH)   // node-dim row stride in h = 10240

__global__ __launch_bounds__(256) void k_zero(float* p, int n) {
  int i = blockIdx.x*256 + threadIdx.x;
  if (i < n) p[i] = 0.f;
}

// inputs (B,T,N,2) -> xin (T, N, B, 2)
__global__ __launch_bounds__(256) void k_transpose_in(const float* __restrict__ in,
                                                      float* __restrict__ xt) {
  int idx = blockIdx.x*256 + threadIdx.x;
  if (idx >= BB*TT*NN*2) return;
  int i = idx & 1;
  int n = (idx >> 1) & (NN-1);
  int bt = idx >> 11;           // = b*TT + t
  int t = bt % TT, b = bt / TT;
  xt[(size_t)t*(NB*2) + (size_t)(n*BB + b)*2 + i] = in[idx];
}

// W (5*Dreal, dout) -> Wp (Kp, dout) with block width padded Dreal->Dp, zero pad rows
__global__ __launch_bounds__(256) void k_padW(const float* __restrict__ W, float* __restrict__ Wp,
                                              int Dreal, int Dp, int Kp, int dout) {
  int idx = blockIdx.x*256 + threadIdx.x;
  if (idx >= Kp*dout) return;
  int o = idx % dout, jp = idx / dout;
  int k = jp / Dp, d = jp - k*Dp;
  float v = 0.f;
  if (k < 5 && d < Dreal) v = W[(size_t)(k*Dreal + d)*dout + o];
  Wp[idx] = v;
}

// mode 0: h[:,0:indim]=inp, h[:,indim:D]=state.  mode 1: h[:,indim:D]=r*state only.
__global__ __launch_bounds__(256) void k_assemble(const float* __restrict__ inp, int indim,
                                                  const float* __restrict__ st,
                                                  const float* __restrict__ ru,
                                                  float* __restrict__ h, int mode) {
  int D = indim + HH;
  int idx = blockIdx.x*256 + threadIdx.x;
  if (idx >= NB*D) return;
  int j = idx % D, nb = idx / D;
  float v;
  if (j < indim) {
    if (mode) return;
    v = inp[(size_t)nb*indim + j];
  } else {
    int hh = j - indim;
    v = st[(size_t)nb*HH + hh];
    if (mode) v *= ru[(size_t)nb*128 + hh];   // r = ru[:, 0:64]
  }
  h[(size_t)nb*LDH + j] = v;
}

// Batched over blockIdx.z: z selects support S_z and (src,dst) column-block offsets.
// Computes h[:, dst_block] = S_z @ h[:, src_block]  (per-b columns, Dp wide each).
__global__ __launch_bounds__(256) void k_spmm(const float* __restrict__ sup,
                                              float* __restrict__ hbuf,
                                              int src0, int src1, int dst0, int dst1, int Dp) {
  __shared__ float sA[32][68];   // sA[k][m] (S tile transposed)
  __shared__ float sB[32][68];   // sB[k][c]
  const float* S = sup + (size_t)blockIdx.z * NN * NN;
  int srcoff = blockIdx.z ? src1 : src0;
  int dstoff = blockIdx.z ? dst1 : dst0;
  int m0 = blockIdx.x << 6;
  int c0 = blockIdx.y << 6;
  int tid = threadIdx.x;
  int ty = tid >> 4, tx = tid & 15;
  int sk = tid & 31, sm = tid >> 5;   // S stage: k=sk, rows sm+8i
  int xc = tid & 63, xk4 = tid >> 6;  // X stage: col xc, rows xk4+4j
  int cg = c0 + xc;
  int bb = cg / Dp, dd = cg - bb*Dp;
  int colsrc = bb*LDH + srcoff + dd;
  float acc[4][4] = {{0.f,0.f,0.f,0.f},{0.f,0.f,0.f,0.f},{0.f,0.f,0.f,0.f},{0.f,0.f,0.f,0.f}};
  for (int k0 = 0; k0 < NN; k0 += 32) {
    #pragma unroll
    for (int i = 0; i < 8; i++)
      sA[sk][sm + i*8] = S[(size_t)(m0 + sm + i*8)*NN + k0 + sk];
    #pragma unroll
    for (int j = 0; j < 8; j++) {
      int k = xk4 + j*4;
      sB[k][xc] = hbuf[(size_t)(k0 + k)*RSTR + colsrc];
    }
    __syncthreads();
    #pragma unroll
    for (int kk = 0; kk < 32; kk++) {
      float4 a = *(const float4*)&sA[kk][ty << 2];
      float4 b = *(const float4*)&sB[kk][tx << 2];
      acc[0][0] += a.x*b.x; acc[0][1] += a.x*b.y; acc[0][2] += a.x*b.z; acc[0][3] += a.x*b.w;
      acc[1][0] += a.y*b.x; acc[1][1] += a.y*b.y; acc[1][2] += a.y*b.z; acc[1][3] += a.y*b.w;
      acc[2][0] += a.z*b.x; acc[2][1] += a.z*b.y; acc[2][2] += a.z*b.z; acc[2][3] += a.z*b.w;
      acc[3][0] += a.w*b.x; acc[3][1] += a.w*b.y; acc[3][2] += a.w*b.z; acc[3][3] += a.w*b.w;
    }
    __syncthreads();
  }
  #pragma unroll
  for (int q = 0; q < 4; q++) {
    int cq = c0 + (tx << 2) + q;
    int bq = cq / Dp, dq = cq - bq*Dp;
    int coldst = bq*LDH + dstoff + dq;
    #pragma unroll
    for (int i = 0; i < 4; i++)
      hbuf[(size_t)(m0 + (ty<<2) + i)*RSTR + coldst] = acc[i][q];
  }
}

// out[(nb), o] = act( h[(nb), :Kp] @ Wp + bias )
// mode 0: sigmoid -> ru[nb*128+o]   (dout=128)
// mode 1: st[nb*64+o] = u*st + (1-u)*tanh(.), u = ru[nb*128+64+o]  (dout=64)
__global__ __launch_bounds__(256) void k_gemm2(const float* __restrict__ h,
        const float* __restrict__ Wp, const float* __restrict__ bias,
        int Kp, int dout, int mode,
        const float* __restrict__ rubuf, float* __restrict__ outp) {
  __shared__ float sA[32][68];   // sA[k][r]
  __shared__ float sB[32][68];   // sB[k][c]
  int r0 = blockIdx.x << 6;
  int c0 = blockIdx.y << 6;
  int tid = threadIdx.x;
  int ty = tid >> 4, tx = tid & 15;
  int ak = tid & 31, ar = tid >> 5;
  int wc = tid & 63, wk4 = tid >> 6;
  float acc[4][4] = {{0.f,0.f,0.f,0.f},{0.f,0.f,0.f,0.f},{0.f,0.f,0.f,0.f},{0.f,0.f,0.f,0.f}};
  for (int k0 = 0; k0 < Kp; k0 += 32) {
    #pragma unroll
    for (int i = 0; i < 8; i++)
      sA[ak][ar + i*8] = h[(size_t)(r0 + ar + i*8)*LDH + k0 + ak];
    #pragma unroll
    for (int j = 0; j < 8; j++) {
      int k = wk4 + j*4;
      sB[k][wc] = Wp[(size_t)(k0 + k)*dout + c0 + wc];
    }
    __syncthreads();
    #pragma unroll
    for (int kk = 0; kk < 32; kk++) {
      float4 a = *(const float4*)&sA[kk][ty << 2];
      float4 b = *(const float4*)&sB[kk][tx << 2];
      acc[0][0] += a.x*b.x; acc[0][1] += a.x*b.y; acc[0][2] += a.x*b.z; acc[0][3] += a.x*b.w;
      acc[1][0] += a.y*b.x; acc[1][1] += a.y*b.y; acc[1][2] += a.y*b.z; acc[1][3] += a.y*b.w;
      acc[2][0] += a.z*b.x; acc[2][1] += a.z*b.y; acc[2][2] += a.z*b.z; acc[2][3] += a.z*b.w;
      acc[3][0] += a.w*b.x; acc[3][1] += a.w*b.y; acc[3][2] += a.w*b.z; acc[3][3] += a.w*b.w;
    }
    __syncthreads();
  }
  #pragma unroll
  for (int q = 0; q < 4; q++) {
    int o = c0 + (tx << 2) + q;
    float bv = bias[o];
    #pragma unroll
    for (int i = 0; i < 4; i++) {
      int nb = r0 + (ty << 2) + i;
      float x = acc[i][q] + bv;
      if (mode == 0) {
        outp[(size_t)nb*128 + o] = 1.f/(1.f + expf(-x));
      } else {
        float u = rubuf[(size_t)nb*128 + 64 + o];
        float sold = outp[(size_t)nb*HH + o];
        outp[(size_t)nb*HH + o] = u*sold + (1.f - u)*tanhf(x);
      }
    }
  }
}

// out_t[n,b] = st1[nb,:] @ outW + outb ; write d_out[b, t, n] and dec_in[nb]
__global__ __launch_bounds__(256) void k_proj(const float* __restrict__ st1,
        const float* __restrict__ ow, const float* __restrict__ ob,
        float* __restrict__ outg, float* __restrict__ dec_in, int t) {
  int nb = blockIdx.x*256 + threadIdx.x;
  if (nb >= NB) return;
  float acc = ob[0];
  #pragma unroll
  for (int hh = 0; hh < HH; hh++) acc += st1[(size_t)nb*HH + hh] * ow[hh];
  int n = nb >> 4, b = nb & 15;
  outg[((size_t)b*TT + t)*NN + n] = acc;
  dec_in[nb] = acc;
}

extern "C" void kernel_launch(void* const* d_in, const int* in_sizes, int n_in,
                              void* d_out, int out_size, void* d_ws, size_t ws_size,
                              hipStream_t stream) {
  const float* inputs   = (const float*)d_in[0];
  const float* supports = (const float*)d_in[1];
  const float* W_e0ru = (const float*)d_in[2];
  const float* b_e0ru = (const float*)d_in[3];
  const float* W_e0c  = (const float*)d_in[4];
  const float* b_e0c  = (const float*)d_in[5];
  const float* W_e1ru = (const float*)d_in[6];
  const float* b_e1ru = (const float*)d_in[7];
  const float* W_e1c  = (const float*)d_in[8];
  const float* b_e1c  = (const float*)d_in[9];
  const float* W_d0ru = (const float*)d_in[10];
  const float* b_d0ru = (const float*)d_in[11];
  const float* W_d0c  = (const float*)d_in[12];
  const float* b_d0c  = (const float*)d_in[13];
  const float* W_d1ru = (const float*)d_in[14];
  const float* b_d1ru = (const float*)d_in[15];
  const float* W_d1c  = (const float*)d_in[16];
  const float* b_d1c  = (const float*)d_in[17];
  const float* outW   = (const float*)d_in[18];
  const float* outB   = (const float*)d_in[19];
  float* out = (float*)d_out;

  float* f = (float*)d_ws;
  float* h     = f;  f += (size_t)NB*LDH + 16;
  float* ru    = f;  f += (size_t)NB*128;
  float* st0   = f;  f += (size_t)NB*HH;
  float* st1   = f;  f += (size_t)NB*HH;
  float* decin = f;  f += NB;
  float* xin   = f;  f += (size_t)TT*NB*2;
  float* Wp_e0ru = f; f += 352*128;
  float* Wp_e0c  = f; f += 352*64;
  float* Wp_e1ru = f; f += 640*128;
  float* Wp_e1c  = f; f += 640*64;
  float* Wp_d0ru = f; f += 352*128;
  float* Wp_d0c  = f; f += 352*64;
  float* Wp_d1ru = f; f += 640*128;
  float* Wp_d1c  = f; f += 640*64;

  auto blocks = [](int n){ return (n + 255)/256; };
  k_zero<<<blocks(NB*HH), 256, 0, stream>>>(st0, NB*HH);
  k_zero<<<blocks(NB*HH), 256, 0, stream>>>(st1, NB*HH);
  k_zero<<<blocks(NB), 256, 0, stream>>>(decin, NB);
  k_transpose_in<<<blocks(BB*TT*NN*2), 256, 0, stream>>>(inputs, xin);
  k_padW<<<blocks(352*128), 256, 0, stream>>>(W_e0ru, Wp_e0ru, 66, 68, 352, 128);
  k_padW<<<blocks(352*64),  256, 0, stream>>>(W_e0c,  Wp_e0c,  66, 68, 352, 64);
  k_padW<<<blocks(640*128), 256, 0, stream>>>(W_e1ru, Wp_e1ru, 128, 128, 640, 128);
  k_padW<<<blocks(640*64),  256, 0, stream>>>(W_e1c,  Wp_e1c,  128, 128, 640, 64);
  k_padW<<<blocks(352*128), 256, 0, stream>>>(W_d0ru, Wp_d0ru, 65, 68, 352, 128);
  k_padW<<<blocks(352*64),  256, 0, stream>>>(W_d0c,  Wp_d0c,  65, 68, 352, 64);
  k_padW<<<blocks(640*128), 256, 0, stream>>>(W_d1ru, Wp_d1ru, 128, 128, 640, 128);
  k_padW<<<blocks(640*64),  256, 0, stream>>>(W_d1c,  Wp_d1c,  128, 128, 640, 64);

  auto cell = [&](const float* inp, int indim, float* st,
                  const float* Wru, const float* bru,
                  const float* Wc, const float* bc, int Dp, int Kp) {
    int D = indim + HH;
    dim3 gs(16, (unsigned)((BB*Dp) >> 6), 2);
    // ru-gate conv
    k_assemble<<<blocks(NB*D), 256, 0, stream>>>(inp, indim, st, nullptr, h, 0);
    k_spmm<<<gs, 256, 0, stream>>>(supports, h, 0, 0, Dp, 3*Dp, Dp);       // S0@b0->b1, S1@b0->b3
    k_spmm<<<gs, 256, 0, stream>>>(supports, h, Dp, 3*Dp, 2*Dp, 4*Dp, Dp); // S0@b1->b2, S1@b3->b4
    k_gemm2<<<dim3(NB/64, 2), 256, 0, stream>>>(h, Wru, bru, Kp, 128, 0, nullptr, ru);
    // candidate conv (r*state)
    k_assemble<<<blocks(NB*D), 256, 0, stream>>>(inp, indim, st, ru, h, 1);
    k_spmm<<<gs, 256, 0, stream>>>(supports, h, 0, 0, Dp, 3*Dp, Dp);
    k_spmm<<<gs, 256, 0, stream>>>(supports, h, Dp, 3*Dp, 2*Dp, 4*Dp, Dp);
    k_gemm2<<<dim3(NB/64, 1), 256, 0, stream>>>(h, Wc, bc, Kp, 64, 1, ru, st);
  };

  for (int t = 0; t < TT; t++) {
    cell(xin + (size_t)t*NB*2, 2, st0, Wp_e0ru, b_e0ru, Wp_e0c, b_e0c, 68, 352);
    cell(st0, 64, st1, Wp_e1ru, b_e1ru, Wp_e1c, b_e1c, 128, 640);
  }
  for (int t = 0; t < TT; t++) {
    cell(decin, 1, st0, Wp_d0ru, b_d0ru, Wp_d0c, b_d0c, 68, 352);
    cell(st0, 64, st1, Wp_d1ru, b_d1ru, Wp_d1c, b_d1c, 128, 640);
    k_proj<<<blocks(NB), 256, 0, stream>>>(st1, outW, outB, out, decin, t);
  }
}

// Round 2
// 15354.263 us; speedup vs baseline: 1.6743x; 1.6743x over previous
//
#include <hip/hip_runtime.h>
#include <math.h>

// DCRNN on MI355X — round 2: bf16 hi/lo split MFMA (3-term) for all GEMMs.
// Diffusion GEMM computed as C^T[c][m] = sum_k X^T[c,k] * S[m,k]  (both k-contig).
// Epilogue writes c-major (next hop input) + nb-major h (projection GEMM input).
// Layer0 Dp=72 (real 66/65, pad cols -> zeroed W rows), layer1 Dp=128.
// KTa (proj K): layer0 384 (360 real), layer1 640.

#define NN 1024
#define BB 16
#define TT 12
#define HH 64
#define NB (NN*BB)      // 16384

typedef unsigned short u16;
typedef unsigned int u32;
typedef __attribute__((ext_vector_type(8))) short sv8;
typedef __attribute__((ext_vector_type(4))) float f32x4;

__device__ __forceinline__ void gload16(const void* g, void* l) {
  __builtin_amdgcn_global_load_lds(
      (const __attribute__((address_space(1))) void*)(unsigned long long)(g),
      (__attribute__((address_space(3))) void*)(l), 16, 0, 0);
}

__device__ __forceinline__ u16 bf16_rne(float x) {
  u32 u = __float_as_uint(x);
  u32 r = (u + 0x7FFFu + ((u >> 16) & 1u)) >> 16;
  return (u16)r;
}
__device__ __forceinline__ void split2(float x, u16& h, u16& l) {
  h = bf16_rne(x);
  float hf = __uint_as_float(((u32)h) << 16);
  l = bf16_rne(x - hf);
}

__global__ __launch_bounds__(256) void k_zero(float* p, int n) {
  int i = blockIdx.x * 256 + threadIdx.x;
  if (i < n) p[i] = 0.f;
}

// inputs (B,T,N,2) -> xin (T, N, B, 2)
__global__ __launch_bounds__(256) void k_transpose_in(const float* __restrict__ in,
                                                      float* __restrict__ xt) {
  int idx = blockIdx.x * 256 + threadIdx.x;
  if (idx >= BB * TT * NN * 2) return;
  int i = idx & 1;
  int n = (idx >> 1) & (NN - 1);
  int bt = idx >> 11;
  int t = bt % TT, b = bt / TT;
  xt[(size_t)t * (NB * 2) + (size_t)(n * BB + b) * 2 + i] = in[idx];
}

// supports f32 -> hi/lo bf16
__global__ __launch_bounds__(256) void k_splitS(const float* __restrict__ s,
                                                u16* __restrict__ sh, u16* __restrict__ sl) {
  int idx = blockIdx.x * 256 + threadIdx.x;
  if (idx >= 2 * NN * NN) return;
  u16 h, l; split2(s[idx], h, l);
  sh[idx] = h; sl[idx] = l;
}

// W (5*Dreal, dout) -> Wt hi/lo [o][KTa], row kk = blk*Dp + d, zeros elsewhere
__global__ __launch_bounds__(256) void k_padWt(const float* __restrict__ W,
        u16* __restrict__ Wth, u16* __restrict__ Wtl,
        int Dreal, int Dp, int KTa, int dout) {
  int idx = blockIdx.x * 256 + threadIdx.x;
  if (idx >= dout * KTa) return;
  int kk = idx % KTa, o = idx / KTa;
  int blk = kk / Dp, d = kk - blk * Dp;
  float v = 0.f;
  if (blk < 5 && d < Dreal) v = W[(size_t)(blk * Dreal + d) * dout + o];
  u16 h, l; split2(v, h, l);
  Wth[idx] = h; Wtl[idx] = l;
}

// builds Yc0 c-major hi/lo: Yc[(b*Dp+d)*NN + n]
__global__ __launch_bounds__(256) void k_prep_c(const float* __restrict__ inp, int indim,
        const float* __restrict__ st, const float* __restrict__ ruptr,
        u16* __restrict__ ych, u16* __restrict__ ycl, int Dp) {
  int idx = blockIdx.x * 256 + threadIdx.x;
  int n = idx & (NN - 1);
  int c = idx >> 10;
  int b = c / Dp, d = c - b * Dp;
  int nb = (n << 4) + b;
  float v = 0.f;
  if (d < indim) v = inp[(size_t)nb * indim + d];
  else if (d < indim + HH) {
    v = st[(size_t)nb * HH + (d - indim)];
    if (ruptr) v *= ruptr[(size_t)nb * 128 + (d - indim)];
  }
  u16 h, l; split2(v, h, l);
  ych[idx] = h; ycl[idx] = l;
}

// builds h block0 nb-major hi/lo: h[nb*KTa + d]
__global__ __launch_bounds__(256) void k_prep_h(const float* __restrict__ inp, int indim,
        const float* __restrict__ st, const float* __restrict__ ruptr,
        u16* __restrict__ hh, u16* __restrict__ hl, int Dp, int KTa) {
  int idx = blockIdx.x * 256 + threadIdx.x;
  int d = idx % Dp, nb = idx / Dp;
  float v = 0.f;
  if (d < indim) v = inp[(size_t)nb * indim + d];
  else if (d < indim + HH) {
    v = st[(size_t)nb * HH + (d - indim)];
    if (ruptr) v *= ruptr[(size_t)nb * 128 + (d - indim)];
  }
  u16 h, l; split2(v, h, l);
  hh[(size_t)nb * KTa + d] = h; hl[(size_t)nb * KTa + d] = l;
}

// Diffusion GEMM: C^T[c][m] = sum_k A[c][k] * S[m][k], 128x128 tile, K=1024.
// A = Yc (c-major), hi/lo; B = support z, hi/lo. 3-term split MFMA.
// Writes: optional c-major Yc-out (z slot), always nb-major h at blkoff.
__global__ __launch_bounds__(256) void k_diffuse(
    const u16* __restrict__ Ah, const u16* __restrict__ Al, size_t zstrA,
    const u16* __restrict__ Sh, const u16* __restrict__ Sl,
    u16* __restrict__ Ych, u16* __restrict__ Ycl, size_t zstrYc, int hasYc,
    u16* __restrict__ hh, u16* __restrict__ hl,
    int blkoff0, int blkoff1, int Dp, int KTa)
{
  __shared__ __attribute__((aligned(16))) u16 lAh[128][32];
  __shared__ __attribute__((aligned(16))) u16 lAl[128][32];
  __shared__ __attribute__((aligned(16))) u16 lBh[128][32];
  __shared__ __attribute__((aligned(16))) u16 lBl[128][32];
  const int tid = threadIdx.x;
  const int lane = tid & 63, wave = tid >> 6;
  const int z = blockIdx.z;
  const u16* A_h = Ah + (size_t)z * zstrA;
  const u16* A_l = Al + (size_t)z * zstrA;
  const u16* B_h = Sh + (size_t)z * (NN * NN);
  const u16* B_l = Sl + (size_t)z * (NN * NN);
  const int a0 = blockIdx.x << 7;
  const int b0 = blockIdx.y << 7;
  const int wm0 = (wave & 1) << 6;
  const int wn0 = (wave >> 1) << 6;
  const int kb = (lane >> 4) << 3;
  const int rsel = lane & 15;

  f32x4 acc[4][4];
  #pragma unroll
  for (int i = 0; i < 4; i++)
    #pragma unroll
    for (int j = 0; j < 4; j++) acc[i][j] = (f32x4){0.f, 0.f, 0.f, 0.f};

  for (int k0 = 0; k0 < NN; k0 += 32) {
    #pragma unroll
    for (int i = 0; i < 2; i++) {
      int slot = tid + (i << 8);
      int row = slot >> 2, ko = (slot & 3) << 3;
      gload16(A_h + (size_t)(a0 + row) * NN + k0 + ko, &lAh[row][ko]);
      gload16(A_l + (size_t)(a0 + row) * NN + k0 + ko, &lAl[row][ko]);
      gload16(B_h + (size_t)(b0 + row) * NN + k0 + ko, &lBh[row][ko]);
      gload16(B_l + (size_t)(b0 + row) * NN + k0 + ko, &lBl[row][ko]);
    }
    __syncthreads();
    sv8 vah[4], vaL[4], vbh[4], vbL[4];
    #pragma unroll
    for (int f = 0; f < 4; f++) {
      vah[f] = *(const sv8*)&lAh[wm0 + f * 16 + rsel][kb];
      vaL[f] = *(const sv8*)&lAl[wm0 + f * 16 + rsel][kb];
      vbh[f] = *(const sv8*)&lBh[wn0 + f * 16 + rsel][kb];
      vbL[f] = *(const sv8*)&lBl[wn0 + f * 16 + rsel][kb];
    }
    #pragma unroll
    for (int fm = 0; fm < 4; fm++)
      #pragma unroll
      for (int fn = 0; fn < 4; fn++) {
        acc[fm][fn] = __builtin_amdgcn_mfma_f32_16x16x32_bf16(vah[fm], vbh[fn], acc[fm][fn], 0, 0, 0);
        acc[fm][fn] = __builtin_amdgcn_mfma_f32_16x16x32_bf16(vah[fm], vbL[fn], acc[fm][fn], 0, 0, 0);
        acc[fm][fn] = __builtin_amdgcn_mfma_f32_16x16x32_bf16(vaL[fm], vbh[fn], acc[fm][fn], 0, 0, 0);
      }
    __syncthreads();
  }

  u16* yh = Ych + (size_t)z * zstrYc;
  u16* yl = Ycl + (size_t)z * zstrYc;
  const int blkoff = z ? blkoff1 : blkoff0;
  #pragma unroll
  for (int fm = 0; fm < 4; fm++) {
    #pragma unroll
    for (int r = 0; r < 4; r++) {
      int cg = a0 + wm0 + fm * 16 + ((lane >> 4) << 2) + r;
      int bq = cg / Dp;
      int dq = cg - bq * Dp;
      #pragma unroll
      for (int fn = 0; fn < 4; fn++) {
        float v = acc[fm][fn][r];
        u16 hi, lo; split2(v, hi, lo);
        int mg = b0 + wn0 + fn * 16 + rsel;
        if (hasYc) {
          yh[(size_t)cg * NN + mg] = hi;
          yl[(size_t)cg * NN + mg] = lo;
        }
        size_t hidx = (size_t)((mg << 4) + bq) * KTa + blkoff + dq;
        hh[hidx] = hi; hl[hidx] = lo;
      }
    }
  }
}

// Projection GEMM: out[nb][o] = act(sum_k h[nb][k] * Wt[o][k] + bias).
// BM=64, BN = dout (128 or 64), 4 waves 2x2 (WM=32, WN=BN/2).
// mode 0: sigmoid -> ru[nb*128+o]; mode 1: GRU update -> st[nb*64+o].
template<int BN>
__global__ __launch_bounds__(256) void k_gemm3(
    const u16* __restrict__ Ah, const u16* __restrict__ Al, int KTa,
    const u16* __restrict__ Bh, const u16* __restrict__ Bl,
    const float* __restrict__ bias, int mode,
    const float* __restrict__ rubuf, float* __restrict__ outp)
{
  constexpr int WN = BN / 2;
  constexpr int FN = WN / 16;
  __shared__ __attribute__((aligned(16))) u16 lAh[64][32];
  __shared__ __attribute__((aligned(16))) u16 lAl[64][32];
  __shared__ __attribute__((aligned(16))) u16 lBh[BN][32];
  __shared__ __attribute__((aligned(16))) u16 lBl[BN][32];
  const int tid = threadIdx.x;
  const int lane = tid & 63, wave = tid >> 6;
  const int a0 = blockIdx.x << 6;
  const int wm0 = (wave & 1) << 5;
  const int wn0 = (wave >> 1) * WN;
  const int kb = (lane >> 4) << 3;
  const int rsel = lane & 15;

  f32x4 acc[2][FN];
  #pragma unroll
  for (int i = 0; i < 2; i++)
    #pragma unroll
    for (int j = 0; j < FN; j++) acc[i][j] = (f32x4){0.f, 0.f, 0.f, 0.f};

  for (int k0 = 0; k0 < KTa; k0 += 32) {
    {
      int row = tid >> 2, ko = (tid & 3) << 3;
      gload16(Ah + (size_t)(a0 + row) * KTa + k0 + ko, &lAh[row][ko]);
      gload16(Al + (size_t)(a0 + row) * KTa + k0 + ko, &lAl[row][ko]);
    }
    #pragma unroll
    for (int i = 0; i < (BN * 4) / 256; i++) {
      int slot = tid + (i << 8);
      int row = slot >> 2, ko = (slot & 3) << 3;
      gload16(Bh + (size_t)row * KTa + k0 + ko, &lBh[row][ko]);
      gload16(Bl + (size_t)row * KTa + k0 + ko, &lBl[row][ko]);
    }
    __syncthreads();
    sv8 vah[2], vaL[2], vbh[FN], vbL[FN];
    #pragma unroll
    for (int f = 0; f < 2; f++) {
      vah[f] = *(const sv8*)&lAh[wm0 + f * 16 + rsel][kb];
      vaL[f] = *(const sv8*)&lAl[wm0 + f * 16 + rsel][kb];
    }
    #pragma unroll
    for (int f = 0; f < FN; f++) {
      vbh[f] = *(const sv8*)&lBh[wn0 + f * 16 + rsel][kb];
      vbL[f] = *(const sv8*)&lBl[wn0 + f * 16 + rsel][kb];
    }
    #pragma unroll
    for (int fm = 0; fm < 2; fm++)
      #pragma unroll
      for (int fn = 0; fn < FN; fn++) {
        acc[fm][fn] = __builtin_amdgcn_mfma_f32_16x16x32_bf16(vah[fm], vbh[fn], acc[fm][fn], 0, 0, 0);
        acc[fm][fn] = __builtin_amdgcn_mfma_f32_16x16x32_bf16(vah[fm], vbL[fn], acc[fm][fn], 0, 0, 0);
        acc[fm][fn] = __builtin_amdgcn_mfma_f32_16x16x32_bf16(vaL[fm], vbh[fn], acc[fm][fn], 0, 0, 0);
      }
    __syncthreads();
  }

  #pragma unroll
  for (int fm = 0; fm < 2; fm++) {
    #pragma unroll
    for (int r = 0; r < 4; r++) {
      int nb = a0 + wm0 + fm * 16 + ((lane >> 4) << 2) + r;
      #pragma unroll
      for (int fn = 0; fn < FN; fn++) {
        int o = wn0 + fn * 16 + rsel;
        float v = acc[fm][fn][r] + bias[o];
        if (mode == 0) {
          outp[(size_t)nb * 128 + o] = 1.f / (1.f + expf(-v));
        } else {
          float u = rubuf[(size_t)nb * 128 + 64 + o];
          float sold = outp[(size_t)nb * HH + o];
          outp[(size_t)nb * HH + o] = u * sold + (1.f - u) * tanhf(v);
        }
      }
    }
  }
}

// out_t[n,b] = st1[nb,:] @ outW + outb ; write d_out[b, t, n] and dec_in[nb]
__global__ __launch_bounds__(256) void k_proj(const float* __restrict__ st1,
        const float* __restrict__ ow, const float* __restrict__ ob,
        float* __restrict__ outg, float* __restrict__ dec_in, int t) {
  int nb = blockIdx.x * 256 + threadIdx.x;
  if (nb >= NB) return;
  float acc = ob[0];
  #pragma unroll
  for (int h = 0; h < HH; h++) acc += st1[(size_t)nb * HH + h] * ow[h];
  int n = nb >> 4, b = nb & 15;
  outg[((size_t)b * TT + t) * NN + n] = acc;
  dec_in[nb] = acc;
}

extern "C" void kernel_launch(void* const* d_in, const int* in_sizes, int n_in,
                              void* d_out, int out_size, void* d_ws, size_t ws_size,
                              hipStream_t stream) {
  const float* inputs   = (const float*)d_in[0];
  const float* supports = (const float*)d_in[1];
  const float* Wsrc[8] = {(const float*)d_in[2], (const float*)d_in[4],
                          (const float*)d_in[6], (const float*)d_in[8],
                          (const float*)d_in[10], (const float*)d_in[12],
                          (const float*)d_in[14], (const float*)d_in[16]};
  const float* bias[8] = {(const float*)d_in[3], (const float*)d_in[5],
                          (const float*)d_in[7], (const float*)d_in[9],
                          (const float*)d_in[11], (const float*)d_in[13],
                          (const float*)d_in[15], (const float*)d_in[17]};
  const float* outW = (const float*)d_in[18];
  const float* outB = (const float*)d_in[19];
  float* out = (float*)d_out;

  char* cur = (char*)d_ws;
  auto alloc = [&](size_t bytes) -> char* {
    char* p = cur; cur += (bytes + 255) & ~(size_t)255; return p;
  };
  u16* Sh   = (u16*)alloc((size_t)2 * NN * NN * 2);
  u16* Sl   = (u16*)alloc((size_t)2 * NN * NN * 2);
  u16* Yc0h = (u16*)alloc((size_t)2048 * NN * 2);
  u16* Yc0l = (u16*)alloc((size_t)2048 * NN * 2);
  u16* Yc1h = (u16*)alloc((size_t)2 * 2048 * NN * 2);
  u16* Yc1l = (u16*)alloc((size_t)2 * 2048 * NN * 2);
  u16* hh   = (u16*)alloc((size_t)NB * 640 * 2);
  u16* hl   = (u16*)alloc((size_t)NB * 640 * 2);
  float* ru    = (float*)alloc((size_t)NB * 128 * 4);
  float* st0   = (float*)alloc((size_t)NB * HH * 4);
  float* st1   = (float*)alloc((size_t)NB * HH * 4);
  float* decin = (float*)alloc((size_t)NB * 4);
  float* xin   = (float*)alloc((size_t)TT * NB * 2 * 4);
  // weight sets: 0 e0ru(128,384) 1 e0c(64,384) 2 e1ru(128,640) 3 e1c(64,640)
  //              4 d0ru 5 d0c 6 d1ru 7 d1c
  const int wDout[8] = {128, 64, 128, 64, 128, 64, 128, 64};
  const int wKTa[8]  = {384, 384, 640, 640, 384, 384, 640, 640};
  const int wDreal[8]= {66, 66, 128, 128, 65, 65, 128, 128};
  const int wDp[8]   = {72, 72, 128, 128, 72, 72, 128, 128};
  u16 *Wth[8], *Wtl[8];
  for (int i = 0; i < 8; i++) {
    Wth[i] = (u16*)alloc((size_t)wDout[i] * wKTa[i] * 2);
    Wtl[i] = (u16*)alloc((size_t)wDout[i] * wKTa[i] * 2);
  }

  auto blocks = [](int n) { return (n + 255) / 256; };
  k_zero<<<blocks(NB * HH), 256, 0, stream>>>(st0, NB * HH);
  k_zero<<<blocks(NB * HH), 256, 0, stream>>>(st1, NB * HH);
  k_zero<<<blocks(NB), 256, 0, stream>>>(decin, NB);
  k_transpose_in<<<blocks(BB * TT * NN * 2), 256, 0, stream>>>(inputs, xin);
  k_splitS<<<blocks(2 * NN * NN), 256, 0, stream>>>(supports, Sh, Sl);
  for (int i = 0; i < 8; i++)
    k_padWt<<<blocks(wDout[i] * wKTa[i]), 256, 0, stream>>>(
        Wsrc[i], Wth[i], Wtl[i], wDreal[i], wDp[i], wKTa[i], wDout[i]);

  // one graph-conv + projection; wi = weight-set index (ru), wi+1 = candidate
  auto conv = [&](const float* inp, int indim, float* st, int wi, bool cand) {
    int Dp = wDp[wi], KTa = wKTa[wi];
    int CB = BB * Dp;                 // 1152 or 2048
    const float* ruptr = cand ? ru : nullptr;
    k_prep_c<<<CB * NN / 256, 256, 0, stream>>>(inp, indim, st, ruptr, Yc0h, Yc0l, Dp);
    k_prep_h<<<NB * Dp / 256, 256, 0, stream>>>(inp, indim, st, ruptr, hh, hl, Dp, KTa);
    dim3 g(CB / 128, NN / 128, 2);
    size_t zy = (size_t)CB * NN;
    k_diffuse<<<g, 256, 0, stream>>>(Yc0h, Yc0l, 0, Sh, Sl,
                                     Yc1h, Yc1l, zy, 1, hh, hl,
                                     1 * Dp, 3 * Dp, Dp, KTa);
    k_diffuse<<<g, 256, 0, stream>>>(Yc1h, Yc1l, zy, Sh, Sl,
                                     Yc1h, Yc1l, 0, 0, hh, hl,
                                     2 * Dp, 4 * Dp, Dp, KTa);
    int wsel = cand ? wi + 1 : wi;
    if (!cand)
      k_gemm3<128><<<dim3(NB / 64, 1), 256, 0, stream>>>(
          hh, hl, KTa, Wth[wsel], Wtl[wsel], bias[wsel], 0, nullptr, ru);
    else
      k_gemm3<64><<<dim3(NB / 64, 1), 256, 0, stream>>>(
          hh, hl, KTa, Wth[wsel], Wtl[wsel], bias[wsel], 1, ru, st);
  };
  auto cell = [&](const float* inp, int indim, float* st, int wi) {
    conv(inp, indim, st, wi, false);
    conv(inp, indim, st, wi, true);
  };

  for (int t = 0; t < TT; t++) {
    cell(xin + (size_t)t * NB * 2, 2, st0, 0);
    cell(st0, 64, st1, 2);
  }
  for (int t = 0; t < TT; t++) {
    cell(decin, 1, st0, 4);
    cell(st0, 64, st1, 6);
    k_proj<<<blocks(NB), 256, 0, stream>>>(st1, outW, outB, out, decin, t);
  }
}

// Round 3
// 13018.724 us; speedup vs baseline: 1.9747x; 1.1794x over previous
//
#include <hip/hip_runtime.h>
#include <math.h>

// DCRNN on MI355X — round 3: same 3-term bf16-split math as R2, restructured for
// occupancy: 8-wave (512-thr) GEMM blocks, merged prep kernel, packed h stores.
// Diffusion GEMM: C^T[c][m] = sum_k Yc[c][k] * S[m][k], tiles BMxBN=BMx128, BK=32.

#define NN 1024
#define BB 16
#define TT 12
#define HH 64
#define NB (NN*BB)      // 16384

typedef unsigned short u16;
typedef unsigned int u32;
typedef __attribute__((ext_vector_type(8))) short sv8;
typedef __attribute__((ext_vector_type(4))) float f32x4;

__device__ __forceinline__ void gload16(const void* g, void* l) {
  __builtin_amdgcn_global_load_lds(
      (const __attribute__((address_space(1))) void*)(unsigned long long)(g),
      (__attribute__((address_space(3))) void*)(l), 16, 0, 0);
}

__device__ __forceinline__ u16 bf16_rne(float x) {
  u32 u = __float_as_uint(x);
  u32 r = (u + 0x7FFFu + ((u >> 16) & 1u)) >> 16;
  return (u16)r;
}
__device__ __forceinline__ void split2(float x, u16& h, u16& l) {
  h = bf16_rne(x);
  float hf = __uint_as_float(((u32)h) << 16);
  l = bf16_rne(x - hf);
}

__global__ __launch_bounds__(256) void k_zero(float* p, int n) {
  int i = blockIdx.x * 256 + threadIdx.x;
  if (i < n) p[i] = 0.f;
}

// inputs (B,T,N,2) -> xin (T, N, B, 2)
__global__ __launch_bounds__(256) void k_transpose_in(const float* __restrict__ in,
                                                      float* __restrict__ xt) {
  int idx = blockIdx.x * 256 + threadIdx.x;
  if (idx >= BB * TT * NN * 2) return;
  int i = idx & 1;
  int n = (idx >> 1) & (NN - 1);
  int bt = idx >> 11;
  int t = bt % TT, b = bt / TT;
  xt[(size_t)t * (NB * 2) + (size_t)(n * BB + b) * 2 + i] = in[idx];
}

// supports f32 -> hi/lo bf16
__global__ __launch_bounds__(256) void k_splitS(const float* __restrict__ s,
                                                u16* __restrict__ sh, u16* __restrict__ sl) {
  int idx = blockIdx.x * 256 + threadIdx.x;
  if (idx >= 2 * NN * NN) return;
  u16 h, l; split2(s[idx], h, l);
  sh[idx] = h; sl[idx] = l;
}

// W (5*Dreal, dout) -> Wt hi/lo [o][KTa], row kk = blk*Dp + d, zeros elsewhere
__global__ __launch_bounds__(256) void k_padWt(const float* __restrict__ W,
        u16* __restrict__ Wth, u16* __restrict__ Wtl,
        int Dreal, int Dp, int KTa, int dout) {
  int idx = blockIdx.x * 256 + threadIdx.x;
  if (idx >= dout * KTa) return;
  int kk = idx % KTa, o = idx / KTa;
  int blk = kk / Dp, d = kk - blk * Dp;
  float v = 0.f;
  if (blk < 5 && d < Dreal) v = W[(size_t)(blk * Dreal + d) * dout + o];
  u16 h, l; split2(v, h, l);
  Wth[idx] = h; Wtl[idx] = l;
}

// Merged prep: writes Yc0 (c-major, packed 4-wide) AND h block0 (nb-major).
// grid = CB blocks x 256 threads; block b handles c = blockIdx.x, 256 n4-groups.
__global__ __launch_bounds__(256) void k_prep(const float* __restrict__ inp, int indim,
        const float* __restrict__ st, const float* __restrict__ ru_,
        u16* __restrict__ ych, u16* __restrict__ ycl,
        u16* __restrict__ hh, u16* __restrict__ hl, int Dp, int KTa) {
  int c = blockIdx.x;
  int n0 = threadIdx.x << 2;
  int b = c / Dp, d = c - b * Dp;
  u16 h4[4], l4[4];
  #pragma unroll
  for (int r = 0; r < 4; r++) {
    int nb = ((n0 + r) << 4) + b;
    float v = 0.f;
    if (d < indim) v = inp[(size_t)nb * indim + d];
    else if (d < indim + HH) {
      v = st[(size_t)nb * HH + (d - indim)];
      if (ru_) v *= ru_[(size_t)nb * 128 + (d - indim)];
    }
    split2(v, h4[r], l4[r]);
    hh[(size_t)nb * KTa + d] = h4[r];
    hl[(size_t)nb * KTa + d] = l4[r];
  }
  uint2 ph, pl;
  ph.x = (u32)h4[0] | ((u32)h4[1] << 16); ph.y = (u32)h4[2] | ((u32)h4[3] << 16);
  pl.x = (u32)l4[0] | ((u32)l4[1] << 16); pl.y = (u32)l4[2] | ((u32)l4[3] << 16);
  *(uint2*)&ych[(size_t)c * NN + n0] = ph;
  *(uint2*)&ycl[(size_t)c * NN + n0] = pl;
}

// Diffusion GEMM, 8 waves (512 thr), tile BM(c) x 128(m), BK=32, 3-term split.
// Wave grid: 2(c) x 4(m); per wave FM x 2 frags of 16x16.
template<int BM>
__global__ __launch_bounds__(512) void k_diffuse(
    const u16* __restrict__ Ah, const u16* __restrict__ Al, size_t zstrA,
    const u16* __restrict__ Sh, const u16* __restrict__ Sl,
    u16* __restrict__ Ych, u16* __restrict__ Ycl, size_t zstrYc, int hasYc,
    u16* __restrict__ hh, u16* __restrict__ hl,
    int blkoff0, int blkoff1, int Dp, int KTa)
{
  constexpr int FM = BM / 32;
  __shared__ __attribute__((aligned(16))) u16 lAh[BM][32];
  __shared__ __attribute__((aligned(16))) u16 lAl[BM][32];
  __shared__ __attribute__((aligned(16))) u16 lBh[128][32];
  __shared__ __attribute__((aligned(16))) u16 lBl[128][32];
  const int tid = threadIdx.x;
  const int lane = tid & 63, wave = tid >> 6;
  const int z = blockIdx.z;
  const u16* A_h = Ah + (size_t)z * zstrA;
  const u16* A_l = Al + (size_t)z * zstrA;
  const u16* B_h = Sh + (size_t)z * (NN * NN);
  const u16* B_l = Sl + (size_t)z * (NN * NN);
  const int a0 = blockIdx.x * BM;
  const int b0 = blockIdx.y << 7;
  const int wc0 = (wave & 1) * (BM / 2);
  const int wm0 = (wave >> 1) << 5;
  const int kb = (lane >> 4) << 3;
  const int rsel = lane & 15;

  f32x4 acc[FM][2];
  #pragma unroll
  for (int i = 0; i < FM; i++)
    #pragma unroll
    for (int j = 0; j < 2; j++) acc[i][j] = (f32x4){0.f, 0.f, 0.f, 0.f};

  for (int k0 = 0; k0 < NN; k0 += 32) {
    if (BM == 128) {
      int row = tid >> 2, ko = (tid & 3) << 3;
      gload16(A_h + (size_t)(a0 + row) * NN + k0 + ko, &lAh[row][ko]);
      gload16(A_l + (size_t)(a0 + row) * NN + k0 + ko, &lAl[row][ko]);
      gload16(B_h + (size_t)(b0 + row) * NN + k0 + ko, &lBh[row][ko]);
      gload16(B_l + (size_t)(b0 + row) * NN + k0 + ko, &lBl[row][ko]);
    } else {
      int arow = (tid & 255) >> 2, ako = (tid & 3) << 3;
      if (tid < 256) gload16(A_h + (size_t)(a0 + arow) * NN + k0 + ako, &lAh[arow][ako]);
      else           gload16(A_l + (size_t)(a0 + arow) * NN + k0 + ako, &lAl[arow][ako]);
      int brow = tid >> 2, bko = (tid & 3) << 3;
      gload16(B_h + (size_t)(b0 + brow) * NN + k0 + bko, &lBh[brow][bko]);
      gload16(B_l + (size_t)(b0 + brow) * NN + k0 + bko, &lBl[brow][bko]);
    }
    __syncthreads();
    sv8 vah[FM], vaL[FM], vbh[2], vbL[2];
    #pragma unroll
    for (int f = 0; f < FM; f++) {
      vah[f] = *(const sv8*)&lAh[wc0 + f * 16 + rsel][kb];
      vaL[f] = *(const sv8*)&lAl[wc0 + f * 16 + rsel][kb];
    }
    #pragma unroll
    for (int f = 0; f < 2; f++) {
      vbh[f] = *(const sv8*)&lBh[wm0 + f * 16 + rsel][kb];
      vbL[f] = *(const sv8*)&lBl[wm0 + f * 16 + rsel][kb];
    }
    #pragma unroll
    for (int fm = 0; fm < FM; fm++)
      #pragma unroll
      for (int fn = 0; fn < 2; fn++) {
        acc[fm][fn] = __builtin_amdgcn_mfma_f32_16x16x32_bf16(vah[fm], vbh[fn], acc[fm][fn], 0, 0, 0);
        acc[fm][fn] = __builtin_amdgcn_mfma_f32_16x16x32_bf16(vah[fm], vbL[fn], acc[fm][fn], 0, 0, 0);
        acc[fm][fn] = __builtin_amdgcn_mfma_f32_16x16x32_bf16(vaL[fm], vbh[fn], acc[fm][fn], 0, 0, 0);
      }
    __syncthreads();
  }

  u16* yh = Ych + (size_t)z * zstrYc;
  u16* yl = Ycl + (size_t)z * zstrYc;
  const int blkoff = z ? blkoff1 : blkoff0;
  #pragma unroll
  for (int fm = 0; fm < FM; fm++) {
    int cgbase = a0 + wc0 + fm * 16 + ((lane >> 4) << 2);
    int bq = cgbase / Dp, dq = cgbase - bq * Dp;   // 4-aligned, same b for r=0..3
    #pragma unroll
    for (int fn = 0; fn < 2; fn++) {
      int mg = b0 + wm0 + fn * 16 + rsel;
      u16 hi4[4], lo4[4];
      #pragma unroll
      for (int r = 0; r < 4; r++) {
        split2(acc[fm][fn][r], hi4[r], lo4[r]);
        if (hasYc) {
          yh[(size_t)(cgbase + r) * NN + mg] = hi4[r];
          yl[(size_t)(cgbase + r) * NN + mg] = lo4[r];
        }
      }
      size_t hidx = (size_t)((mg << 4) + bq) * KTa + blkoff + dq;
      uint2 ph, pl;
      ph.x = (u32)hi4[0] | ((u32)hi4[1] << 16); ph.y = (u32)hi4[2] | ((u32)hi4[3] << 16);
      pl.x = (u32)lo4[0] | ((u32)lo4[1] << 16); pl.y = (u32)lo4[2] | ((u32)lo4[3] << 16);
      *(uint2*)&hh[hidx] = ph;
      *(uint2*)&hl[hidx] = pl;
    }
  }
}

// Projection GEMM: out[nb][o] = act(sum_k h[nb][k] * Wt[o][k] + bias).
// BM=64 rows; BN=128 -> 512 thr (8 waves, 2x4); BN=64 -> 256 thr (4 waves, 2x2).
template<int BN>
__global__ __launch_bounds__(BN * 4) void k_gemm3(
    const u16* __restrict__ Ah_g, const u16* __restrict__ Al_g, int KTa,
    const u16* __restrict__ Bh_g, const u16* __restrict__ Bl_g,
    const float* __restrict__ bias, int mode,
    const float* __restrict__ rubuf, float* __restrict__ outp)
{
  __shared__ __attribute__((aligned(16))) u16 lAh[64][32];
  __shared__ __attribute__((aligned(16))) u16 lAl[64][32];
  __shared__ __attribute__((aligned(16))) u16 lBh[BN][32];
  __shared__ __attribute__((aligned(16))) u16 lBl[BN][32];
  const int tid = threadIdx.x;
  const int lane = tid & 63, wave = tid >> 6;
  const int a0 = blockIdx.x << 6;
  const int wr0 = (wave & 1) << 5;
  const int wn0 = (wave >> 1) << 5;
  const int kb = (lane >> 4) << 3;
  const int rsel = lane & 15;

  f32x4 acc[2][2];
  #pragma unroll
  for (int i = 0; i < 2; i++)
    #pragma unroll
    for (int j = 0; j < 2; j++) acc[i][j] = (f32x4){0.f, 0.f, 0.f, 0.f};

  for (int k0 = 0; k0 < KTa; k0 += 32) {
    if (BN == 128) {
      int arow = (tid & 255) >> 2, ako = (tid & 3) << 3;
      if (tid < 256) gload16(Ah_g + (size_t)(a0 + arow) * KTa + k0 + ako, &lAh[arow][ako]);
      else           gload16(Al_g + (size_t)(a0 + arow) * KTa + k0 + ako, &lAl[arow][ako]);
      int brow = tid >> 2, bko = (tid & 3) << 3;
      gload16(Bh_g + (size_t)brow * KTa + k0 + bko, &lBh[brow][bko]);
      gload16(Bl_g + (size_t)brow * KTa + k0 + bko, &lBl[brow][bko]);
    } else {
      int arow = tid >> 2, ako = (tid & 3) << 3;
      gload16(Ah_g + (size_t)(a0 + arow) * KTa + k0 + ako, &lAh[arow][ako]);
      gload16(Al_g + (size_t)(a0 + arow) * KTa + k0 + ako, &lAl[arow][ako]);
      gload16(Bh_g + (size_t)arow * KTa + k0 + ako, &lBh[arow][ako]);
      gload16(Bl_g + (size_t)arow * KTa + k0 + ako, &lBl[arow][ako]);
    }
    __syncthreads();
    sv8 vah[2], vaL[2], vbh[2], vbL[2];
    #pragma unroll
    for (int f = 0; f < 2; f++) {
      vah[f] = *(const sv8*)&lAh[wr0 + f * 16 + rsel][kb];
      vaL[f] = *(const sv8*)&lAl[wr0 + f * 16 + rsel][kb];
      vbh[f] = *(const sv8*)&lBh[wn0 + f * 16 + rsel][kb];
      vbL[f] = *(const sv8*)&lBl[wn0 + f * 16 + rsel][kb];
    }
    #pragma unroll
    for (int fm = 0; fm < 2; fm++)
      #pragma unroll
      for (int fn = 0; fn < 2; fn++) {
        acc[fm][fn] = __builtin_amdgcn_mfma_f32_16x16x32_bf16(vah[fm], vbh[fn], acc[fm][fn], 0, 0, 0);
        acc[fm][fn] = __builtin_amdgcn_mfma_f32_16x16x32_bf16(vah[fm], vbL[fn], acc[fm][fn], 0, 0, 0);
        acc[fm][fn] = __builtin_amdgcn_mfma_f32_16x16x32_bf16(vaL[fm], vbh[fn], acc[fm][fn], 0, 0, 0);
      }
    __syncthreads();
  }

  #pragma unroll
  for (int fm = 0; fm < 2; fm++) {
    #pragma unroll
    for (int r = 0; r < 4; r++) {
      int nb = a0 + wr0 + fm * 16 + ((lane >> 4) << 2) + r;
      #pragma unroll
      for (int fn = 0; fn < 2; fn++) {
        int o = wn0 + fn * 16 + rsel;
        float v = acc[fm][fn][r] + bias[o];
        if (mode == 0) {
          outp[(size_t)nb * 128 + o] = 1.f / (1.f + expf(-v));
        } else {
          float u = rubuf[(size_t)nb * 128 + 64 + o];
          float sold = outp[(size_t)nb * HH + o];
          outp[(size_t)nb * HH + o] = u * sold + (1.f - u) * tanhf(v);
        }
      }
    }
  }
}

// out_t[n,b] = st1[nb,:] @ outW + outb ; write d_out[b, t, n] and dec_in[nb]
__global__ __launch_bounds__(256) void k_proj(const float* __restrict__ st1,
        const float* __restrict__ ow, const float* __restrict__ ob,
        float* __restrict__ outg, float* __restrict__ dec_in, int t) {
  int nb = blockIdx.x * 256 + threadIdx.x;
  if (nb >= NB) return;
  float acc = ob[0];
  #pragma unroll
  for (int h = 0; h < HH; h++) acc += st1[(size_t)nb * HH + h] * ow[h];
  int n = nb >> 4, b = nb & 15;
  outg[((size_t)b * TT + t) * NN + n] = acc;
  dec_in[nb] = acc;
}

extern "C" void kernel_launch(void* const* d_in, const int* in_sizes, int n_in,
                              void* d_out, int out_size, void* d_ws, size_t ws_size,
                              hipStream_t stream) {
  const float* inputs   = (const float*)d_in[0];
  const float* supports = (const float*)d_in[1];
  const float* Wsrc[8] = {(const float*)d_in[2], (const float*)d_in[4],
                          (const float*)d_in[6], (const float*)d_in[8],
                          (const float*)d_in[10], (const float*)d_in[12],
                          (const float*)d_in[14], (const float*)d_in[16]};
  const float* bias[8] = {(const float*)d_in[3], (const float*)d_in[5],
                          (const float*)d_in[7], (const float*)d_in[9],
                          (const float*)d_in[11], (const float*)d_in[13],
                          (const float*)d_in[15], (const float*)d_in[17]};
  const float* outW = (const float*)d_in[18];
  const float* outB = (const float*)d_in[19];
  float* out = (float*)d_out;

  char* cur = (char*)d_ws;
  auto alloc = [&](size_t bytes) -> char* {
    char* p = cur; cur += (bytes + 255) & ~(size_t)255; return p;
  };
  u16* Sh   = (u16*)alloc((size_t)2 * NN * NN * 2);
  u16* Sl   = (u16*)alloc((size_t)2 * NN * NN * 2);
  u16* Yc0h = (u16*)alloc((size_t)2048 * NN * 2);
  u16* Yc0l = (u16*)alloc((size_t)2048 * NN * 2);
  u16* Yc1h = (u16*)alloc((size_t)2 * 2048 * NN * 2);
  u16* Yc1l = (u16*)alloc((size_t)2 * 2048 * NN * 2);
  u16* hh   = (u16*)alloc((size_t)NB * 640 * 2);
  u16* hl   = (u16*)alloc((size_t)NB * 640 * 2);
  float* ru    = (float*)alloc((size_t)NB * 128 * 4);
  float* st0   = (float*)alloc((size_t)NB * HH * 4);
  float* st1   = (float*)alloc((size_t)NB * HH * 4);
  float* decin = (float*)alloc((size_t)NB * 4);
  float* xin   = (float*)alloc((size_t)TT * NB * 2 * 4);
  const int wDout[8] = {128, 64, 128, 64, 128, 64, 128, 64};
  const int wKTa[8]  = {384, 384, 640, 640, 384, 384, 640, 640};
  const int wDreal[8]= {66, 66, 128, 128, 65, 65, 128, 128};
  const int wDp[8]   = {72, 72, 128, 128, 72, 72, 128, 128};
  u16 *Wth[8], *Wtl[8];
  for (int i = 0; i < 8; i++) {
    Wth[i] = (u16*)alloc((size_t)wDout[i] * wKTa[i] * 2);
    Wtl[i] = (u16*)alloc((size_t)wDout[i] * wKTa[i] * 2);
  }

  auto blocks = [](int n) { return (n + 255) / 256; };
  k_zero<<<blocks(NB * HH), 256, 0, stream>>>(st0, NB * HH);
  k_zero<<<blocks(NB * HH), 256, 0, stream>>>(st1, NB * HH);
  k_zero<<<blocks(NB), 256, 0, stream>>>(decin, NB);
  k_transpose_in<<<blocks(BB * TT * NN * 2), 256, 0, stream>>>(inputs, xin);
  k_splitS<<<blocks(2 * NN * NN), 256, 0, stream>>>(supports, Sh, Sl);
  for (int i = 0; i < 8; i++)
    k_padWt<<<blocks(wDout[i] * wKTa[i]), 256, 0, stream>>>(
        Wsrc[i], Wth[i], Wtl[i], wDreal[i], wDp[i], wKTa[i], wDout[i]);

  auto conv = [&](const float* inp, int indim, float* st, int wi, bool cand) {
    int Dp = wDp[wi], KTa = wKTa[wi];
    int CB = BB * Dp;                 // 1152 or 2048
    const float* ruptr = cand ? ru : nullptr;
    k_prep<<<CB, 256, 0, stream>>>(inp, indim, st, ruptr, Yc0h, Yc0l, hh, hl, Dp, KTa);
    size_t zy = (size_t)CB * NN;
    if (Dp == 128) {
      dim3 g(CB / 128, 8, 2);
      k_diffuse<128><<<g, 512, 0, stream>>>(Yc0h, Yc0l, 0, Sh, Sl,
                                            Yc1h, Yc1l, zy, 1, hh, hl,
                                            1 * Dp, 3 * Dp, Dp, KTa);
      k_diffuse<128><<<g, 512, 0, stream>>>(Yc1h, Yc1l, zy, Sh, Sl,
                                            Yc1h, Yc1l, 0, 0, hh, hl,
                                            2 * Dp, 4 * Dp, Dp, KTa);
    } else {
      dim3 g(CB / 64, 8, 2);
      k_diffuse<64><<<g, 512, 0, stream>>>(Yc0h, Yc0l, 0, Sh, Sl,
                                           Yc1h, Yc1l, zy, 1, hh, hl,
                                           1 * Dp, 3 * Dp, Dp, KTa);
      k_diffuse<64><<<g, 512, 0, stream>>>(Yc1h, Yc1l, zy, Sh, Sl,
                                           Yc1h, Yc1l, 0, 0, hh, hl,
                                           2 * Dp, 4 * Dp, Dp, KTa);
    }
    int wsel = cand ? wi + 1 : wi;
    if (!cand)
      k_gemm3<128><<<NB / 64, 512, 0, stream>>>(
          hh, hl, KTa, Wth[wsel], Wtl[wsel], bias[wsel], 0, nullptr, ru);
    else
      k_gemm3<64><<<NB / 64, 256, 0, stream>>>(
          hh, hl, KTa, Wth[wsel], Wtl[wsel], bias[wsel], 1, ru, st);
  };
  auto cell = [&](const float* inp, int indim, float* st, int wi) {
    conv(inp, indim, st, wi, false);
    conv(inp, indim, st, wi, true);
  };

  for (int t = 0; t < TT; t++) {
    cell(xin + (size_t)t * NB * 2, 2, st0, 0);
    cell(st0, 64, st1, 2);
  }
  for (int t = 0; t < TT; t++) {
    cell(decin, 1, st0, 4);
    cell(st0, 64, st1, 6);
    k_proj<<<blocks(NB), 256, 0, stream>>>(st1, outW, outB, out, decin, t);
  }
}

// Round 4
// 12486.116 us; speedup vs baseline: 2.0589x; 1.0427x over previous
//
#include <hip/hip_runtime.h>
#include <math.h>

// DCRNN on MI355X — round 4: R3 + XOR-swizzled LDS tile layout (both-sides,
// rule #21) to kill the 8-way ds_read_b128 bank conflict. Numerics identical
// to R3 (absmax must stay 3.051758e-05 exactly).
// slot(row,g) = (rp<<3) | ((((row&1)<<2)|g) ^ (rp&7)),  rp = row>>1, g = 16B k-chunk.

#define NN 1024
#define BB 16
#define TT 12
#define HH 64
#define NB (NN*BB)      // 16384

typedef unsigned short u16;
typedef unsigned int u32;
typedef __attribute__((ext_vector_type(8))) short sv8;
typedef __attribute__((ext_vector_type(4))) float f32x4;

__device__ __forceinline__ void gload16(const void* g, void* l) {
  __builtin_amdgcn_global_load_lds(
      (const __attribute__((address_space(1))) void*)(unsigned long long)(g),
      (__attribute__((address_space(3))) void*)(l), 16, 0, 0);
}

// 16-byte-slot index of (row, k-chunk g) in a swizzled tile buffer.
__device__ __forceinline__ int swz(int row, int g) {
  int rp = row >> 1;
  int j = ((row & 1) << 2) | g;
  return (rp << 3) | (j ^ (rp & 7));
}

__device__ __forceinline__ u16 bf16_rne(float x) {
  u32 u = __float_as_uint(x);
  u32 r = (u + 0x7FFFu + ((u >> 16) & 1u)) >> 16;
  return (u16)r;
}
__device__ __forceinline__ void split2(float x, u16& h, u16& l) {
  h = bf16_rne(x);
  float hf = __uint_as_float(((u32)h) << 16);
  l = bf16_rne(x - hf);
}

__global__ __launch_bounds__(256) void k_zero(float* p, int n) {
  int i = blockIdx.x * 256 + threadIdx.x;
  if (i < n) p[i] = 0.f;
}

// inputs (B,T,N,2) -> xin (T, N, B, 2)
__global__ __launch_bounds__(256) void k_transpose_in(const float* __restrict__ in,
                                                      float* __restrict__ xt) {
  int idx = blockIdx.x * 256 + threadIdx.x;
  if (idx >= BB * TT * NN * 2) return;
  int i = idx & 1;
  int n = (idx >> 1) & (NN - 1);
  int bt = idx >> 11;
  int t = bt % TT, b = bt / TT;
  xt[(size_t)t * (NB * 2) + (size_t)(n * BB + b) * 2 + i] = in[idx];
}

// supports f32 -> hi/lo bf16
__global__ __launch_bounds__(256) void k_splitS(const float* __restrict__ s,
                                                u16* __restrict__ sh, u16* __restrict__ sl) {
  int idx = blockIdx.x * 256 + threadIdx.x;
  if (idx >= 2 * NN * NN) return;
  u16 h, l; split2(s[idx], h, l);
  sh[idx] = h; sl[idx] = l;
}

// W (5*Dreal, dout) -> Wt hi/lo [o][KTa], row kk = blk*Dp + d, zeros elsewhere
__global__ __launch_bounds__(256) void k_padWt(const float* __restrict__ W,
        u16* __restrict__ Wth, u16* __restrict__ Wtl,
        int Dreal, int Dp, int KTa, int dout) {
  int idx = blockIdx.x * 256 + threadIdx.x;
  if (idx >= dout * KTa) return;
  int kk = idx % KTa, o = idx / KTa;
  int blk = kk / Dp, d = kk - blk * Dp;
  float v = 0.f;
  if (blk < 5 && d < Dreal) v = W[(size_t)(blk * Dreal + d) * dout + o];
  u16 h, l; split2(v, h, l);
  Wth[idx] = h; Wtl[idx] = l;
}

// Merged prep: writes Yc0 (c-major, packed 4-wide) AND h block0 (nb-major).
__global__ __launch_bounds__(256) void k_prep(const float* __restrict__ inp, int indim,
        const float* __restrict__ st, const float* __restrict__ ru_,
        u16* __restrict__ ych, u16* __restrict__ ycl,
        u16* __restrict__ hh, u16* __restrict__ hl, int Dp, int KTa) {
  int c = blockIdx.x;
  int n0 = threadIdx.x << 2;
  int b = c / Dp, d = c - b * Dp;
  u16 h4[4], l4[4];
  #pragma unroll
  for (int r = 0; r < 4; r++) {
    int nb = ((n0 + r) << 4) + b;
    float v = 0.f;
    if (d < indim) v = inp[(size_t)nb * indim + d];
    else if (d < indim + HH) {
      v = st[(size_t)nb * HH + (d - indim)];
      if (ru_) v *= ru_[(size_t)nb * 128 + (d - indim)];
    }
    split2(v, h4[r], l4[r]);
    hh[(size_t)nb * KTa + d] = h4[r];
    hl[(size_t)nb * KTa + d] = l4[r];
  }
  uint2 ph, pl;
  ph.x = (u32)h4[0] | ((u32)h4[1] << 16); ph.y = (u32)h4[2] | ((u32)h4[3] << 16);
  pl.x = (u32)l4[0] | ((u32)l4[1] << 16); pl.y = (u32)l4[2] | ((u32)l4[3] << 16);
  *(uint2*)&ych[(size_t)c * NN + n0] = ph;
  *(uint2*)&ycl[(size_t)c * NN + n0] = pl;
}

// Diffusion GEMM, 8 waves, tile BM(c) x 128(m), BK=32, 3-term split, swizzled LDS.
template<int BM>
__global__ __launch_bounds__(512) void k_diffuse(
    const u16* __restrict__ Ah, const u16* __restrict__ Al, size_t zstrA,
    const u16* __restrict__ Sh, const u16* __restrict__ Sl,
    u16* __restrict__ Ych, u16* __restrict__ Ycl, size_t zstrYc, int hasYc,
    u16* __restrict__ hh, u16* __restrict__ hl,
    int blkoff0, int blkoff1, int Dp, int KTa)
{
  constexpr int FM = BM / 32;
  __shared__ __attribute__((aligned(16))) u16 lAh[BM * 32];
  __shared__ __attribute__((aligned(16))) u16 lAl[BM * 32];
  __shared__ __attribute__((aligned(16))) u16 lBh[128 * 32];
  __shared__ __attribute__((aligned(16))) u16 lBl[128 * 32];
  const int tid = threadIdx.x;
  const int lane = tid & 63, wave = tid >> 6;
  const int z = blockIdx.z;
  const u16* A_h = Ah + (size_t)z * zstrA;
  const u16* A_l = Al + (size_t)z * zstrA;
  const u16* B_h = Sh + (size_t)z * (NN * NN);
  const u16* B_l = Sl + (size_t)z * (NN * NN);
  const int a0 = blockIdx.x * BM;
  const int b0 = blockIdx.y << 7;
  const int wc0 = (wave & 1) * (BM / 2);
  const int wm0 = (wave >> 1) << 5;
  const int gw = lane >> 4;           // k-chunk this lane reads
  const int rsel = lane & 15;

  // stage-side inverse mapping (loop-invariant per thread)
  const int sA = (BM == 128) ? tid : (tid & 255);
  const int rpA = sA >> 3, jxA = (sA & 7) ^ (rpA & 7);
  const int rowA = (rpA << 1) | (jxA >> 2), gAc = jxA & 3;
  const int sB = tid;
  const int rpB = sB >> 3, jxB = (sB & 7) ^ (rpB & 7);
  const int rowB = (rpB << 1) | (jxB >> 2), gBc = jxB & 3;

  f32x4 acc[FM][2];
  #pragma unroll
  for (int i = 0; i < FM; i++)
    #pragma unroll
    for (int j = 0; j < 2; j++) acc[i][j] = (f32x4){0.f, 0.f, 0.f, 0.f};

  for (int k0 = 0; k0 < NN; k0 += 32) {
    if (BM == 128) {
      gload16(A_h + (size_t)(a0 + rowA) * NN + k0 + gAc * 8, &lAh[sA * 8]);
      gload16(A_l + (size_t)(a0 + rowA) * NN + k0 + gAc * 8, &lAl[sA * 8]);
      gload16(B_h + (size_t)(b0 + rowB) * NN + k0 + gBc * 8, &lBh[sB * 8]);
      gload16(B_l + (size_t)(b0 + rowB) * NN + k0 + gBc * 8, &lBl[sB * 8]);
    } else {
      if (tid < 256) gload16(A_h + (size_t)(a0 + rowA) * NN + k0 + gAc * 8, &lAh[sA * 8]);
      else           gload16(A_l + (size_t)(a0 + rowA) * NN + k0 + gAc * 8, &lAl[sA * 8]);
      gload16(B_h + (size_t)(b0 + rowB) * NN + k0 + gBc * 8, &lBh[sB * 8]);
      gload16(B_l + (size_t)(b0 + rowB) * NN + k0 + gBc * 8, &lBl[sB * 8]);
    }
    __syncthreads();
    sv8 vah[FM], vaL[FM], vbh[2], vbL[2];
    #pragma unroll
    for (int f = 0; f < FM; f++) {
      int off = swz(wc0 + f * 16 + rsel, gw) * 8;
      vah[f] = *(const sv8*)&lAh[off];
      vaL[f] = *(const sv8*)&lAl[off];
    }
    #pragma unroll
    for (int f = 0; f < 2; f++) {
      int off = swz(wm0 + f * 16 + rsel, gw) * 8;
      vbh[f] = *(const sv8*)&lBh[off];
      vbL[f] = *(const sv8*)&lBl[off];
    }
    #pragma unroll
    for (int fm = 0; fm < FM; fm++)
      #pragma unroll
      for (int fn = 0; fn < 2; fn++) {
        acc[fm][fn] = __builtin_amdgcn_mfma_f32_16x16x32_bf16(vah[fm], vbh[fn], acc[fm][fn], 0, 0, 0);
        acc[fm][fn] = __builtin_amdgcn_mfma_f32_16x16x32_bf16(vah[fm], vbL[fn], acc[fm][fn], 0, 0, 0);
        acc[fm][fn] = __builtin_amdgcn_mfma_f32_16x16x32_bf16(vaL[fm], vbh[fn], acc[fm][fn], 0, 0, 0);
      }
    __syncthreads();
  }

  u16* yh = Ych + (size_t)z * zstrYc;
  u16* yl = Ycl + (size_t)z * zstrYc;
  const int blkoff = z ? blkoff1 : blkoff0;
  #pragma unroll
  for (int fm = 0; fm < FM; fm++) {
    int cgbase = a0 + wc0 + fm * 16 + ((lane >> 4) << 2);
    int bq = cgbase / Dp, dq = cgbase - bq * Dp;   // 4-aligned, same b for r=0..3
    #pragma unroll
    for (int fn = 0; fn < 2; fn++) {
      int mg = b0 + wm0 + fn * 16 + rsel;
      u16 hi4[4], lo4[4];
      #pragma unroll
      for (int r = 0; r < 4; r++) {
        split2(acc[fm][fn][r], hi4[r], lo4[r]);
        if (hasYc) {
          yh[(size_t)(cgbase + r) * NN + mg] = hi4[r];
          yl[(size_t)(cgbase + r) * NN + mg] = lo4[r];
        }
      }
      size_t hidx = (size_t)((mg << 4) + bq) * KTa + blkoff + dq;
      uint2 ph, pl;
      ph.x = (u32)hi4[0] | ((u32)hi4[1] << 16); ph.y = (u32)hi4[2] | ((u32)hi4[3] << 16);
      pl.x = (u32)lo4[0] | ((u32)lo4[1] << 16); pl.y = (u32)lo4[2] | ((u32)lo4[3] << 16);
      *(uint2*)&hh[hidx] = ph;
      *(uint2*)&hl[hidx] = pl;
    }
  }
}

// Projection GEMM: out[nb][o] = act(sum_k h[nb][k] * Wt[o][k] + bias). Swizzled LDS.
// BM=64 rows; BN=128 -> 512 thr (8 waves, 2x4); BN=64 -> 256 thr (4 waves, 2x2).
template<int BN>
__global__ __launch_bounds__(BN * 4) void k_gemm3(
    const u16* __restrict__ Ah_g, const u16* __restrict__ Al_g, int KTa,
    const u16* __restrict__ Bh_g, const u16* __restrict__ Bl_g,
    const float* __restrict__ bias, int mode,
    const float* __restrict__ rubuf, float* __restrict__ outp)
{
  __shared__ __attribute__((aligned(16))) u16 lAh[64 * 32];
  __shared__ __attribute__((aligned(16))) u16 lAl[64 * 32];
  __shared__ __attribute__((aligned(16))) u16 lBh[BN * 32];
  __shared__ __attribute__((aligned(16))) u16 lBl[BN * 32];
  const int tid = threadIdx.x;
  const int lane = tid & 63, wave = tid >> 6;
  const int a0 = blockIdx.x << 6;
  const int wr0 = (wave & 1) << 5;
  const int wn0 = (wave >> 1) << 5;
  const int gw = lane >> 4;
  const int rsel = lane & 15;

  const int sA = (BN == 128) ? (tid & 255) : tid;
  const int rpA = sA >> 3, jxA = (sA & 7) ^ (rpA & 7);
  const int rowA = (rpA << 1) | (jxA >> 2), gAc = jxA & 3;
  const int sB = tid;
  const int rpB = sB >> 3, jxB = (sB & 7) ^ (rpB & 7);
  const int rowB = (rpB << 1) | (jxB >> 2), gBc = jxB & 3;

  f32x4 acc[2][2];
  #pragma unroll
  for (int i = 0; i < 2; i++)
    #pragma unroll
    for (int j = 0; j < 2; j++) acc[i][j] = (f32x4){0.f, 0.f, 0.f, 0.f};

  for (int k0 = 0; k0 < KTa; k0 += 32) {
    if (BN == 128) {
      if (tid < 256) gload16(Ah_g + (size_t)(a0 + rowA) * KTa + k0 + gAc * 8, &lAh[sA * 8]);
      else           gload16(Al_g + (size_t)(a0 + rowA) * KTa + k0 + gAc * 8, &lAl[sA * 8]);
      gload16(Bh_g + (size_t)rowB * KTa + k0 + gBc * 8, &lBh[sB * 8]);
      gload16(Bl_g + (size_t)rowB * KTa + k0 + gBc * 8, &lBl[sB * 8]);
    } else {
      gload16(Ah_g + (size_t)(a0 + rowA) * KTa + k0 + gAc * 8, &lAh[sA * 8]);
      gload16(Al_g + (size_t)(a0 + rowA) * KTa + k0 + gAc * 8, &lAl[sA * 8]);
      gload16(Bh_g + (size_t)rowB * KTa + k0 + gBc * 8, &lBh[sB * 8]);
      gload16(Bl_g + (size_t)rowB * KTa + k0 + gBc * 8, &lBl[sB * 8]);
    }
    __syncthreads();
    sv8 vah[2], vaL[2], vbh[2], vbL[2];
    #pragma unroll
    for (int f = 0; f < 2; f++) {
      int offa = swz(wr0 + f * 16 + rsel, gw) * 8;
      vah[f] = *(const sv8*)&lAh[offa];
      vaL[f] = *(const sv8*)&lAl[offa];
      int offb = swz(wn0 + f * 16 + rsel, gw) * 8;
      vbh[f] = *(const sv8*)&lBh[offb];
      vbL[f] = *(const sv8*)&lBl[offb];
    }
    #pragma unroll
    for (int fm = 0; fm < 2; fm++)
      #pragma unroll
      for (int fn = 0; fn < 2; fn++) {
        acc[fm][fn] = __builtin_amdgcn_mfma_f32_16x16x32_bf16(vah[fm], vbh[fn], acc[fm][fn], 0, 0, 0);
        acc[fm][fn] = __builtin_amdgcn_mfma_f32_16x16x32_bf16(vah[fm], vbL[fn], acc[fm][fn], 0, 0, 0);
        acc[fm][fn] = __builtin_amdgcn_mfma_f32_16x16x32_bf16(vaL[fm], vbh[fn], acc[fm][fn], 0, 0, 0);
      }
    __syncthreads();
  }

  #pragma unroll
  for (int fm = 0; fm < 2; fm++) {
    #pragma unroll
    for (int r = 0; r < 4; r++) {
      int nb = a0 + wr0 + fm * 16 + ((lane >> 4) << 2) + r;
      #pragma unroll
      for (int fn = 0; fn < 2; fn++) {
        int o = wn0 + fn * 16 + rsel;
        float v = acc[fm][fn][r] + bias[o];
        if (mode == 0) {
          outp[(size_t)nb * 128 + o] = 1.f / (1.f + expf(-v));
        } else {
          float u = rubuf[(size_t)nb * 128 + 64 + o];
          float sold = outp[(size_t)nb * HH + o];
          outp[(size_t)nb * HH + o] = u * sold + (1.f - u) * tanhf(v);
        }
      }
    }
  }
}

// out_t[n,b] = st1[nb,:] @ outW + outb ; write d_out[b, t, n] and dec_in[nb]
__global__ __launch_bounds__(256) void k_proj(const float* __restrict__ st1,
        const float* __restrict__ ow, const float* __restrict__ ob,
        float* __restrict__ outg, float* __restrict__ dec_in, int t) {
  int nb = blockIdx.x * 256 + threadIdx.x;
  if (nb >= NB) return;
  float acc = ob[0];
  #pragma unroll
  for (int h = 0; h < HH; h++) acc += st1[(size_t)nb * HH + h] * ow[h];
  int n = nb >> 4, b = nb & 15;
  outg[((size_t)b * TT + t) * NN + n] = acc;
  dec_in[nb] = acc;
}

extern "C" void kernel_launch(void* const* d_in, const int* in_sizes, int n_in,
                              void* d_out, int out_size, void* d_ws, size_t ws_size,
                              hipStream_t stream) {
  const float* inputs   = (const float*)d_in[0];
  const float* supports = (const float*)d_in[1];
  const float* Wsrc[8] = {(const float*)d_in[2], (const float*)d_in[4],
                          (const float*)d_in[6], (const float*)d_in[8],
                          (const float*)d_in[10], (const float*)d_in[12],
                          (const float*)d_in[14], (const float*)d_in[16]};
  const float* bias[8] = {(const float*)d_in[3], (const float*)d_in[5],
                          (const float*)d_in[7], (const float*)d_in[9],
                          (const float*)d_in[11], (const float*)d_in[13],
                          (const float*)d_in[15], (const float*)d_in[17]};
  const float* outW = (const float*)d_in[18];
  const float* outB = (const float*)d_in[19];
  float* out = (float*)d_out;

  char* cur = (char*)d_ws;
  auto alloc = [&](size_t bytes) -> char* {
    char* p = cur; cur += (bytes + 255) & ~(size_t)255; return p;
  };
  u16* Sh   = (u16*)alloc((size_t)2 * NN * NN * 2);
  u16* Sl   = (u16*)alloc((size_t)2 * NN * NN * 2);
  u16* Yc0h = (u16*)alloc((size_t)2048 * NN * 2);
  u16* Yc0l = (u16*)alloc((size_t)2048 * NN * 2);
  u16* Yc1h = (u16*)alloc((size_t)2 * 2048 * NN * 2);
  u16* Yc1l = (u16*)alloc((size_t)2 * 2048 * NN * 2);
  u16* hh   = (u16*)alloc((size_t)NB * 640 * 2);
  u16* hl   = (u16*)alloc((size_t)NB * 640 * 2);
  float* ru    = (float*)alloc((size_t)NB * 128 * 4);
  float* st0   = (float*)alloc((size_t)NB * HH * 4);
  float* st1   = (float*)alloc((size_t)NB * HH * 4);
  float* decin = (float*)alloc((size_t)NB * 4);
  float* xin   = (float*)alloc((size_t)TT * NB * 2 * 4);
  const int wDout[8] = {128, 64, 128, 64, 128, 64, 128, 64};
  const int wKTa[8]  = {384, 384, 640, 640, 384, 384, 640, 640};
  const int wDreal[8]= {66, 66, 128, 128, 65, 65, 128, 128};
  const int wDp[8]   = {72, 72, 128, 128, 72, 72, 128, 128};
  u16 *Wth[8], *Wtl[8];
  for (int i = 0; i < 8; i++) {
    Wth[i] = (u16*)alloc((size_t)wDout[i] * wKTa[i] * 2);
    Wtl[i] = (u16*)alloc((size_t)wDout[i] * wKTa[i] * 2);
  }

  auto blocks = [](int n) { return (n + 255) / 256; };
  k_zero<<<blocks(NB * HH), 256, 0, stream>>>(st0, NB * HH);
  k_zero<<<blocks(NB * HH), 256, 0, stream>>>(st1, NB * HH);
  k_zero<<<blocks(NB), 256, 0, stream>>>(decin, NB);
  k_transpose_in<<<blocks(BB * TT * NN * 2), 256, 0, stream>>>(inputs, xin);
  k_splitS<<<blocks(2 * NN * NN), 256, 0, stream>>>(supports, Sh, Sl);
  for (int i = 0; i < 8; i++)
    k_padWt<<<blocks(wDout[i] * wKTa[i]), 256, 0, stream>>>(
        Wsrc[i], Wth[i], Wtl[i], wDreal[i], wDp[i], wKTa[i], wDout[i]);

  auto conv = [&](const float* inp, int indim, float* st, int wi, bool cand) {
    int Dp = wDp[wi], KTa = wKTa[wi];
    int CB = BB * Dp;                 // 1152 or 2048
    const float* ruptr = cand ? ru : nullptr;
    k_prep<<<CB, 256, 0, stream>>>(inp, indim, st, ruptr, Yc0h, Yc0l, hh, hl, Dp, KTa);
    size_t zy = (size_t)CB * NN;
    if (Dp == 128) {
      dim3 g(CB / 128, 8, 2);
      k_diffuse<128><<<g, 512, 0, stream>>>(Yc0h, Yc0l, 0, Sh, Sl,
                                            Yc1h, Yc1l, zy, 1, hh, hl,
                                            1 * Dp, 3 * Dp, Dp, KTa);
      k_diffuse<128><<<g, 512, 0, stream>>>(Yc1h, Yc1l, zy, Sh, Sl,
                                            Yc1h, Yc1l, 0, 0, hh, hl,
                                            2 * Dp, 4 * Dp, Dp, KTa);
    } else {
      dim3 g(CB / 64, 8, 2);
      k_diffuse<64><<<g, 512, 0, stream>>>(Yc0h, Yc0l, 0, Sh, Sl,
                                           Yc1h, Yc1l, zy, 1, hh, hl,
                                           1 * Dp, 3 * Dp, Dp, KTa);
      k_diffuse<64><<<g, 512, 0, stream>>>(Yc1h, Yc1l, zy, Sh, Sl,
                                           Yc1h, Yc1l, 0, 0, hh, hl,
                                           2 * Dp, 4 * Dp, Dp, KTa);
    }
    int wsel = cand ? wi + 1 : wi;
    if (!cand)
      k_gemm3<128><<<NB / 64, 512, 0, stream>>>(
          hh, hl, KTa, Wth[wsel], Wtl[wsel], bias[wsel], 0, nullptr, ru);
    else
      k_gemm3<64><<<NB / 64, 256, 0, stream>>>(
          hh, hl, KTa, Wth[wsel], Wtl[wsel], bias[wsel], 1, ru, st);
  };
  auto cell = [&](const float* inp, int indim, float* st, int wi) {
    conv(inp, indim, st, wi, false);
    conv(inp, indim, st, wi, true);
  };

  for (int t = 0; t < TT; t++) {
    cell(xin + (size_t)t * NB * 2, 2, st0, 0);
    cell(st0, 64, st1, 2);
  }
  for (int t = 0; t < TT; t++) {
    cell(decin, 1, st0, 4);
    cell(st0, 64, st1, 6);
    k_proj<<<blocks(NB), 256, 0, stream>>>(st1, outW, outB, out, decin, t);
  }
}

// Round 5
// 11316.053 us; speedup vs baseline: 2.2718x; 1.1034x over previous
//
#include <hip/hip_runtime.h>
#include <math.h>

// DCRNN on MI355X — round 5: S^2 precompute (4-way z-batched single diffuse
// launch per conv), 32x32x16 MFMA with 64x64 wave tiles (4 waves, 128x128 block),
// double-buffered LDS with prefetch-before-compute + single barrier per K-step.
// 3-term bf16 hi/lo split math unchanged. gemm3/prep/proj kept from R4.

#define NN 1024
#define BB 16
#define TT 12
#define HH 64
#define NB (NN*BB)      // 16384

typedef unsigned short u16;
typedef unsigned int u32;
typedef __attribute__((ext_vector_type(8))) short sv8;
typedef __attribute__((ext_vector_type(4))) float f32x4;
typedef __attribute__((ext_vector_type(16))) float f32x16;

__device__ __forceinline__ void gload16(const void* g, void* l) {
  __builtin_amdgcn_global_load_lds(
      (const __attribute__((address_space(1))) void*)(unsigned long long)(g),
      (__attribute__((address_space(3))) void*)(l), 16, 0, 0);
}

// 16-byte-slot index of (row, g) in a swizzled tile buffer (R4-verified bijection).
__device__ __forceinline__ int swz(int row, int g) {
  int rp = row >> 1;
  int j = ((row & 1) << 2) | g;
  return (rp << 3) | (j ^ (rp & 7));
}

__device__ __forceinline__ u16 bf16_rne(float x) {
  u32 u = __float_as_uint(x);
  u32 r = (u + 0x7FFFu + ((u >> 16) & 1u)) >> 16;
  return (u16)r;
}
__device__ __forceinline__ void split2(float x, u16& h, u16& l) {
  h = bf16_rne(x);
  float hf = __uint_as_float(((u32)h) << 16);
  l = bf16_rne(x - hf);
}

__global__ __launch_bounds__(256) void k_zero(float* p, int n) {
  int i = blockIdx.x * 256 + threadIdx.x;
  if (i < n) p[i] = 0.f;
}

// inputs (B,T,N,2) -> xin (T, N, B, 2)
__global__ __launch_bounds__(256) void k_transpose_in(const float* __restrict__ in,
                                                      float* __restrict__ xt) {
  int idx = blockIdx.x * 256 + threadIdx.x;
  if (idx >= BB * TT * NN * 2) return;
  int i = idx & 1;
  int n = (idx >> 1) & (NN - 1);
  int bt = idx >> 11;
  int t = bt % TT, b = bt / TT;
  xt[(size_t)t * (NB * 2) + (size_t)(n * BB + b) * 2 + i] = in[idx];
}

// supports f32 -> hi/lo bf16 (slots z=0,1 of S arrays)
__global__ __launch_bounds__(256) void k_splitS(const float* __restrict__ s,
                                                u16* __restrict__ sh, u16* __restrict__ sl) {
  int idx = blockIdx.x * 256 + threadIdx.x;
  if (idx >= 2 * NN * NN) return;
  u16 h, l; split2(s[idx], h, l);
  sh[idx] = h; sl[idx] = l;
}

// ST[z][k][j] = S[z][j][k]  (u16 hi/lo), coalesced writes
__global__ __launch_bounds__(256) void k_transpS(const u16* __restrict__ sh,
        const u16* __restrict__ sl, u16* __restrict__ sth, u16* __restrict__ stl) {
  int idx = blockIdx.x * 256 + threadIdx.x;
  if (idx >= 2 * NN * NN) return;
  int j = idx & (NN - 1);
  int k = (idx >> 10) & (NN - 1);
  int z = idx >> 20;
  size_t src = ((size_t)z << 20) | ((size_t)j << 10) | (size_t)k;
  sth[idx] = sh[src];
  stl[idx] = sl[src];
}

// W (5*Dreal, dout) -> Wt hi/lo [o][KTa], row kk = blk*Dp + d, zeros elsewhere
__global__ __launch_bounds__(256) void k_padWt(const float* __restrict__ W,
        u16* __restrict__ Wth, u16* __restrict__ Wtl,
        int Dreal, int Dp, int KTa, int dout) {
  int idx = blockIdx.x * 256 + threadIdx.x;
  if (idx >= dout * KTa) return;
  int kk = idx % KTa, o = idx / KTa;
  int blk = kk / Dp, d = kk - blk * Dp;
  float v = 0.f;
  if (blk < 5 && d < Dreal) v = W[(size_t)(blk * Dreal + d) * dout + o];
  u16 h, l; split2(v, h, l);
  Wth[idx] = h; Wtl[idx] = l;
}

// Merged prep: writes Yc0 (c-major, packed 4-wide) AND h block0 (nb-major).
__global__ __launch_bounds__(256) void k_prep(const float* __restrict__ inp, int indim,
        const float* __restrict__ st, const float* __restrict__ ru_,
        u16* __restrict__ ych, u16* __restrict__ ycl,
        u16* __restrict__ hh, u16* __restrict__ hl, int Dp, int KTa) {
  int c = blockIdx.x;
  int n0 = threadIdx.x << 2;
  int b = c / Dp, d = c - b * Dp;
  u16 h4[4], l4[4];
  #pragma unroll
  for (int r = 0; r < 4; r++) {
    int nb = ((n0 + r) << 4) + b;
    float v = 0.f;
    if (d < indim) v = inp[(size_t)nb * indim + d];
    else if (d < indim + HH) {
      v = st[(size_t)nb * HH + (d - indim)];
      if (ru_) v *= ru_[(size_t)nb * 128 + (d - indim)];
    }
    split2(v, h4[r], l4[r]);
    hh[(size_t)nb * KTa + d] = h4[r];
    hl[(size_t)nb * KTa + d] = l4[r];
  }
  uint2 ph, pl;
  ph.x = (u32)h4[0] | ((u32)h4[1] << 16); ph.y = (u32)h4[2] | ((u32)h4[3] << 16);
  pl.x = (u32)l4[0] | ((u32)l4[1] << 16); pl.y = (u32)l4[2] | ((u32)l4[3] << 16);
  *(uint2*)&ych[(size_t)c * NN + n0] = ph;
  *(uint2*)&ycl[(size_t)c * NN + n0] = pl;
}

// ---- shared staging helper geometry for 128x128 tiles, BK=32 ----
// slots: 512 per (matrix, hi/lo); thread t handles slots t and t+256.
struct StageMap {
  int row1, g1, row2, g2;
  __device__ StageMap(int tid) {
    int rp = tid >> 3, jx = (tid & 7) ^ (rp & 7);
    row1 = (rp << 1) | (jx >> 2); g1 = jx & 3;
    int s = tid + 256; rp = s >> 3; jx = (s & 7) ^ (rp & 7);
    row2 = (rp << 1) | (jx >> 2); g2 = jx & 3;
  }
};

// Ssq[z][m][k] = sum_j S[z][m][j] * ST[z][k][j]  (3-term split, f32 acc),
// output split2 into slots z+2 of Sh/Sl. 128x128 tiles, 4 waves, 32x32x16 MFMA.
__global__ __launch_bounds__(256) void k_sq(
    const u16* __restrict__ Sh, const u16* __restrict__ Sl,
    const u16* __restrict__ STh, const u16* __restrict__ STl,
    u16* __restrict__ Oh, u16* __restrict__ Ol)
{
  __shared__ __attribute__((aligned(16))) u16 lA[2][2][4096];
  __shared__ __attribute__((aligned(16))) u16 lB[2][2][4096];
  const int tid = threadIdx.x;
  const int lane = tid & 63, wave = tid >> 6;
  const int z = blockIdx.z;
  const int a0 = blockIdx.x << 7;
  const int b0 = blockIdx.y << 7;
  const int wc0 = (wave & 1) << 6;
  const int wn0 = (wave >> 1) << 6;
  StageMap sm(tid);
  const u16* pa1h = Sh + (size_t)z * NN * NN + (size_t)(a0 + sm.row1) * NN + sm.g1 * 8;
  const u16* pa2h = Sh + (size_t)z * NN * NN + (size_t)(a0 + sm.row2) * NN + sm.g2 * 8;
  const u16* pa1l = Sl + (size_t)z * NN * NN + (size_t)(a0 + sm.row1) * NN + sm.g1 * 8;
  const u16* pa2l = Sl + (size_t)z * NN * NN + (size_t)(a0 + sm.row2) * NN + sm.g2 * 8;
  const u16* pb1h = STh + (size_t)z * NN * NN + (size_t)(b0 + sm.row1) * NN + sm.g1 * 8;
  const u16* pb2h = STh + (size_t)z * NN * NN + (size_t)(b0 + sm.row2) * NN + sm.g2 * 8;
  const u16* pb1l = STl + (size_t)z * NN * NN + (size_t)(b0 + sm.row1) * NN + sm.g1 * 8;
  const u16* pb2l = STl + (size_t)z * NN * NN + (size_t)(b0 + sm.row2) * NN + sm.g2 * 8;

  f32x16 acc[2][2];
  #pragma unroll
  for (int i = 0; i < 2; i++)
    #pragma unroll
    for (int j = 0; j < 2; j++)
      #pragma unroll
      for (int e = 0; e < 16; e++) acc[i][j][e] = 0.f;

  auto stage = [&](int buf, int k0) {
    gload16(pa1h + k0, &lA[buf][0][tid * 8]);
    gload16(pa2h + k0, &lA[buf][0][tid * 8 + 2048]);
    gload16(pa1l + k0, &lA[buf][1][tid * 8]);
    gload16(pa2l + k0, &lA[buf][1][tid * 8 + 2048]);
    gload16(pb1h + k0, &lB[buf][0][tid * 8]);
    gload16(pb2h + k0, &lB[buf][0][tid * 8 + 2048]);
    gload16(pb1l + k0, &lB[buf][1][tid * 8]);
    gload16(pb2l + k0, &lB[buf][1][tid * 8 + 2048]);
  };

  stage(0, 0);
  __syncthreads();
  int cur = 0;
  for (int kt = 0; kt < 32; kt++) {
    if (kt < 31) stage(cur ^ 1, (kt + 1) * 32);
    #pragma unroll
    for (int kh = 0; kh < 2; kh++) {
      sv8 vah[2], vaL[2], vbh[2], vbL[2];
      int gsel = (kh << 1) | (lane >> 5);
      #pragma unroll
      for (int f = 0; f < 2; f++) {
        int offa = swz(wc0 + f * 32 + (lane & 31), gsel) * 8;
        vah[f] = *(const sv8*)&lA[cur][0][offa];
        vaL[f] = *(const sv8*)&lA[cur][1][offa];
        int offb = swz(wn0 + f * 32 + (lane & 31), gsel) * 8;
        vbh[f] = *(const sv8*)&lB[cur][0][offb];
        vbL[f] = *(const sv8*)&lB[cur][1][offb];
      }
      #pragma unroll
      for (int fm = 0; fm < 2; fm++)
        #pragma unroll
        for (int fn = 0; fn < 2; fn++) {
          acc[fm][fn] = __builtin_amdgcn_mfma_f32_32x32x16_bf16(vah[fm], vbh[fn], acc[fm][fn], 0, 0, 0);
          acc[fm][fn] = __builtin_amdgcn_mfma_f32_32x32x16_bf16(vah[fm], vbL[fn], acc[fm][fn], 0, 0, 0);
          acc[fm][fn] = __builtin_amdgcn_mfma_f32_32x32x16_bf16(vaL[fm], vbh[fn], acc[fm][fn], 0, 0, 0);
        }
    }
    __syncthreads();
    cur ^= 1;
  }

  u16* oh = Oh + (size_t)z * NN * NN;
  u16* ol = Ol + (size_t)z * NN * NN;
  #pragma unroll
  for (int fm = 0; fm < 2; fm++)
    #pragma unroll
    for (int q = 0; q < 4; q++) {
      int m4 = a0 + wc0 + fm * 32 + q * 8 + ((lane >> 5) << 2);
      #pragma unroll
      for (int fn = 0; fn < 2; fn++) {
        int kc = b0 + wn0 + fn * 32 + (lane & 31);
        #pragma unroll
        for (int r = 0; r < 4; r++) {
          u16 hi, lo; split2(acc[fm][fn][q * 4 + r], hi, lo);
          oh[(size_t)(m4 + r) * NN + kc] = hi;
          ol[(size_t)(m4 + r) * NN + kc] = lo;
        }
      }
    }
}

// Diffusion: C^T[c][m] = sum_k Yc[c][k] * Sz[m][k] for z in {S0,S1,S0^2,S1^2};
// writes nb-major h at block 1+((z&1)<<1)+(z>>1). 128x128 tile, 4 waves 2x2,
// 64x64 wave tiles, 32x32x16 MFMA, 3-term split, dbuf prefetch single-barrier.
template<int DP, int KTA>
__global__ __launch_bounds__(256) void k_diffuse2(
    const u16* __restrict__ Ah, const u16* __restrict__ Al,
    const u16* __restrict__ Sh, const u16* __restrict__ Sl,
    u16* __restrict__ hh, u16* __restrict__ hl)
{
  __shared__ __attribute__((aligned(16))) u16 lA[2][2][4096];
  __shared__ __attribute__((aligned(16))) u16 lB[2][2][4096];
  const int tid = threadIdx.x;
  const int lane = tid & 63, wave = tid >> 6;
  const int z = blockIdx.z;
  const int a0 = blockIdx.x << 7;
  const int b0 = blockIdx.y << 7;
  const int wc0 = (wave & 1) << 6;
  const int wn0 = (wave >> 1) << 6;
  StageMap sm(tid);
  const u16* pa1h = Ah + (size_t)(a0 + sm.row1) * NN + sm.g1 * 8;
  const u16* pa2h = Ah + (size_t)(a0 + sm.row2) * NN + sm.g2 * 8;
  const u16* pa1l = Al + (size_t)(a0 + sm.row1) * NN + sm.g1 * 8;
  const u16* pa2l = Al + (size_t)(a0 + sm.row2) * NN + sm.g2 * 8;
  const u16* pb1h = Sh + (size_t)z * NN * NN + (size_t)(b0 + sm.row1) * NN + sm.g1 * 8;
  const u16* pb2h = Sh + (size_t)z * NN * NN + (size_t)(b0 + sm.row2) * NN + sm.g2 * 8;
  const u16* pb1l = Sl + (size_t)z * NN * NN + (size_t)(b0 + sm.row1) * NN + sm.g1 * 8;
  const u16* pb2l = Sl + (size_t)z * NN * NN + (size_t)(b0 + sm.row2) * NN + sm.g2 * 8;

  f32x16 acc[2][2];
  #pragma unroll
  for (int i = 0; i < 2; i++)
    #pragma unroll
    for (int j = 0; j < 2; j++)
      #pragma unroll
      for (int e = 0; e < 16; e++) acc[i][j][e] = 0.f;

  auto stage = [&](int buf, int k0) {
    gload16(pa1h + k0, &lA[buf][0][tid * 8]);
    gload16(pa2h + k0, &lA[buf][0][tid * 8 + 2048]);
    gload16(pa1l + k0, &lA[buf][1][tid * 8]);
    gload16(pa2l + k0, &lA[buf][1][tid * 8 + 2048]);
    gload16(pb1h + k0, &lB[buf][0][tid * 8]);
    gload16(pb2h + k0, &lB[buf][0][tid * 8 + 2048]);
    gload16(pb1l + k0, &lB[buf][1][tid * 8]);
    gload16(pb2l + k0, &lB[buf][1][tid * 8 + 2048]);
  };

  stage(0, 0);
  __syncthreads();
  int cur = 0;
  for (int kt = 0; kt < 32; kt++) {
    if (kt < 31) stage(cur ^ 1, (kt + 1) * 32);
    #pragma unroll
    for (int kh = 0; kh < 2; kh++) {
      sv8 vah[2], vaL[2], vbh[2], vbL[2];
      int gsel = (kh << 1) | (lane >> 5);
      #pragma unroll
      for (int f = 0; f < 2; f++) {
        int offa = swz(wc0 + f * 32 + (lane & 31), gsel) * 8;
        vah[f] = *(const sv8*)&lA[cur][0][offa];
        vaL[f] = *(const sv8*)&lA[cur][1][offa];
        int offb = swz(wn0 + f * 32 + (lane & 31), gsel) * 8;
        vbh[f] = *(const sv8*)&lB[cur][0][offb];
        vbL[f] = *(const sv8*)&lB[cur][1][offb];
      }
      #pragma unroll
      for (int fm = 0; fm < 2; fm++)
        #pragma unroll
        for (int fn = 0; fn < 2; fn++) {
          acc[fm][fn] = __builtin_amdgcn_mfma_f32_32x32x16_bf16(vah[fm], vbh[fn], acc[fm][fn], 0, 0, 0);
          acc[fm][fn] = __builtin_amdgcn_mfma_f32_32x32x16_bf16(vah[fm], vbL[fn], acc[fm][fn], 0, 0, 0);
          acc[fm][fn] = __builtin_amdgcn_mfma_f32_32x32x16_bf16(vaL[fm], vbh[fn], acc[fm][fn], 0, 0, 0);
        }
    }
    __syncthreads();
    cur ^= 1;
  }

  const int blkoff = (1 + ((z & 1) << 1) + (z >> 1)) * DP;
  #pragma unroll
  for (int fm = 0; fm < 2; fm++)
    #pragma unroll
    for (int q = 0; q < 4; q++) {
      int cg4 = a0 + wc0 + fm * 32 + q * 8 + ((lane >> 5) << 2);
      int bq = cg4 / DP, dq = cg4 - bq * DP;
      #pragma unroll
      for (int fn = 0; fn < 2; fn++) {
        int mg = b0 + wn0 + fn * 32 + (lane & 31);
        u16 hi4[4], lo4[4];
        #pragma unroll
        for (int r = 0; r < 4; r++)
          split2(acc[fm][fn][q * 4 + r], hi4[r], lo4[r]);
        size_t hidx = (size_t)((mg << 4) + bq) * KTA + blkoff + dq;
        uint2 ph, pl;
        ph.x = (u32)hi4[0] | ((u32)hi4[1] << 16); ph.y = (u32)hi4[2] | ((u32)hi4[3] << 16);
        pl.x = (u32)lo4[0] | ((u32)lo4[1] << 16); pl.y = (u32)lo4[2] | ((u32)lo4[3] << 16);
        *(uint2*)&hh[hidx] = ph;
        *(uint2*)&hl[hidx] = pl;
      }
    }
}

// Projection GEMM (R4, unchanged): out[nb][o] = act(sum_k h[nb][k]*Wt[o][k]+bias).
template<int BN>
__global__ __launch_bounds__(BN * 4) void k_gemm3(
    const u16* __restrict__ Ah_g, const u16* __restrict__ Al_g, int KTa,
    const u16* __restrict__ Bh_g, const u16* __restrict__ Bl_g,
    const float* __restrict__ bias, int mode,
    const float* __restrict__ rubuf, float* __restrict__ outp)
{
  __shared__ __attribute__((aligned(16))) u16 lAh[64 * 32];
  __shared__ __attribute__((aligned(16))) u16 lAl[64 * 32];
  __shared__ __attribute__((aligned(16))) u16 lBh[BN * 32];
  __shared__ __attribute__((aligned(16))) u16 lBl[BN * 32];
  const int tid = threadIdx.x;
  const int lane = tid & 63, wave = tid >> 6;
  const int a0 = blockIdx.x << 6;
  const int wr0 = (wave & 1) << 5;
  const int wn0 = (wave >> 1) << 5;
  const int gw = lane >> 4;
  const int rsel = lane & 15;

  const int sA = (BN == 128) ? (tid & 255) : tid;
  const int rpA = sA >> 3, jxA = (sA & 7) ^ (rpA & 7);
  const int rowA = (rpA << 1) | (jxA >> 2), gAc = jxA & 3;
  const int sB = tid;
  const int rpB = sB >> 3, jxB = (sB & 7) ^ (rpB & 7);
  const int rowB = (rpB << 1) | (jxB >> 2), gBc = jxB & 3;

  f32x4 acc[2][2];
  #pragma unroll
  for (int i = 0; i < 2; i++)
    #pragma unroll
    for (int j = 0; j < 2; j++) acc[i][j] = (f32x4){0.f, 0.f, 0.f, 0.f};

  for (int k0 = 0; k0 < KTa; k0 += 32) {
    if (BN == 128) {
      if (tid < 256) gload16(Ah_g + (size_t)(a0 + rowA) * KTa + k0 + gAc * 8, &lAh[sA * 8]);
      else           gload16(Al_g + (size_t)(a0 + rowA) * KTa + k0 + gAc * 8, &lAl[sA * 8]);
      gload16(Bh_g + (size_t)rowB * KTa + k0 + gBc * 8, &lBh[sB * 8]);
      gload16(Bl_g + (size_t)rowB * KTa + k0 + gBc * 8, &lBl[sB * 8]);
    } else {
      gload16(Ah_g + (size_t)(a0 + rowA) * KTa + k0 + gAc * 8, &lAh[sA * 8]);
      gload16(Al_g + (size_t)(a0 + rowA) * KTa + k0 + gAc * 8, &lAl[sA * 8]);
      gload16(Bh_g + (size_t)rowB * KTa + k0 + gBc * 8, &lBh[sB * 8]);
      gload16(Bl_g + (size_t)rowB * KTa + k0 + gBc * 8, &lBl[sB * 8]);
    }
    __syncthreads();
    sv8 vah[2], vaL[2], vbh[2], vbL[2];
    #pragma unroll
    for (int f = 0; f < 2; f++) {
      int offa = swz(wr0 + f * 16 + rsel, gw) * 8;
      vah[f] = *(const sv8*)&lAh[offa];
      vaL[f] = *(const sv8*)&lAl[offa];
      int offb = swz(wn0 + f * 16 + rsel, gw) * 8;
      vbh[f] = *(const sv8*)&lBh[offb];
      vbL[f] = *(const sv8*)&lBl[offb];
    }
    #pragma unroll
    for (int fm = 0; fm < 2; fm++)
      #pragma unroll
      for (int fn = 0; fn < 2; fn++) {
        acc[fm][fn] = __builtin_amdgcn_mfma_f32_16x16x32_bf16(vah[fm], vbh[fn], acc[fm][fn], 0, 0, 0);
        acc[fm][fn] = __builtin_amdgcn_mfma_f32_16x16x32_bf16(vah[fm], vbL[fn], acc[fm][fn], 0, 0, 0);
        acc[fm][fn] = __builtin_amdgcn_mfma_f32_16x16x32_bf16(vaL[fm], vbh[fn], acc[fm][fn], 0, 0, 0);
      }
    __syncthreads();
  }

  #pragma unroll
  for (int fm = 0; fm < 2; fm++) {
    #pragma unroll
    for (int r = 0; r < 4; r++) {
      int nb = a0 + wr0 + fm * 16 + ((lane >> 4) << 2) + r;
      #pragma unroll
      for (int fn = 0; fn < 2; fn++) {
        int o = wn0 + fn * 16 + rsel;
        float v = acc[fm][fn][r] + bias[o];
        if (mode == 0) {
          outp[(size_t)nb * 128 + o] = 1.f / (1.f + expf(-v));
        } else {
          float u = rubuf[(size_t)nb * 128 + 64 + o];
          float sold = outp[(size_t)nb * HH + o];
          outp[(size_t)nb * HH + o] = u * sold + (1.f - u) * tanhf(v);
        }
      }
    }
  }
}

// out_t[n,b] = st1[nb,:] @ outW + outb ; write d_out[b, t, n] and dec_in[nb]
__global__ __launch_bounds__(256) void k_proj(const float* __restrict__ st1,
        const float* __restrict__ ow, const float* __restrict__ ob,
        float* __restrict__ outg, float* __restrict__ dec_in, int t) {
  int nb = blockIdx.x * 256 + threadIdx.x;
  if (nb >= NB) return;
  float acc = ob[0];
  #pragma unroll
  for (int h = 0; h < HH; h++) acc += st1[(size_t)nb * HH + h] * ow[h];
  int n = nb >> 4, b = nb & 15;
  outg[((size_t)b * TT + t) * NN + n] = acc;
  dec_in[nb] = acc;
}

extern "C" void kernel_launch(void* const* d_in, const int* in_sizes, int n_in,
                              void* d_out, int out_size, void* d_ws, size_t ws_size,
                              hipStream_t stream) {
  const float* inputs   = (const float*)d_in[0];
  const float* supports = (const float*)d_in[1];
  const float* Wsrc[8] = {(const float*)d_in[2], (const float*)d_in[4],
                          (const float*)d_in[6], (const float*)d_in[8],
                          (const float*)d_in[10], (const float*)d_in[12],
                          (const float*)d_in[14], (const float*)d_in[16]};
  const float* bias[8] = {(const float*)d_in[3], (const float*)d_in[5],
                          (const float*)d_in[7], (const float*)d_in[9],
                          (const float*)d_in[11], (const float*)d_in[13],
                          (const float*)d_in[15], (const float*)d_in[17]};
  const float* outW = (const float*)d_in[18];
  const float* outB = (const float*)d_in[19];
  float* out = (float*)d_out;

  char* cur = (char*)d_ws;
  auto alloc = [&](size_t bytes) -> char* {
    char* p = cur; cur += (bytes + 255) & ~(size_t)255; return p;
  };
  u16* Sh   = (u16*)alloc((size_t)4 * NN * NN * 2);   // S0,S1,S0^2,S1^2
  u16* Sl   = (u16*)alloc((size_t)4 * NN * NN * 2);
  u16* STh  = (u16*)alloc((size_t)2 * NN * NN * 2);
  u16* STl  = (u16*)alloc((size_t)2 * NN * NN * 2);
  u16* Yc0h = (u16*)alloc((size_t)2048 * NN * 2);
  u16* Yc0l = (u16*)alloc((size_t)2048 * NN * 2);
  u16* hh   = (u16*)alloc((size_t)NB * 640 * 2);
  u16* hl   = (u16*)alloc((size_t)NB * 640 * 2);
  float* ru    = (float*)alloc((size_t)NB * 128 * 4);
  float* st0   = (float*)alloc((size_t)NB * HH * 4);
  float* st1   = (float*)alloc((size_t)NB * HH * 4);
  float* decin = (float*)alloc((size_t)NB * 4);
  float* xin   = (float*)alloc((size_t)TT * NB * 2 * 4);
  const int wDout[8] = {128, 64, 128, 64, 128, 64, 128, 64};
  const int wKTa[8]  = {384, 384, 640, 640, 384, 384, 640, 640};
  const int wDreal[8]= {66, 66, 128, 128, 65, 65, 128, 128};
  const int wDp[8]   = {72, 72, 128, 128, 72, 72, 128, 128};
  u16 *Wth[8], *Wtl[8];
  for (int i = 0; i < 8; i++) {
    Wth[i] = (u16*)alloc((size_t)wDout[i] * wKTa[i] * 2);
    Wtl[i] = (u16*)alloc((size_t)wDout[i] * wKTa[i] * 2);
  }

  auto blocks = [](int n) { return (n + 255) / 256; };
  k_zero<<<blocks(NB * HH), 256, 0, stream>>>(st0, NB * HH);
  k_zero<<<blocks(NB * HH), 256, 0, stream>>>(st1, NB * HH);
  k_zero<<<blocks(NB), 256, 0, stream>>>(decin, NB);
  k_transpose_in<<<blocks(BB * TT * NN * 2), 256, 0, stream>>>(inputs, xin);
  k_splitS<<<blocks(2 * NN * NN), 256, 0, stream>>>(supports, Sh, Sl);
  k_transpS<<<blocks(2 * NN * NN), 256, 0, stream>>>(Sh, Sl, STh, STl);
  k_sq<<<dim3(8, 8, 2), 256, 0, stream>>>(Sh, Sl, STh, STl,
                                          Sh + (size_t)2 * NN * NN,
                                          Sl + (size_t)2 * NN * NN);
  for (int i = 0; i < 8; i++)
    k_padWt<<<blocks(wDout[i] * wKTa[i]), 256, 0, stream>>>(
        Wsrc[i], Wth[i], Wtl[i], wDreal[i], wDp[i], wKTa[i], wDout[i]);

  auto conv = [&](const float* inp, int indim, float* st, int wi, bool cand) {
    int Dp = wDp[wi], KTa = wKTa[wi];
    int CB = BB * Dp;                 // 1152 or 2048
    const float* ruptr = cand ? ru : nullptr;
    k_prep<<<CB, 256, 0, stream>>>(inp, indim, st, ruptr, Yc0h, Yc0l, hh, hl, Dp, KTa);
    if (Dp == 128) {
      k_diffuse2<128, 640><<<dim3(16, 8, 4), 256, 0, stream>>>(Yc0h, Yc0l, Sh, Sl, hh, hl);
    } else {
      k_diffuse2<72, 384><<<dim3(9, 8, 4), 256, 0, stream>>>(Yc0h, Yc0l, Sh, Sl, hh, hl);
    }
    int wsel = cand ? wi + 1 : wi;
    if (!cand)
      k_gemm3<128><<<NB / 64, 512, 0, stream>>>(
          hh, hl, KTa, Wth[wsel], Wtl[wsel], bias[wsel], 0, nullptr, ru);
    else
      k_gemm3<64><<<NB / 64, 256, 0, stream>>>(
          hh, hl, KTa, Wth[wsel], Wtl[wsel], bias[wsel], 1, ru, st);
  };
  auto cell = [&](const float* inp, int indim, float* st, int wi) {
    conv(inp, indim, st, wi, false);
    conv(inp, indim, st, wi, true);
  };

  for (int t = 0; t < TT; t++) {
    cell(xin + (size_t)t * NB * 2, 2, st0, 0);
    cell(st0, 64, st1, 2);
  }
  for (int t = 0; t < TT; t++) {
    cell(decin, 1, st0, 4);
    cell(st0, 64, st1, 6);
    k_proj<<<blocks(NB), 256, 0, stream>>>(st1, outW, outB, out, decin, t);
  }
}

// Round 6
// 9663.686 us; speedup vs baseline: 2.6602x; 1.1710x over previous
//
#include <hip/hip_runtime.h>
#include <math.h>

// DCRNN on MI355X — round 6: column order [state|inp|pad] + candidate-conv
// partial diffusion (state cols only; inp-derived h cols persist from ru pass).
// Templated diffuse BN(64/128) for >=512-block grids. 3-term bf16 split math.

#define NN 1024
#define BB 16
#define TT 12
#define HH 64
#define NB (NN*BB)      // 16384

typedef unsigned short u16;
typedef unsigned int u32;
typedef __attribute__((ext_vector_type(8))) short sv8;
typedef __attribute__((ext_vector_type(4))) float f32x4;
typedef __attribute__((ext_vector_type(16))) float f32x16;

__device__ __forceinline__ void gload16(const void* g, void* l) {
  __builtin_amdgcn_global_load_lds(
      (const __attribute__((address_space(1))) void*)(unsigned long long)(g),
      (__attribute__((address_space(3))) void*)(l), 16, 0, 0);
}

// 16-byte-slot index of (row, g) in a swizzled tile buffer (R4-verified bijection).
__device__ __forceinline__ int swz(int row, int g) {
  int rp = row >> 1;
  int j = ((row & 1) << 2) | g;
  return (rp << 3) | (j ^ (rp & 7));
}

__device__ __forceinline__ u16 bf16_rne(float x) {
  u32 u = __float_as_uint(x);
  u32 r = (u + 0x7FFFu + ((u >> 16) & 1u)) >> 16;
  return (u16)r;
}
__device__ __forceinline__ void split2(float x, u16& h, u16& l) {
  h = bf16_rne(x);
  float hf = __uint_as_float(((u32)h) << 16);
  l = bf16_rne(x - hf);
}

__global__ __launch_bounds__(256) void k_zero(float* p, int n) {
  int i = blockIdx.x * 256 + threadIdx.x;
  if (i < n) p[i] = 0.f;
}

// inputs (B,T,N,2) -> xin (T, N, B, 2)
__global__ __launch_bounds__(256) void k_transpose_in(const float* __restrict__ in,
                                                      float* __restrict__ xt) {
  int idx = blockIdx.x * 256 + threadIdx.x;
  if (idx >= BB * TT * NN * 2) return;
  int i = idx & 1;
  int n = (idx >> 1) & (NN - 1);
  int bt = idx >> 11;
  int t = bt % TT, b = bt / TT;
  xt[(size_t)t * (NB * 2) + (size_t)(n * BB + b) * 2 + i] = in[idx];
}

// supports f32 -> hi/lo bf16 (slots z=0,1)
__global__ __launch_bounds__(256) void k_splitS(const float* __restrict__ s,
                                                u16* __restrict__ sh, u16* __restrict__ sl) {
  int idx = blockIdx.x * 256 + threadIdx.x;
  if (idx >= 2 * NN * NN) return;
  u16 h, l; split2(s[idx], h, l);
  sh[idx] = h; sl[idx] = l;
}

// ST[z][k][j] = S[z][j][k]
__global__ __launch_bounds__(256) void k_transpS(const u16* __restrict__ sh,
        const u16* __restrict__ sl, u16* __restrict__ sth, u16* __restrict__ stl) {
  int idx = blockIdx.x * 256 + threadIdx.x;
  if (idx >= 2 * NN * NN) return;
  int j = idx & (NN - 1);
  int k = (idx >> 10) & (NN - 1);
  int z = idx >> 20;
  size_t src = ((size_t)z << 20) | ((size_t)j << 10) | (size_t)k;
  sth[idx] = sh[src];
  stl[idx] = sl[src];
}

// W (5*Dreal, dout) -> Wt hi/lo [o][KTa]; feature order per block: [state(64)|inp|pad]
// source row for block blk, new col d: d<64 -> blk*Dreal + indim + d (state)
//                                      64<=d<64+indim -> blk*Dreal + (d-64) (inp)
__global__ __launch_bounds__(256) void k_padWt(const float* __restrict__ W,
        u16* __restrict__ Wth, u16* __restrict__ Wtl,
        int indim, int Dp, int KTa, int dout) {
  int idx = blockIdx.x * 256 + threadIdx.x;
  if (idx >= dout * KTa) return;
  int kk = idx % KTa, o = idx / KTa;
  int blk = kk / Dp, d = kk - blk * Dp;
  int Dreal = indim + 64;
  float v = 0.f;
  if (blk < 5) {
    int dorig = -1;
    if (d < 64) dorig = indim + d;
    else if (d - 64 < indim) dorig = d - 64;
    if (dorig >= 0) v = W[(size_t)(blk * Dreal + dorig) * dout + o];
  }
  u16 h, l; split2(v, h, l);
  Wth[idx] = h; Wtl[idx] = l;
}

// Merged prep: Yc (c-major, packed) + h block0 cols. CW = column span this pass
// (full: Dp; cand: 64 = state cols only). col d<64: state (x r if cand); else inp.
__global__ __launch_bounds__(256) void k_prep(const float* __restrict__ inp, int indim,
        const float* __restrict__ st, const float* __restrict__ ru_,
        u16* __restrict__ ych, u16* __restrict__ ycl,
        u16* __restrict__ hh, u16* __restrict__ hl, int CW, int KTa) {
  int c = blockIdx.x;
  int n0 = threadIdx.x << 2;
  int b = c / CW, d = c - b * CW;
  u16 h4[4], l4[4];
  #pragma unroll
  for (int r = 0; r < 4; r++) {
    int nb = ((n0 + r) << 4) + b;
    float v = 0.f;
    if (d < 64) {
      v = st[(size_t)nb * HH + d];
      if (ru_) v *= ru_[(size_t)nb * 128 + d];
    } else if (d - 64 < indim) {
      v = inp[(size_t)nb * indim + (d - 64)];
    }
    split2(v, h4[r], l4[r]);
    hh[(size_t)nb * KTa + d] = h4[r];
    hl[(size_t)nb * KTa + d] = l4[r];
  }
  uint2 ph, pl;
  ph.x = (u32)h4[0] | ((u32)h4[1] << 16); ph.y = (u32)h4[2] | ((u32)h4[3] << 16);
  pl.x = (u32)l4[0] | ((u32)l4[1] << 16); pl.y = (u32)l4[2] | ((u32)l4[3] << 16);
  *(uint2*)&ych[(size_t)c * NN + n0] = ph;
  *(uint2*)&ycl[(size_t)c * NN + n0] = pl;
}

// slots: thread t handles 16B slots t and t+256 of a 512-slot (128-row) matrix.
struct StageMap {
  int row1, g1, row2, g2;
  __device__ StageMap(int tid) {
    int rp = tid >> 3, jx = (tid & 7) ^ (rp & 7);
    row1 = (rp << 1) | (jx >> 2); g1 = jx & 3;
    int s = tid + 256; rp = s >> 3; jx = (s & 7) ^ (rp & 7);
    row2 = (rp << 1) | (jx >> 2); g2 = jx & 3;
  }
};

// Ssq[z][m][k] = sum_j S[z][m][j] * ST[z][k][j]; output -> slots z+2.
__global__ __launch_bounds__(256) void k_sq(
    const u16* __restrict__ Sh, const u16* __restrict__ Sl,
    const u16* __restrict__ STh, const u16* __restrict__ STl,
    u16* __restrict__ Oh, u16* __restrict__ Ol)
{
  __shared__ __attribute__((aligned(16))) u16 lA[2][2][4096];
  __shared__ __attribute__((aligned(16))) u16 lB[2][2][4096];
  const int tid = threadIdx.x;
  const int lane = tid & 63, wave = tid >> 6;
  const int z = blockIdx.z;
  const int a0 = blockIdx.x << 7;
  const int b0 = blockIdx.y << 7;
  const int wc0 = (wave & 1) << 6;
  const int wn0 = (wave >> 1) << 6;
  StageMap sm(tid);
  const u16* pa1h = Sh + (size_t)z * NN * NN + (size_t)(a0 + sm.row1) * NN + sm.g1 * 8;
  const u16* pa2h = Sh + (size_t)z * NN * NN + (size_t)(a0 + sm.row2) * NN + sm.g2 * 8;
  const u16* pa1l = Sl + (size_t)z * NN * NN + (size_t)(a0 + sm.row1) * NN + sm.g1 * 8;
  const u16* pa2l = Sl + (size_t)z * NN * NN + (size_t)(a0 + sm.row2) * NN + sm.g2 * 8;
  const u16* pb1h = STh + (size_t)z * NN * NN + (size_t)(b0 + sm.row1) * NN + sm.g1 * 8;
  const u16* pb2h = STh + (size_t)z * NN * NN + (size_t)(b0 + sm.row2) * NN + sm.g2 * 8;
  const u16* pb1l = STl + (size_t)z * NN * NN + (size_t)(b0 + sm.row1) * NN + sm.g1 * 8;
  const u16* pb2l = STl + (size_t)z * NN * NN + (size_t)(b0 + sm.row2) * NN + sm.g2 * 8;

  f32x16 acc[2][2];
  #pragma unroll
  for (int i = 0; i < 2; i++)
    #pragma unroll
    for (int j = 0; j < 2; j++)
      #pragma unroll
      for (int e = 0; e < 16; e++) acc[i][j][e] = 0.f;

  auto stage = [&](int buf, int k0) {
    gload16(pa1h + k0, &lA[buf][0][tid * 8]);
    gload16(pa2h + k0, &lA[buf][0][tid * 8 + 2048]);
    gload16(pa1l + k0, &lA[buf][1][tid * 8]);
    gload16(pa2l + k0, &lA[buf][1][tid * 8 + 2048]);
    gload16(pb1h + k0, &lB[buf][0][tid * 8]);
    gload16(pb2h + k0, &lB[buf][0][tid * 8 + 2048]);
    gload16(pb1l + k0, &lB[buf][1][tid * 8]);
    gload16(pb2l + k0, &lB[buf][1][tid * 8 + 2048]);
  };

  stage(0, 0);
  __syncthreads();
  int cur = 0;
  for (int kt = 0; kt < 32; kt++) {
    if (kt < 31) stage(cur ^ 1, (kt + 1) * 32);
    #pragma unroll
    for (int kh = 0; kh < 2; kh++) {
      sv8 vah[2], vaL[2], vbh[2], vbL[2];
      int gsel = (kh << 1) | (lane >> 5);
      #pragma unroll
      for (int f = 0; f < 2; f++) {
        int offa = swz(wc0 + f * 32 + (lane & 31), gsel) * 8;
        vah[f] = *(const sv8*)&lA[cur][0][offa];
        vaL[f] = *(const sv8*)&lA[cur][1][offa];
        int offb = swz(wn0 + f * 32 + (lane & 31), gsel) * 8;
        vbh[f] = *(const sv8*)&lB[cur][0][offb];
        vbL[f] = *(const sv8*)&lB[cur][1][offb];
      }
      #pragma unroll
      for (int fm = 0; fm < 2; fm++)
        #pragma unroll
        for (int fn = 0; fn < 2; fn++) {
          acc[fm][fn] = __builtin_amdgcn_mfma_f32_32x32x16_bf16(vah[fm], vbh[fn], acc[fm][fn], 0, 0, 0);
          acc[fm][fn] = __builtin_amdgcn_mfma_f32_32x32x16_bf16(vah[fm], vbL[fn], acc[fm][fn], 0, 0, 0);
          acc[fm][fn] = __builtin_amdgcn_mfma_f32_32x32x16_bf16(vaL[fm], vbh[fn], acc[fm][fn], 0, 0, 0);
        }
    }
    __syncthreads();
    cur ^= 1;
  }

  u16* oh = Oh + (size_t)z * NN * NN;
  u16* ol = Ol + (size_t)z * NN * NN;
  #pragma unroll
  for (int fm = 0; fm < 2; fm++)
    #pragma unroll
    for (int q = 0; q < 4; q++) {
      int m4 = a0 + wc0 + fm * 32 + q * 8 + ((lane >> 5) << 2);
      #pragma unroll
      for (int fn = 0; fn < 2; fn++) {
        int kc = b0 + wn0 + fn * 32 + (lane & 31);
        #pragma unroll
        for (int r = 0; r < 4; r++) {
          u16 hi, lo; split2(acc[fm][fn][q * 4 + r], hi, lo);
          oh[(size_t)(m4 + r) * NN + kc] = hi;
          ol[(size_t)(m4 + r) * NN + kc] = lo;
        }
      }
    }
}

// Diffusion: C^T[c][m] = sum_k Yc[c][k] * Sz[m][k], z in {S0,S1,S0^2,S1^2};
// writes h block (1+((z&1)<<1)+(z>>1))*DP + (c % CW). BM=128, 4 waves.
// BN=128: waves 2x2 (64x64 tiles); BN=64: waves 2x2 (64x32 tiles).
template<int BN, int CW, int DP, int KTA>
__global__ __launch_bounds__(256) void k_diffuse2(
    const u16* __restrict__ Ah, const u16* __restrict__ Al,
    const u16* __restrict__ Sh, const u16* __restrict__ Sl,
    u16* __restrict__ hh, u16* __restrict__ hl)
{
  constexpr int FN = BN / 64;
  __shared__ __attribute__((aligned(16))) u16 lA[2][2][4096];
  __shared__ __attribute__((aligned(16))) u16 lB[2][2][BN * 32];
  const int tid = threadIdx.x;
  const int lane = tid & 63, wave = tid >> 6;
  const int z = blockIdx.z;
  const int a0 = blockIdx.x << 7;
  const int b0 = blockIdx.y * BN;
  const int wc0 = (wave & 1) << 6;
  const int wn0 = (wave >> 1) * (BN / 2);
  StageMap sm(tid);
  const u16* pa1h = Ah + (size_t)(a0 + sm.row1) * NN + sm.g1 * 8;
  const u16* pa2h = Ah + (size_t)(a0 + sm.row2) * NN + sm.g2 * 8;
  const u16* pa1l = Al + (size_t)(a0 + sm.row1) * NN + sm.g1 * 8;
  const u16* pa2l = Al + (size_t)(a0 + sm.row2) * NN + sm.g2 * 8;
  const u16* pb1h = Sh + (size_t)z * NN * NN + (size_t)(b0 + sm.row1) * NN + sm.g1 * 8;
  const u16* pb2h = Sh + (size_t)z * NN * NN + (size_t)(b0 + sm.row2) * NN + sm.g2 * 8;
  const u16* pb1l = Sl + (size_t)z * NN * NN + (size_t)(b0 + sm.row1) * NN + sm.g1 * 8;
  const u16* pb2l = Sl + (size_t)z * NN * NN + (size_t)(b0 + sm.row2) * NN + sm.g2 * 8;

  f32x16 acc[2][FN];
  #pragma unroll
  for (int i = 0; i < 2; i++)
    #pragma unroll
    for (int j = 0; j < FN; j++)
      #pragma unroll
      for (int e = 0; e < 16; e++) acc[i][j][e] = 0.f;

  auto stage = [&](int buf, int k0) {
    gload16(pa1h + k0, &lA[buf][0][tid * 8]);
    gload16(pa2h + k0, &lA[buf][0][tid * 8 + 2048]);
    gload16(pa1l + k0, &lA[buf][1][tid * 8]);
    gload16(pa2l + k0, &lA[buf][1][tid * 8 + 2048]);
    gload16(pb1h + k0, &lB[buf][0][tid * 8]);
    gload16(pb1l + k0, &lB[buf][1][tid * 8]);
    if (BN == 128) {
      gload16(pb2h + k0, &lB[buf][0][tid * 8 + 2048]);
      gload16(pb2l + k0, &lB[buf][1][tid * 8 + 2048]);
    }
  };

  stage(0, 0);
  __syncthreads();
  int cur = 0;
  for (int kt = 0; kt < 32; kt++) {
    if (kt < 31) stage(cur ^ 1, (kt + 1) * 32);
    #pragma unroll
    for (int kh = 0; kh < 2; kh++) {
      sv8 vah[2], vaL[2], vbh[FN], vbL[FN];
      int gsel = (kh << 1) | (lane >> 5);
      #pragma unroll
      for (int f = 0; f < 2; f++) {
        int offa = swz(wc0 + f * 32 + (lane & 31), gsel) * 8;
        vah[f] = *(const sv8*)&lA[cur][0][offa];
        vaL[f] = *(const sv8*)&lA[cur][1][offa];
      }
      #pragma unroll
      for (int f = 0; f < FN; f++) {
        int offb = swz(wn0 + f * 32 + (lane & 31), gsel) * 8;
        vbh[f] = *(const sv8*)&lB[cur][0][offb];
        vbL[f] = *(const sv8*)&lB[cur][1][offb];
      }
      #pragma unroll
      for (int fm = 0; fm < 2; fm++)
        #pragma unroll
        for (int fn = 0; fn < FN; fn++) {
          acc[fm][fn] = __builtin_amdgcn_mfma_f32_32x32x16_bf16(vah[fm], vbh[fn], acc[fm][fn], 0, 0, 0);
          acc[fm][fn] = __builtin_amdgcn_mfma_f32_32x32x16_bf16(vah[fm], vbL[fn], acc[fm][fn], 0, 0, 0);
          acc[fm][fn] = __builtin_amdgcn_mfma_f32_32x32x16_bf16(vaL[fm], vbh[fn], acc[fm][fn], 0, 0, 0);
        }
    }
    __syncthreads();
    cur ^= 1;
  }

  const int blkoff = (1 + ((z & 1) << 1) + (z >> 1)) * DP;
  #pragma unroll
  for (int fm = 0; fm < 2; fm++)
    #pragma unroll
    for (int q = 0; q < 4; q++) {
      int cg4 = a0 + wc0 + fm * 32 + q * 8 + ((lane >> 5) << 2);
      int bq = cg4 / CW, dq = cg4 - bq * CW;
      #pragma unroll
      for (int fn = 0; fn < FN; fn++) {
        int mg = b0 + wn0 + fn * 32 + (lane & 31);
        u16 hi4[4], lo4[4];
        #pragma unroll
        for (int r = 0; r < 4; r++)
          split2(acc[fm][fn][q * 4 + r], hi4[r], lo4[r]);
        size_t hidx = (size_t)((mg << 4) + bq) * KTA + blkoff + dq;
        uint2 ph, pl;
        ph.x = (u32)hi4[0] | ((u32)hi4[1] << 16); ph.y = (u32)hi4[2] | ((u32)hi4[3] << 16);
        pl.x = (u32)lo4[0] | ((u32)lo4[1] << 16); pl.y = (u32)lo4[2] | ((u32)lo4[3] << 16);
        *(uint2*)&hh[hidx] = ph;
        *(uint2*)&hl[hidx] = pl;
      }
    }
}

// Projection GEMM: out[nb][o] = act(sum_k h[nb][k]*Wt[o][k]+bias).
template<int BN>
__global__ __launch_bounds__(BN * 4) void k_gemm3(
    const u16* __restrict__ Ah_g, const u16* __restrict__ Al_g, int KTa,
    const u16* __restrict__ Bh_g, const u16* __restrict__ Bl_g,
    const float* __restrict__ bias, int mode,
    const float* __restrict__ rubuf, float* __restrict__ outp)
{
  __shared__ __attribute__((aligned(16))) u16 lAh[64 * 32];
  __shared__ __attribute__((aligned(16))) u16 lAl[64 * 32];
  __shared__ __attribute__((aligned(16))) u16 lBh[BN * 32];
  __shared__ __attribute__((aligned(16))) u16 lBl[BN * 32];
  const int tid = threadIdx.x;
  const int lane = tid & 63, wave = tid >> 6;
  const int a0 = blockIdx.x << 6;
  const int wr0 = (wave & 1) << 5;
  const int wn0 = (wave >> 1) << 5;
  const int gw = lane >> 4;
  const int rsel = lane & 15;

  const int sA = (BN == 128) ? (tid & 255) : tid;
  const int rpA = sA >> 3, jxA = (sA & 7) ^ (rpA & 7);
  const int rowA = (rpA << 1) | (jxA >> 2), gAc = jxA & 3;
  const int sB = tid;
  const int rpB = sB >> 3, jxB = (sB & 7) ^ (rpB & 7);
  const int rowB = (rpB << 1) | (jxB >> 2), gBc = jxB & 3;

  f32x4 acc[2][2];
  #pragma unroll
  for (int i = 0; i < 2; i++)
    #pragma unroll
    for (int j = 0; j < 2; j++) acc[i][j] = (f32x4){0.f, 0.f, 0.f, 0.f};

  for (int k0 = 0; k0 < KTa; k0 += 32) {
    if (BN == 128) {
      if (tid < 256) gload16(Ah_g + (size_t)(a0 + rowA) * KTa + k0 + gAc * 8, &lAh[sA * 8]);
      else           gload16(Al_g + (size_t)(a0 + rowA) * KTa + k0 + gAc * 8, &lAl[sA * 8]);
      gload16(Bh_g + (size_t)rowB * KTa + k0 + gBc * 8, &lBh[sB * 8]);
      gload16(Bl_g + (size_t)rowB * KTa + k0 + gBc * 8, &lBl[sB * 8]);
    } else {
      gload16(Ah_g + (size_t)(a0 + rowA) * KTa + k0 + gAc * 8, &lAh[sA * 8]);
      gload16(Al_g + (size_t)(a0 + rowA) * KTa + k0 + gAc * 8, &lAl[sA * 8]);
      gload16(Bh_g + (size_t)rowB * KTa + k0 + gBc * 8, &lBh[sB * 8]);
      gload16(Bl_g + (size_t)rowB * KTa + k0 + gBc * 8, &lBl[sB * 8]);
    }
    __syncthreads();
    sv8 vah[2], vaL[2], vbh[2], vbL[2];
    #pragma unroll
    for (int f = 0; f < 2; f++) {
      int offa = swz(wr0 + f * 16 + rsel, gw) * 8;
      vah[f] = *(const sv8*)&lAh[offa];
      vaL[f] = *(const sv8*)&lAl[offa];
      int offb = swz(wn0 + f * 16 + rsel, gw) * 8;
      vbh[f] = *(const sv8*)&lBh[offb];
      vbL[f] = *(const sv8*)&lBl[offb];
    }
    #pragma unroll
    for (int fm = 0; fm < 2; fm++)
      #pragma unroll
      for (int fn = 0; fn < 2; fn++) {
        acc[fm][fn] = __builtin_amdgcn_mfma_f32_16x16x32_bf16(vah[fm], vbh[fn], acc[fm][fn], 0, 0, 0);
        acc[fm][fn] = __builtin_amdgcn_mfma_f32_16x16x32_bf16(vah[fm], vbL[fn], acc[fm][fn], 0, 0, 0);
        acc[fm][fn] = __builtin_amdgcn_mfma_f32_16x16x32_bf16(vaL[fm], vbh[fn], acc[fm][fn], 0, 0, 0);
      }
    __syncthreads();
  }

  #pragma unroll
  for (int fm = 0; fm < 2; fm++) {
    #pragma unroll
    for (int r = 0; r < 4; r++) {
      int nb = a0 + wr0 + fm * 16 + ((lane >> 4) << 2) + r;
      #pragma unroll
      for (int fn = 0; fn < 2; fn++) {
        int o = wn0 + fn * 16 + rsel;
        float v = acc[fm][fn][r] + bias[o];
        if (mode == 0) {
          outp[(size_t)nb * 128 + o] = 1.f / (1.f + expf(-v));
        } else {
          float u = rubuf[(size_t)nb * 128 + 64 + o];
          float sold = outp[(size_t)nb * HH + o];
          outp[(size_t)nb * HH + o] = u * sold + (1.f - u) * tanhf(v);
        }
      }
    }
  }
}

// out_t[n,b] = st1[nb,:] @ outW + outb ; write d_out[b, t, n] and dec_in[nb]
__global__ __launch_bounds__(256) void k_proj(const float* __restrict__ st1,
        const float* __restrict__ ow, const float* __restrict__ ob,
        float* __restrict__ outg, float* __restrict__ dec_in, int t) {
  int nb = blockIdx.x * 256 + threadIdx.x;
  if (nb >= NB) return;
  float acc = ob[0];
  #pragma unroll
  for (int h = 0; h < HH; h++) acc += st1[(size_t)nb * HH + h] * ow[h];
  int n = nb >> 4, b = nb & 15;
  outg[((size_t)b * TT + t) * NN + n] = acc;
  dec_in[nb] = acc;
}

extern "C" void kernel_launch(void* const* d_in, const int* in_sizes, int n_in,
                              void* d_out, int out_size, void* d_ws, size_t ws_size,
                              hipStream_t stream) {
  const float* inputs   = (const float*)d_in[0];
  const float* supports = (const float*)d_in[1];
  const float* Wsrc[8] = {(const float*)d_in[2], (const float*)d_in[4],
                          (const float*)d_in[6], (const float*)d_in[8],
                          (const float*)d_in[10], (const float*)d_in[12],
                          (const float*)d_in[14], (const float*)d_in[16]};
  const float* bias[8] = {(const float*)d_in[3], (const float*)d_in[5],
                          (const float*)d_in[7], (const float*)d_in[9],
                          (const float*)d_in[11], (const float*)d_in[13],
                          (const float*)d_in[15], (const float*)d_in[17]};
  const float* outW = (const float*)d_in[18];
  const float* outB = (const float*)d_in[19];
  float* out = (float*)d_out;

  char* cur = (char*)d_ws;
  auto alloc = [&](size_t bytes) -> char* {
    char* p = cur; cur += (bytes + 255) & ~(size_t)255; return p;
  };
  u16* Sh   = (u16*)alloc((size_t)4 * NN * NN * 2);   // S0,S1,S0^2,S1^2
  u16* Sl   = (u16*)alloc((size_t)4 * NN * NN * 2);
  u16* STh  = (u16*)alloc((size_t)2 * NN * NN * 2);
  u16* STl  = (u16*)alloc((size_t)2 * NN * NN * 2);
  u16* Yc0h = (u16*)alloc((size_t)2048 * NN * 2);
  u16* Yc0l = (u16*)alloc((size_t)2048 * NN * 2);
  u16* hh   = (u16*)alloc((size_t)NB * 640 * 2);
  u16* hl   = (u16*)alloc((size_t)NB * 640 * 2);
  float* ru    = (float*)alloc((size_t)NB * 128 * 4);
  float* st0   = (float*)alloc((size_t)NB * HH * 4);
  float* st1   = (float*)alloc((size_t)NB * HH * 4);
  float* decin = (float*)alloc((size_t)NB * 4);
  float* xin   = (float*)alloc((size_t)TT * NB * 2 * 4);
  const int wDout[8] = {128, 64, 128, 64, 128, 64, 128, 64};
  const int wKTa[8]  = {384, 384, 640, 640, 384, 384, 640, 640};
  const int wIndim[8]= {2, 2, 64, 64, 1, 1, 64, 64};
  const int wDp[8]   = {72, 72, 128, 128, 72, 72, 128, 128};
  u16 *Wth[8], *Wtl[8];
  for (int i = 0; i < 8; i++) {
    Wth[i] = (u16*)alloc((size_t)wDout[i] * wKTa[i] * 2);
    Wtl[i] = (u16*)alloc((size_t)wDout[i] * wKTa[i] * 2);
  }

  auto blocks = [](int n) { return (n + 255) / 256; };
  k_zero<<<blocks(NB * HH), 256, 0, stream>>>(st0, NB * HH);
  k_zero<<<blocks(NB * HH), 256, 0, stream>>>(st1, NB * HH);
  k_zero<<<blocks(NB), 256, 0, stream>>>(decin, NB);
  k_transpose_in<<<blocks(BB * TT * NN * 2), 256, 0, stream>>>(inputs, xin);
  k_splitS<<<blocks(2 * NN * NN), 256, 0, stream>>>(supports, Sh, Sl);
  k_transpS<<<blocks(2 * NN * NN), 256, 0, stream>>>(Sh, Sl, STh, STl);
  k_sq<<<dim3(8, 8, 2), 256, 0, stream>>>(Sh, Sl, STh, STl,
                                          Sh + (size_t)2 * NN * NN,
                                          Sl + (size_t)2 * NN * NN);
  for (int i = 0; i < 8; i++)
    k_padWt<<<blocks(wDout[i] * wKTa[i]), 256, 0, stream>>>(
        Wsrc[i], Wth[i], Wtl[i], wIndim[i], wDp[i], wKTa[i], wDout[i]);

  auto conv = [&](const float* inp, int indim, float* st, int wi, bool cand) {
    int Dp = wDp[wi], KTa = wKTa[wi];
    int CW = cand ? 64 : Dp;
    int CB = BB * CW;
    const float* ruptr = cand ? ru : nullptr;
    k_prep<<<CB, 256, 0, stream>>>(inp, indim, st, ruptr, Yc0h, Yc0l, hh, hl, CW, KTa);
    if (!cand) {
      if (Dp == 128)
        k_diffuse2<128, 128, 128, 640><<<dim3(16, 8, 4), 256, 0, stream>>>(Yc0h, Yc0l, Sh, Sl, hh, hl);
      else
        k_diffuse2<64, 72, 72, 384><<<dim3(9, 16, 4), 256, 0, stream>>>(Yc0h, Yc0l, Sh, Sl, hh, hl);
    } else {
      if (Dp == 128)
        k_diffuse2<64, 64, 128, 640><<<dim3(8, 16, 4), 256, 0, stream>>>(Yc0h, Yc0l, Sh, Sl, hh, hl);
      else
        k_diffuse2<64, 64, 72, 384><<<dim3(8, 16, 4), 256, 0, stream>>>(Yc0h, Yc0l, Sh, Sl, hh, hl);
    }
    int wsel = cand ? wi + 1 : wi;
    if (!cand)
      k_gemm3<128><<<NB / 64, 512, 0, stream>>>(
          hh, hl, KTa, Wth[wsel], Wtl[wsel], bias[wsel], 0, nullptr, ru);
    else
      k_gemm3<64><<<NB / 64, 256, 0, stream>>>(
          hh, hl, KTa, Wth[wsel], Wtl[wsel], bias[wsel], 1, ru, st);
  };
  auto cell = [&](const float* inp, int indim, float* st, int wi) {
    conv(inp, indim, st, wi, false);
    conv(inp, indim, st, wi, true);
  };

  for (int t = 0; t < TT; t++) {
    cell(xin + (size_t)t * NB * 2, 2, st0, 0);
    cell(st0, 64, st1, 2);
  }
  for (int t = 0; t < TT; t++) {
    cell(decin, 1, st0, 4);
    cell(st0, 64, st1, 6);
    k_proj<<<blocks(NB), 256, 0, stream>>>(st1, outW, outB, out, decin, t);
  }
}

// Round 7
// 9458.024 us; speedup vs baseline: 2.7181x; 1.0217x over previous
//
#include <hip/hip_runtime.h>
#include <math.h>

// DCRNN on MI355X — round 7: R6 + bijective XCD-aware block swizzle on the
// diffusion GEMMs (and k_sq). Chunk bid%8 -> XCD pins one S-half (2MB) in that
// XCD's 4MB L2; x iterates fastest so co-resident blocks share the B panel.
// Numerics identical to R6 (absmax must stay 3.051758e-05).

#define NN 1024
#define BB 16
#define TT 12
#define HH 64
#define NB (NN*BB)      // 16384

typedef unsigned short u16;
typedef unsigned int u32;
typedef __attribute__((ext_vector_type(8))) short sv8;
typedef __attribute__((ext_vector_type(4))) float f32x4;
typedef __attribute__((ext_vector_type(16))) float f32x16;

__device__ __forceinline__ void gload16(const void* g, void* l) {
  __builtin_amdgcn_global_load_lds(
      (const __attribute__((address_space(1))) void*)(unsigned long long)(g),
      (__attribute__((address_space(3))) void*)(l), 16, 0, 0);
}

// XCD-aware decode of a 1-D grid (NX*NY*NZ blocks, multiple of 8):
// chunk = bid%8 -> one XCD (round-robin dispatch); each chunk = fixed z and
// y-half, x fastest. ZREP = chunks per z.
template<int NX, int NY, int NZ>
__device__ __forceinline__ void xcdmap(int bid, int& x, int& y, int& z) {
  constexpr int ZREP = 8 / NZ;
  constexpr int YH = NY / ZREP;
  int chunk = bid & 7, pos = bid >> 3;
  z = chunk / ZREP;
  int yh = chunk % ZREP;
  x = pos % NX;
  int yl = pos / NX;
  y = yh * YH + yl;
}

// 16-byte-slot index of (row, g) in a swizzled tile buffer (R4-verified bijection).
__device__ __forceinline__ int swz(int row, int g) {
  int rp = row >> 1;
  int j = ((row & 1) << 2) | g;
  return (rp << 3) | (j ^ (rp & 7));
}

__device__ __forceinline__ u16 bf16_rne(float x) {
  u32 u = __float_as_uint(x);
  u32 r = (u + 0x7FFFu + ((u >> 16) & 1u)) >> 16;
  return (u16)r;
}
__device__ __forceinline__ void split2(float x, u16& h, u16& l) {
  h = bf16_rne(x);
  float hf = __uint_as_float(((u32)h) << 16);
  l = bf16_rne(x - hf);
}

__global__ __launch_bounds__(256) void k_zero(float* p, int n) {
  int i = blockIdx.x * 256 + threadIdx.x;
  if (i < n) p[i] = 0.f;
}

// inputs (B,T,N,2) -> xin (T, N, B, 2)
__global__ __launch_bounds__(256) void k_transpose_in(const float* __restrict__ in,
                                                      float* __restrict__ xt) {
  int idx = blockIdx.x * 256 + threadIdx.x;
  if (idx >= BB * TT * NN * 2) return;
  int i = idx & 1;
  int n = (idx >> 1) & (NN - 1);
  int bt = idx >> 11;
  int t = bt % TT, b = bt / TT;
  xt[(size_t)t * (NB * 2) + (size_t)(n * BB + b) * 2 + i] = in[idx];
}

// supports f32 -> hi/lo bf16 (slots z=0,1)
__global__ __launch_bounds__(256) void k_splitS(const float* __restrict__ s,
                                                u16* __restrict__ sh, u16* __restrict__ sl) {
  int idx = blockIdx.x * 256 + threadIdx.x;
  if (idx >= 2 * NN * NN) return;
  u16 h, l; split2(s[idx], h, l);
  sh[idx] = h; sl[idx] = l;
}

// ST[z][k][j] = S[z][j][k]
__global__ __launch_bounds__(256) void k_transpS(const u16* __restrict__ sh,
        const u16* __restrict__ sl, u16* __restrict__ sth, u16* __restrict__ stl) {
  int idx = blockIdx.x * 256 + threadIdx.x;
  if (idx >= 2 * NN * NN) return;
  int j = idx & (NN - 1);
  int k = (idx >> 10) & (NN - 1);
  int z = idx >> 20;
  size_t src = ((size_t)z << 20) | ((size_t)j << 10) | (size_t)k;
  sth[idx] = sh[src];
  stl[idx] = sl[src];
}

// W (5*Dreal, dout) -> Wt hi/lo [o][KTa]; feature order per block: [state(64)|inp|pad]
__global__ __launch_bounds__(256) void k_padWt(const float* __restrict__ W,
        u16* __restrict__ Wth, u16* __restrict__ Wtl,
        int indim, int Dp, int KTa, int dout) {
  int idx = blockIdx.x * 256 + threadIdx.x;
  if (idx >= dout * KTa) return;
  int kk = idx % KTa, o = idx / KTa;
  int blk = kk / Dp, d = kk - blk * Dp;
  int Dreal = indim + 64;
  float v = 0.f;
  if (blk < 5) {
    int dorig = -1;
    if (d < 64) dorig = indim + d;
    else if (d - 64 < indim) dorig = d - 64;
    if (dorig >= 0) v = W[(size_t)(blk * Dreal + dorig) * dout + o];
  }
  u16 h, l; split2(v, h, l);
  Wth[idx] = h; Wtl[idx] = l;
}

// Merged prep: Yc (c-major, packed) + h block0 cols. CW = column span this pass.
__global__ __launch_bounds__(256) void k_prep(const float* __restrict__ inp, int indim,
        const float* __restrict__ st, const float* __restrict__ ru_,
        u16* __restrict__ ych, u16* __restrict__ ycl,
        u16* __restrict__ hh, u16* __restrict__ hl, int CW, int KTa) {
  int c = blockIdx.x;
  int n0 = threadIdx.x << 2;
  int b = c / CW, d = c - b * CW;
  u16 h4[4], l4[4];
  #pragma unroll
  for (int r = 0; r < 4; r++) {
    int nb = ((n0 + r) << 4) + b;
    float v = 0.f;
    if (d < 64) {
      v = st[(size_t)nb * HH + d];
      if (ru_) v *= ru_[(size_t)nb * 128 + d];
    } else if (d - 64 < indim) {
      v = inp[(size_t)nb * indim + (d - 64)];
    }
    split2(v, h4[r], l4[r]);
    hh[(size_t)nb * KTa + d] = h4[r];
    hl[(size_t)nb * KTa + d] = l4[r];
  }
  uint2 ph, pl;
  ph.x = (u32)h4[0] | ((u32)h4[1] << 16); ph.y = (u32)h4[2] | ((u32)h4[3] << 16);
  pl.x = (u32)l4[0] | ((u32)l4[1] << 16); pl.y = (u32)l4[2] | ((u32)l4[3] << 16);
  *(uint2*)&ych[(size_t)c * NN + n0] = ph;
  *(uint2*)&ycl[(size_t)c * NN + n0] = pl;
}

// slots: thread t handles 16B slots t and t+256 of a 512-slot (128-row) matrix.
struct StageMap {
  int row1, g1, row2, g2;
  __device__ StageMap(int tid) {
    int rp = tid >> 3, jx = (tid & 7) ^ (rp & 7);
    row1 = (rp << 1) | (jx >> 2); g1 = jx & 3;
    int s = tid + 256; rp = s >> 3; jx = (s & 7) ^ (rp & 7);
    row2 = (rp << 1) | (jx >> 2); g2 = jx & 3;
  }
};

// Ssq[z][m][k] = sum_j S[z][m][j] * ST[z][k][j]; output -> slots z+2. XCD-swizzled.
__global__ __launch_bounds__(256) void k_sq(
    const u16* __restrict__ Sh, const u16* __restrict__ Sl,
    const u16* __restrict__ STh, const u16* __restrict__ STl,
    u16* __restrict__ Oh, u16* __restrict__ Ol)
{
  __shared__ __attribute__((aligned(16))) u16 lA[2][2][4096];
  __shared__ __attribute__((aligned(16))) u16 lB[2][2][4096];
  const int tid = threadIdx.x;
  const int lane = tid & 63, wave = tid >> 6;
  int bx, by, z;
  xcdmap<8, 8, 2>(blockIdx.x, bx, by, z);
  const int a0 = bx << 7;
  const int b0 = by << 7;
  const int wc0 = (wave & 1) << 6;
  const int wn0 = (wave >> 1) << 6;
  StageMap sm(tid);
  const u16* pa1h = Sh + (size_t)z * NN * NN + (size_t)(a0 + sm.row1) * NN + sm.g1 * 8;
  const u16* pa2h = Sh + (size_t)z * NN * NN + (size_t)(a0 + sm.row2) * NN + sm.g2 * 8;
  const u16* pa1l = Sl + (size_t)z * NN * NN + (size_t)(a0 + sm.row1) * NN + sm.g1 * 8;
  const u16* pa2l = Sl + (size_t)z * NN * NN + (size_t)(a0 + sm.row2) * NN + sm.g2 * 8;
  const u16* pb1h = STh + (size_t)z * NN * NN + (size_t)(b0 + sm.row1) * NN + sm.g1 * 8;
  const u16* pb2h = STh + (size_t)z * NN * NN + (size_t)(b0 + sm.row2) * NN + sm.g2 * 8;
  const u16* pb1l = STl + (size_t)z * NN * NN + (size_t)(b0 + sm.row1) * NN + sm.g1 * 8;
  const u16* pb2l = STl + (size_t)z * NN * NN + (size_t)(b0 + sm.row2) * NN + sm.g2 * 8;

  f32x16 acc[2][2];
  #pragma unroll
  for (int i = 0; i < 2; i++)
    #pragma unroll
    for (int j = 0; j < 2; j++)
      #pragma unroll
      for (int e = 0; e < 16; e++) acc[i][j][e] = 0.f;

  auto stage = [&](int buf, int k0) {
    gload16(pa1h + k0, &lA[buf][0][tid * 8]);
    gload16(pa2h + k0, &lA[buf][0][tid * 8 + 2048]);
    gload16(pa1l + k0, &lA[buf][1][tid * 8]);
    gload16(pa2l + k0, &lA[buf][1][tid * 8 + 2048]);
    gload16(pb1h + k0, &lB[buf][0][tid * 8]);
    gload16(pb2h + k0, &lB[buf][0][tid * 8 + 2048]);
    gload16(pb1l + k0, &lB[buf][1][tid * 8]);
    gload16(pb2l + k0, &lB[buf][1][tid * 8 + 2048]);
  };

  stage(0, 0);
  __syncthreads();
  int cur = 0;
  for (int kt = 0; kt < 32; kt++) {
    if (kt < 31) stage(cur ^ 1, (kt + 1) * 32);
    #pragma unroll
    for (int kh = 0; kh < 2; kh++) {
      sv8 vah[2], vaL[2], vbh[2], vbL[2];
      int gsel = (kh << 1) | (lane >> 5);
      #pragma unroll
      for (int f = 0; f < 2; f++) {
        int offa = swz(wc0 + f * 32 + (lane & 31), gsel) * 8;
        vah[f] = *(const sv8*)&lA[cur][0][offa];
        vaL[f] = *(const sv8*)&lA[cur][1][offa];
        int offb = swz(wn0 + f * 32 + (lane & 31), gsel) * 8;
        vbh[f] = *(const sv8*)&lB[cur][0][offb];
        vbL[f] = *(const sv8*)&lB[cur][1][offb];
      }
      #pragma unroll
      for (int fm = 0; fm < 2; fm++)
        #pragma unroll
        for (int fn = 0; fn < 2; fn++) {
          acc[fm][fn] = __builtin_amdgcn_mfma_f32_32x32x16_bf16(vah[fm], vbh[fn], acc[fm][fn], 0, 0, 0);
          acc[fm][fn] = __builtin_amdgcn_mfma_f32_32x32x16_bf16(vah[fm], vbL[fn], acc[fm][fn], 0, 0, 0);
          acc[fm][fn] = __builtin_amdgcn_mfma_f32_32x32x16_bf16(vaL[fm], vbh[fn], acc[fm][fn], 0, 0, 0);
        }
    }
    __syncthreads();
    cur ^= 1;
  }

  u16* oh = Oh + (size_t)z * NN * NN;
  u16* ol = Ol + (size_t)z * NN * NN;
  #pragma unroll
  for (int fm = 0; fm < 2; fm++)
    #pragma unroll
    for (int q = 0; q < 4; q++) {
      int m4 = a0 + wc0 + fm * 32 + q * 8 + ((lane >> 5) << 2);
      #pragma unroll
      for (int fn = 0; fn < 2; fn++) {
        int kc = b0 + wn0 + fn * 32 + (lane & 31);
        #pragma unroll
        for (int r = 0; r < 4; r++) {
          u16 hi, lo; split2(acc[fm][fn][q * 4 + r], hi, lo);
          oh[(size_t)(m4 + r) * NN + kc] = hi;
          ol[(size_t)(m4 + r) * NN + kc] = lo;
        }
      }
    }
}

// Diffusion: C^T[c][m] = sum_k Yc[c][k] * Sz[m][k], z in {S0,S1,S0^2,S1^2};
// writes h block (1+((z&1)<<1)+(z>>1))*DP + (c % CW). 1-D grid, XCD-swizzled.
template<int BN, int CW, int DP, int KTA, int NX, int NY>
__global__ __launch_bounds__(256) void k_diffuse2(
    const u16* __restrict__ Ah, const u16* __restrict__ Al,
    const u16* __restrict__ Sh, const u16* __restrict__ Sl,
    u16* __restrict__ hh, u16* __restrict__ hl)
{
  constexpr int FN = BN / 64;
  __shared__ __attribute__((aligned(16))) u16 lA[2][2][4096];
  __shared__ __attribute__((aligned(16))) u16 lB[2][2][BN * 32];
  const int tid = threadIdx.x;
  const int lane = tid & 63, wave = tid >> 6;
  int bx, by, z;
  xcdmap<NX, NY, 4>(blockIdx.x, bx, by, z);
  const int a0 = bx << 7;
  const int b0 = by * BN;
  const int wc0 = (wave & 1) << 6;
  const int wn0 = (wave >> 1) * (BN / 2);
  StageMap sm(tid);
  const u16* pa1h = Ah + (size_t)(a0 + sm.row1) * NN + sm.g1 * 8;
  const u16* pa2h = Ah + (size_t)(a0 + sm.row2) * NN + sm.g2 * 8;
  const u16* pa1l = Al + (size_t)(a0 + sm.row1) * NN + sm.g1 * 8;
  const u16* pa2l = Al + (size_t)(a0 + sm.row2) * NN + sm.g2 * 8;
  const u16* pb1h = Sh + (size_t)z * NN * NN + (size_t)(b0 + sm.row1) * NN + sm.g1 * 8;
  const u16* pb2h = Sh + (size_t)z * NN * NN + (size_t)(b0 + sm.row2) * NN + sm.g2 * 8;
  const u16* pb1l = Sl + (size_t)z * NN * NN + (size_t)(b0 + sm.row1) * NN + sm.g1 * 8;
  const u16* pb2l = Sl + (size_t)z * NN * NN + (size_t)(b0 + sm.row2) * NN + sm.g2 * 8;

  f32x16 acc[2][FN];
  #pragma unroll
  for (int i = 0; i < 2; i++)
    #pragma unroll
    for (int j = 0; j < FN; j++)
      #pragma unroll
      for (int e = 0; e < 16; e++) acc[i][j][e] = 0.f;

  auto stage = [&](int buf, int k0) {
    gload16(pa1h + k0, &lA[buf][0][tid * 8]);
    gload16(pa2h + k0, &lA[buf][0][tid * 8 + 2048]);
    gload16(pa1l + k0, &lA[buf][1][tid * 8]);
    gload16(pa2l + k0, &lA[buf][1][tid * 8 + 2048]);
    gload16(pb1h + k0, &lB[buf][0][tid * 8]);
    gload16(pb1l + k0, &lB[buf][1][tid * 8]);
    if (BN == 128) {
      gload16(pb2h + k0, &lB[buf][0][tid * 8 + 2048]);
      gload16(pb2l + k0, &lB[buf][1][tid * 8 + 2048]);
    }
  };

  stage(0, 0);
  __syncthreads();
  int cur = 0;
  for (int kt = 0; kt < 32; kt++) {
    if (kt < 31) stage(cur ^ 1, (kt + 1) * 32);
    #pragma unroll
    for (int kh = 0; kh < 2; kh++) {
      sv8 vah[2], vaL[2], vbh[FN], vbL[FN];
      int gsel = (kh << 1) | (lane >> 5);
      #pragma unroll
      for (int f = 0; f < 2; f++) {
        int offa = swz(wc0 + f * 32 + (lane & 31), gsel) * 8;
        vah[f] = *(const sv8*)&lA[cur][0][offa];
        vaL[f] = *(const sv8*)&lA[cur][1][offa];
      }
      #pragma unroll
      for (int f = 0; f < FN; f++) {
        int offb = swz(wn0 + f * 32 + (lane & 31), gsel) * 8;
        vbh[f] = *(const sv8*)&lB[cur][0][offb];
        vbL[f] = *(const sv8*)&lB[cur][1][offb];
      }
      #pragma unroll
      for (int fm = 0; fm < 2; fm++)
        #pragma unroll
        for (int fn = 0; fn < FN; fn++) {
          acc[fm][fn] = __builtin_amdgcn_mfma_f32_32x32x16_bf16(vah[fm], vbh[fn], acc[fm][fn], 0, 0, 0);
          acc[fm][fn] = __builtin_amdgcn_mfma_f32_32x32x16_bf16(vah[fm], vbL[fn], acc[fm][fn], 0, 0, 0);
          acc[fm][fn] = __builtin_amdgcn_mfma_f32_32x32x16_bf16(vaL[fm], vbh[fn], acc[fm][fn], 0, 0, 0);
        }
    }
    __syncthreads();
    cur ^= 1;
  }

  const int blkoff = (1 + ((z & 1) << 1) + (z >> 1)) * DP;
  #pragma unroll
  for (int fm = 0; fm < 2; fm++)
    #pragma unroll
    for (int q = 0; q < 4; q++) {
      int cg4 = a0 + wc0 + fm * 32 + q * 8 + ((lane >> 5) << 2);
      int bq = cg4 / CW, dq = cg4 - bq * CW;
      #pragma unroll
      for (int fn = 0; fn < FN; fn++) {
        int mg = b0 + wn0 + fn * 32 + (lane & 31);
        u16 hi4[4], lo4[4];
        #pragma unroll
        for (int r = 0; r < 4; r++)
          split2(acc[fm][fn][q * 4 + r], hi4[r], lo4[r]);
        size_t hidx = (size_t)((mg << 4) + bq) * KTA + blkoff + dq;
        uint2 ph, pl;
        ph.x = (u32)hi4[0] | ((u32)hi4[1] << 16); ph.y = (u32)hi4[2] | ((u32)hi4[3] << 16);
        pl.x = (u32)lo4[0] | ((u32)lo4[1] << 16); pl.y = (u32)lo4[2] | ((u32)lo4[3] << 16);
        *(uint2*)&hh[hidx] = ph;
        *(uint2*)&hl[hidx] = pl;
      }
    }
}

// Projection GEMM: out[nb][o] = act(sum_k h[nb][k]*Wt[o][k]+bias).
template<int BN>
__global__ __launch_bounds__(BN * 4) void k_gemm3(
    const u16* __restrict__ Ah_g, const u16* __restrict__ Al_g, int KTa,
    const u16* __restrict__ Bh_g, const u16* __restrict__ Bl_g,
    const float* __restrict__ bias, int mode,
    const float* __restrict__ rubuf, float* __restrict__ outp)
{
  __shared__ __attribute__((aligned(16))) u16 lAh[64 * 32];
  __shared__ __attribute__((aligned(16))) u16 lAl[64 * 32];
  __shared__ __attribute__((aligned(16))) u16 lBh[BN * 32];
  __shared__ __attribute__((aligned(16))) u16 lBl[BN * 32];
  const int tid = threadIdx.x;
  const int lane = tid & 63, wave = tid >> 6;
  const int a0 = blockIdx.x << 6;
  const int wr0 = (wave & 1) << 5;
  const int wn0 = (wave >> 1) << 5;
  const int gw = lane >> 4;
  const int rsel = lane & 15;

  const int sA = (BN == 128) ? (tid & 255) : tid;
  const int rpA = sA >> 3, jxA = (sA & 7) ^ (rpA & 7);
  const int rowA = (rpA << 1) | (jxA >> 2), gAc = jxA & 3;
  const int sB = tid;
  const int rpB = sB >> 3, jxB = (sB & 7) ^ (rpB & 7);
  const int rowB = (rpB << 1) | (jxB >> 2), gBc = jxB & 3;

  f32x4 acc[2][2];
  #pragma unroll
  for (int i = 0; i < 2; i++)
    #pragma unroll
    for (int j = 0; j < 2; j++) acc[i][j] = (f32x4){0.f, 0.f, 0.f, 0.f};

  for (int k0 = 0; k0 < KTa; k0 += 32) {
    if (BN == 128) {
      if (tid < 256) gload16(Ah_g + (size_t)(a0 + rowA) * KTa + k0 + gAc * 8, &lAh[sA * 8]);
      else           gload16(Al_g + (size_t)(a0 + rowA) * KTa + k0 + gAc * 8, &lAl[sA * 8]);
      gload16(Bh_g + (size_t)rowB * KTa + k0 + gBc * 8, &lBh[sB * 8]);
      gload16(Bl_g + (size_t)rowB * KTa + k0 + gBc * 8, &lBl[sB * 8]);
    } else {
      gload16(Ah_g + (size_t)(a0 + rowA) * KTa + k0 + gAc * 8, &lAh[sA * 8]);
      gload16(Al_g + (size_t)(a0 + rowA) * KTa + k0 + gAc * 8, &lAl[sA * 8]);
      gload16(Bh_g + (size_t)rowB * KTa + k0 + gBc * 8, &lBh[sB * 8]);
      gload16(Bl_g + (size_t)rowB * KTa + k0 + gBc * 8, &lBl[sB * 8]);
    }
    __syncthreads();
    sv8 vah[2], vaL[2], vbh[2], vbL[2];
    #pragma unroll
    for (int f = 0; f < 2; f++) {
      int offa = swz(wr0 + f * 16 + rsel, gw) * 8;
      vah[f] = *(const sv8*)&lAh[offa];
      vaL[f] = *(const sv8*)&lAl[offa];
      int offb = swz(wn0 + f * 16 + rsel, gw) * 8;
      vbh[f] = *(const sv8*)&lBh[offb];
      vbL[f] = *(const sv8*)&lBl[offb];
    }
    #pragma unroll
    for (int fm = 0; fm < 2; fm++)
      #pragma unroll
      for (int fn = 0; fn < 2; fn++) {
        acc[fm][fn] = __builtin_amdgcn_mfma_f32_16x16x32_bf16(vah[fm], vbh[fn], acc[fm][fn], 0, 0, 0);
        acc[fm][fn] = __builtin_amdgcn_mfma_f32_16x16x32_bf16(vah[fm], vbL[fn], acc[fm][fn], 0, 0, 0);
        acc[fm][fn] = __builtin_amdgcn_mfma_f32_16x16x32_bf16(vaL[fm], vbh[fn], acc[fm][fn], 0, 0, 0);
      }
    __syncthreads();
  }

  #pragma unroll
  for (int fm = 0; fm < 2; fm++) {
    #pragma unroll
    for (int r = 0; r < 4; r++) {
      int nb = a0 + wr0 + fm * 16 + ((lane >> 4) << 2) + r;
      #pragma unroll
      for (int fn = 0; fn < 2; fn++) {
        int o = wn0 + fn * 16 + rsel;
        float v = acc[fm][fn][r] + bias[o];
        if (mode == 0) {
          outp[(size_t)nb * 128 + o] = 1.f / (1.f + expf(-v));
        } else {
          float u = rubuf[(size_t)nb * 128 + 64 + o];
          float sold = outp[(size_t)nb * HH + o];
          outp[(size_t)nb * HH + o] = u * sold + (1.f - u) * tanhf(v);
        }
      }
    }
  }
}

// out_t[n,b] = st1[nb,:] @ outW + outb ; write d_out[b, t, n] and dec_in[nb]
__global__ __launch_bounds__(256) void k_proj(const float* __restrict__ st1,
        const float* __restrict__ ow, const float* __restrict__ ob,
        float* __restrict__ outg, float* __restrict__ dec_in, int t) {
  int nb = blockIdx.x * 256 + threadIdx.x;
  if (nb >= NB) return;
  float acc = ob[0];
  #pragma unroll
  for (int h = 0; h < HH; h++) acc += st1[(size_t)nb * HH + h] * ow[h];
  int n = nb >> 4, b = nb & 15;
  outg[((size_t)b * TT + t) * NN + n] = acc;
  dec_in[nb] = acc;
}

extern "C" void kernel_launch(void* const* d_in, const int* in_sizes, int n_in,
                              void* d_out, int out_size, void* d_ws, size_t ws_size,
                              hipStream_t stream) {
  const float* inputs   = (const float*)d_in[0];
  const float* supports = (const float*)d_in[1];
  const float* Wsrc[8] = {(const float*)d_in[2], (const float*)d_in[4],
                          (const float*)d_in[6], (const float*)d_in[8],
                          (const float*)d_in[10], (const float*)d_in[12],
                          (const float*)d_in[14], (const float*)d_in[16]};
  const float* bias[8] = {(const float*)d_in[3], (const float*)d_in[5],
                          (const float*)d_in[7], (const float*)d_in[9],
                          (const float*)d_in[11], (const float*)d_in[13],
                          (const float*)d_in[15], (const float*)d_in[17]};
  const float* outW = (const float*)d_in[18];
  const float* outB = (const float*)d_in[19];
  float* out = (float*)d_out;

  char* cur = (char*)d_ws;
  auto alloc = [&](size_t bytes) -> char* {
    char* p = cur; cur += (bytes + 255) & ~(size_t)255; return p;
  };
  u16* Sh   = (u16*)alloc((size_t)4 * NN * NN * 2);   // S0,S1,S0^2,S1^2
  u16* Sl   = (u16*)alloc((size_t)4 * NN * NN * 2);
  u16* STh  = (u16*)alloc((size_t)2 * NN * NN * 2);
  u16* STl  = (u16*)alloc((size_t)2 * NN * NN * 2);
  u16* Yc0h = (u16*)alloc((size_t)2048 * NN * 2);
  u16* Yc0l = (u16*)alloc((size_t)2048 * NN * 2);
  u16* hh   = (u16*)alloc((size_t)NB * 640 * 2);
  u16* hl   = (u16*)alloc((size_t)NB * 640 * 2);
  float* ru    = (float*)alloc((size_t)NB * 128 * 4);
  float* st0   = (float*)alloc((size_t)NB * HH * 4);
  float* st1   = (float*)alloc((size_t)NB * HH * 4);
  float* decin = (float*)alloc((size_t)NB * 4);
  float* xin   = (float*)alloc((size_t)TT * NB * 2 * 4);
  const int wDout[8] = {128, 64, 128, 64, 128, 64, 128, 64};
  const int wKTa[8]  = {384, 384, 640, 640, 384, 384, 640, 640};
  const int wIndim[8]= {2, 2, 64, 64, 1, 1, 64, 64};
  const int wDp[8]   = {72, 72, 128, 128, 72, 72, 128, 128};
  u16 *Wth[8], *Wtl[8];
  for (int i = 0; i < 8; i++) {
    Wth[i] = (u16*)alloc((size_t)wDout[i] * wKTa[i] * 2);
    Wtl[i] = (u16*)alloc((size_t)wDout[i] * wKTa[i] * 2);
  }

  auto blocks = [](int n) { return (n + 255) / 256; };
  k_zero<<<blocks(NB * HH), 256, 0, stream>>>(st0, NB * HH);
  k_zero<<<blocks(NB * HH), 256, 0, stream>>>(st1, NB * HH);
  k_zero<<<blocks(NB), 256, 0, stream>>>(decin, NB);
  k_transpose_in<<<blocks(BB * TT * NN * 2), 256, 0, stream>>>(inputs, xin);
  k_splitS<<<blocks(2 * NN * NN), 256, 0, stream>>>(supports, Sh, Sl);
  k_transpS<<<blocks(2 * NN * NN), 256, 0, stream>>>(Sh, Sl, STh, STl);
  k_sq<<<128, 256, 0, stream>>>(Sh, Sl, STh, STl,
                                Sh + (size_t)2 * NN * NN,
                                Sl + (size_t)2 * NN * NN);
  for (int i = 0; i < 8; i++)
    k_padWt<<<blocks(wDout[i] * wKTa[i]), 256, 0, stream>>>(
        Wsrc[i], Wth[i], Wtl[i], wIndim[i], wDp[i], wKTa[i], wDout[i]);

  auto conv = [&](const float* inp, int indim, float* st, int wi, bool cand) {
    int Dp = wDp[wi], KTa = wKTa[wi];
    int CW = cand ? 64 : Dp;
    int CB = BB * CW;
    const float* ruptr = cand ? ru : nullptr;
    k_prep<<<CB, 256, 0, stream>>>(inp, indim, st, ruptr, Yc0h, Yc0l, hh, hl, CW, KTa);
    if (!cand) {
      if (Dp == 128)
        k_diffuse2<128, 128, 128, 640, 16, 8><<<512, 256, 0, stream>>>(Yc0h, Yc0l, Sh, Sl, hh, hl);
      else
        k_diffuse2<64, 72, 72, 384, 9, 16><<<576, 256, 0, stream>>>(Yc0h, Yc0l, Sh, Sl, hh, hl);
    } else {
      if (Dp == 128)
        k_diffuse2<64, 64, 128, 640, 8, 16><<<512, 256, 0, stream>>>(Yc0h, Yc0l, Sh, Sl, hh, hl);
      else
        k_diffuse2<64, 64, 72, 384, 8, 16><<<512, 256, 0, stream>>>(Yc0h, Yc0l, Sh, Sl, hh, hl);
    }
    int wsel = cand ? wi + 1 : wi;
    if (!cand)
      k_gemm3<128><<<NB / 64, 512, 0, stream>>>(
          hh, hl, KTa, Wth[wsel], Wtl[wsel], bias[wsel], 0, nullptr, ru);
    else
      k_gemm3<64><<<NB / 64, 256, 0, stream>>>(
          hh, hl, KTa, Wth[wsel], Wtl[wsel], bias[wsel], 1, ru, st);
  };
  auto cell = [&](const float* inp, int indim, float* st, int wi) {
    conv(inp, indim, st, wi, false);
    conv(inp, indim, st, wi, true);
  };

  for (int t = 0; t < TT; t++) {
    cell(xin + (size_t)t * NB * 2, 2, st0, 0);
    cell(st0, 64, st1, 2);
  }
  for (int t = 0; t < TT; t++) {
    cell(decin, 1, st0, 4);
    cell(st0, 64, st1, 6);
    k_proj<<<blocks(NB), 256, 0, stream>>>(st1, outW, outB, out, decin, t);
  }
}

// Round 8
// 9005.339 us; speedup vs baseline: 2.8547x; 1.0503x over previous
//
#include <hip/hip_runtime.h>
#include <math.h>

// DCRNN on MI355X — round 8: launch-count attack. Encoder software-pipelined
// (l0(t) ∥ l1(t-1)) via multi-segment merged kernels; cand-prep fused into
// gemm-ru epilogue (r*state -> h[KTa..KTa+64) + Yc_cand, race-free); decoder
// proj fused into dec-l1 gemm-cand. 3-term bf16 hi/lo split math unchanged.

#define NN 1024
#define BB 16
#define TT 12
#define HH 64
#define NB (NN*BB)      // 16384

typedef unsigned short u16;
typedef unsigned int u32;
typedef __attribute__((ext_vector_type(8))) short sv8;
typedef __attribute__((ext_vector_type(4))) float f32x4;
typedef __attribute__((ext_vector_type(16))) float f32x16;

__device__ __forceinline__ void gload16(const void* g, void* l) {
  __builtin_amdgcn_global_load_lds(
      (const __attribute__((address_space(1))) void*)(unsigned long long)(g),
      (__attribute__((address_space(3))) void*)(l), 16, 0, 0);
}

template<int NX, int NY, int NZ>
__device__ __forceinline__ void xcdmap(int bid, int& x, int& y, int& z) {
  constexpr int ZREP = 8 / NZ;
  constexpr int YH = NY / ZREP;
  int chunk = bid & 7, pos = bid >> 3;
  z = chunk / ZREP;
  int yh = chunk % ZREP;
  x = pos % NX;
  y = yh * YH + pos / NX;
}

__device__ __forceinline__ int swz(int row, int g) {
  int rp = row >> 1;
  int j = ((row & 1) << 2) | g;
  return (rp << 3) | (j ^ (rp & 7));
}

__device__ __forceinline__ u16 bf16_rne(float x) {
  u32 u = __float_as_uint(x);
  return (u16)((u + 0x7FFFu + ((u >> 16) & 1u)) >> 16);
}
__device__ __forceinline__ void split2(float x, u16& h, u16& l) {
  h = bf16_rne(x);
  float hf = __uint_as_float(((u32)h) << 16);
  l = bf16_rne(x - hf);
}

__global__ __launch_bounds__(256) void k_zero(float* p, int n) {
  int i = blockIdx.x * 256 + threadIdx.x;
  if (i < n) p[i] = 0.f;
}

__global__ __launch_bounds__(256) void k_transpose_in(const float* __restrict__ in,
                                                      float* __restrict__ xt) {
  int idx = blockIdx.x * 256 + threadIdx.x;
  if (idx >= BB * TT * NN * 2) return;
  int i = idx & 1;
  int n = (idx >> 1) & (NN - 1);
  int bt = idx >> 11;
  int t = bt % TT, b = bt / TT;
  xt[(size_t)t * (NB * 2) + (size_t)(n * BB + b) * 2 + i] = in[idx];
}

__global__ __launch_bounds__(256) void k_splitS(const float* __restrict__ s,
                                                u16* __restrict__ sh, u16* __restrict__ sl) {
  int idx = blockIdx.x * 256 + threadIdx.x;
  if (idx >= 2 * NN * NN) return;
  u16 h, l; split2(s[idx], h, l);
  sh[idx] = h; sl[idx] = l;
}

__global__ __launch_bounds__(256) void k_transpS(const u16* __restrict__ sh,
        const u16* __restrict__ sl, u16* __restrict__ sth, u16* __restrict__ stl) {
  int idx = blockIdx.x * 256 + threadIdx.x;
  if (idx >= 2 * NN * NN) return;
  int j = idx & (NN - 1);
  int k = (idx >> 10) & (NN - 1);
  int z = idx >> 20;
  size_t src = ((size_t)z << 20) | ((size_t)j << 10) | (size_t)k;
  sth[idx] = sh[src];
  stl[idx] = sl[src];
}

// ru weights: [o][KTa], per-block col order [state(64)|inp|pad]
__global__ __launch_bounds__(256) void k_padWt(const float* __restrict__ W,
        u16* __restrict__ Wth, u16* __restrict__ Wtl,
        int indim, int Dp, int KTa, int dout) {
  int idx = blockIdx.x * 256 + threadIdx.x;
  if (idx >= dout * KTa) return;
  int kk = idx % KTa, o = idx / KTa;
  int blk = kk / Dp, d = kk - blk * Dp;
  int Dreal = indim + 64;
  float v = 0.f;
  if (blk < 5) {
    int dorig = -1;
    if (d < 64) dorig = indim + d;
    else if (d - 64 < indim) dorig = d - 64;
    if (dorig >= 0) v = W[(size_t)(blk * Dreal + dorig) * dout + o];
  }
  u16 h, l; split2(v, h, l);
  Wth[idx] = h; Wtl[idx] = l;
}

// cand weights: Wtc[o][kk] maps h col c=64+kk (h width KTa+64; r*state at [KTa,KTa+64))
__global__ __launch_bounds__(256) void k_padWtCand(const float* __restrict__ W,
        u16* __restrict__ Wth, u16* __restrict__ Wtl,
        int indim, int Dp, int KTa, int dout) {
  int idx = blockIdx.x * 256 + threadIdx.x;
  if (idx >= dout * KTa) return;
  int kk = idx % KTa, o = idx / KTa;
  int c = 64 + kk;
  int Dreal = indim + 64;
  float v = 0.f;
  if (c >= KTa) {
    int d = c - KTa;                       // block0 state
    v = W[(size_t)(indim + d) * dout + o];
  } else {
    int blk = c / Dp, d = c - blk * Dp;
    if (blk == 0) {
      int di = d - 64;
      if (di < indim) v = W[(size_t)di * dout + o];
    } else {
      if (d < 64) v = W[(size_t)(blk * Dreal + indim + d) * dout + o];
      else if (d - 64 < indim) v = W[(size_t)(blk * Dreal + (d - 64)) * dout + o];
    }
  }
  u16 h, l; split2(v, h, l);
  Wth[idx] = h; Wtl[idx] = l;
}

// ---------- prep (ru pass only): Yc_ru c-major + h block0 ----------
struct PrepSeg {
  const float *inp, *st;
  u16 *ych, *ycl, *hh, *hl;
  int indim, CW, STR, nblk;
};
__global__ __launch_bounds__(256) void k_prepM(PrepSeg s0, PrepSeg s1) {
  const bool first = (int)blockIdx.x < s0.nblk;
  const PrepSeg s = first ? s0 : s1;
  const int c = first ? blockIdx.x : blockIdx.x - s0.nblk;
  int n0 = threadIdx.x << 2;
  int b = c / s.CW, d = c - b * s.CW;
  u16 h4[4], l4[4];
  #pragma unroll
  for (int r = 0; r < 4; r++) {
    int nb = ((n0 + r) << 4) + b;
    float v = 0.f;
    if (d < 64) v = s.st[(size_t)nb * HH + d];
    else if (d - 64 < s.indim) v = s.inp[(size_t)nb * s.indim + (d - 64)];
    split2(v, h4[r], l4[r]);
    s.hh[(size_t)nb * s.STR + d] = h4[r];
    s.hl[(size_t)nb * s.STR + d] = l4[r];
  }
  uint2 ph, pl;
  ph.x = (u32)h4[0] | ((u32)h4[1] << 16); ph.y = (u32)h4[2] | ((u32)h4[3] << 16);
  pl.x = (u32)l4[0] | ((u32)l4[1] << 16); pl.y = (u32)l4[2] | ((u32)l4[3] << 16);
  *(uint2*)&s.ych[(size_t)c * NN + n0] = ph;
  *(uint2*)&s.ycl[(size_t)c * NN + n0] = pl;
}

struct StageMap {
  int row1, g1, row2, g2;
  __device__ StageMap(int tid) {
    int rp = tid >> 3, jx = (tid & 7) ^ (rp & 7);
    row1 = (rp << 1) | (jx >> 2); g1 = jx & 3;
    int s = tid + 256; rp = s >> 3; jx = (s & 7) ^ (rp & 7);
    row2 = (rp << 1) | (jx >> 2); g2 = jx & 3;
  }
};

// ---------- S^2 (setup) ----------
__global__ __launch_bounds__(256) void k_sq(
    const u16* __restrict__ Sh, const u16* __restrict__ Sl,
    const u16* __restrict__ STh, const u16* __restrict__ STl,
    u16* __restrict__ Oh, u16* __restrict__ Ol)
{
  __shared__ __attribute__((aligned(16))) u16 lA[2][2][4096];
  __shared__ __attribute__((aligned(16))) u16 lB[2][2][4096];
  const int tid = threadIdx.x;
  const int lane = tid & 63, wave = tid >> 6;
  int bx, by, z;
  xcdmap<8, 8, 2>(blockIdx.x, bx, by, z);
  const int a0 = bx << 7, b0 = by << 7;
  const int wc0 = (wave & 1) << 6, wn0 = (wave >> 1) << 6;
  StageMap sm(tid);
  const u16* pa1h = Sh + (size_t)z * NN * NN + (size_t)(a0 + sm.row1) * NN + sm.g1 * 8;
  const u16* pa2h = Sh + (size_t)z * NN * NN + (size_t)(a0 + sm.row2) * NN + sm.g2 * 8;
  const u16* pa1l = Sl + (size_t)z * NN * NN + (size_t)(a0 + sm.row1) * NN + sm.g1 * 8;
  const u16* pa2l = Sl + (size_t)z * NN * NN + (size_t)(a0 + sm.row2) * NN + sm.g2 * 8;
  const u16* pb1h = STh + (size_t)z * NN * NN + (size_t)(b0 + sm.row1) * NN + sm.g1 * 8;
  const u16* pb2h = STh + (size_t)z * NN * NN + (size_t)(b0 + sm.row2) * NN + sm.g2 * 8;
  const u16* pb1l = STl + (size_t)z * NN * NN + (size_t)(b0 + sm.row1) * NN + sm.g1 * 8;
  const u16* pb2l = STl + (size_t)z * NN * NN + (size_t)(b0 + sm.row2) * NN + sm.g2 * 8;

  f32x16 acc[2][2];
  #pragma unroll
  for (int i = 0; i < 2; i++)
    #pragma unroll
    for (int j = 0; j < 2; j++)
      #pragma unroll
      for (int e = 0; e < 16; e++) acc[i][j][e] = 0.f;

  auto stage = [&](int buf, int k0) {
    gload16(pa1h + k0, &lA[buf][0][tid * 8]);
    gload16(pa2h + k0, &lA[buf][0][tid * 8 + 2048]);
    gload16(pa1l + k0, &lA[buf][1][tid * 8]);
    gload16(pa2l + k0, &lA[buf][1][tid * 8 + 2048]);
    gload16(pb1h + k0, &lB[buf][0][tid * 8]);
    gload16(pb2h + k0, &lB[buf][0][tid * 8 + 2048]);
    gload16(pb1l + k0, &lB[buf][1][tid * 8]);
    gload16(pb2l + k0, &lB[buf][1][tid * 8 + 2048]);
  };
  stage(0, 0);
  __syncthreads();
  int cur = 0;
  for (int kt = 0; kt < 32; kt++) {
    if (kt < 31) stage(cur ^ 1, (kt + 1) * 32);
    #pragma unroll
    for (int kh = 0; kh < 2; kh++) {
      sv8 vah[2], vaL[2], vbh[2], vbL[2];
      int gsel = (kh << 1) | (lane >> 5);
      #pragma unroll
      for (int f = 0; f < 2; f++) {
        int offa = swz(wc0 + f * 32 + (lane & 31), gsel) * 8;
        vah[f] = *(const sv8*)&lA[cur][0][offa];
        vaL[f] = *(const sv8*)&lA[cur][1][offa];
        int offb = swz(wn0 + f * 32 + (lane & 31), gsel) * 8;
        vbh[f] = *(const sv8*)&lB[cur][0][offb];
        vbL[f] = *(const sv8*)&lB[cur][1][offb];
      }
      #pragma unroll
      for (int fm = 0; fm < 2; fm++)
        #pragma unroll
        for (int fn = 0; fn < 2; fn++) {
          acc[fm][fn] = __builtin_amdgcn_mfma_f32_32x32x16_bf16(vah[fm], vbh[fn], acc[fm][fn], 0, 0, 0);
          acc[fm][fn] = __builtin_amdgcn_mfma_f32_32x32x16_bf16(vah[fm], vbL[fn], acc[fm][fn], 0, 0, 0);
          acc[fm][fn] = __builtin_amdgcn_mfma_f32_32x32x16_bf16(vaL[fm], vbh[fn], acc[fm][fn], 0, 0, 0);
        }
    }
    __syncthreads();
    cur ^= 1;
  }
  u16* oh = Oh + (size_t)z * NN * NN;
  u16* ol = Ol + (size_t)z * NN * NN;
  #pragma unroll
  for (int fm = 0; fm < 2; fm++)
    #pragma unroll
    for (int q = 0; q < 4; q++) {
      int m4 = a0 + wc0 + fm * 32 + q * 8 + ((lane >> 5) << 2);
      #pragma unroll
      for (int fn = 0; fn < 2; fn++) {
        int kc = b0 + wn0 + fn * 32 + (lane & 31);
        #pragma unroll
        for (int r = 0; r < 4; r++) {
          u16 hi, lo; split2(acc[fm][fn][q * 4 + r], hi, lo);
          oh[(size_t)(m4 + r) * NN + kc] = hi;
          ol[(size_t)(m4 + r) * NN + kc] = lo;
        }
      }
    }
}

// ---------- diffusion (merged segments, variant-templated body) ----------
// V0: l0 full (BN64,CW72,DP72,KTA384,9x16)  V1: l1 full (128,128,128,640,16x8)
// V2: l0 cand (64,64,72,384,8x16)           V3: l1 cand (64,64,128,640,8x16)
struct DiffSeg { const u16 *Ah, *Al; u16 *hh, *hl; int nblk; };

template<int V>
__device__ __forceinline__ void diffuse_body(int bid, const DiffSeg s,
    const u16* __restrict__ Sh, const u16* __restrict__ Sl,
    u16* sA, u16* sB)
{
  constexpr int BN  = (V == 1) ? 128 : 64;
  constexpr int CW  = (V == 0) ? 72 : ((V == 1) ? 128 : 64);
  constexpr int DP  = (V == 0 || V == 2) ? 72 : 128;
  constexpr int KTA = (V == 0 || V == 2) ? 384 : 640;
  constexpr int STR = KTA + 64;
  constexpr int NX  = (V == 0) ? 9 : ((V == 1) ? 16 : 8);
  constexpr int NY  = (V == 1) ? 8 : 16;
  constexpr int FN  = BN / 64;
  const int tid = threadIdx.x;
  const int lane = tid & 63, wave = tid >> 6;
  int bx, by, z;
  xcdmap<NX, NY, 4>(bid, bx, by, z);
  const int a0 = bx << 7;
  const int b0 = by * BN;
  const int wc0 = (wave & 1) << 6;
  const int wn0 = (wave >> 1) * (BN / 2);
  StageMap sm(tid);
  const u16* pa1h = s.Ah + (size_t)(a0 + sm.row1) * NN + sm.g1 * 8;
  const u16* pa2h = s.Ah + (size_t)(a0 + sm.row2) * NN + sm.g2 * 8;
  const u16* pa1l = s.Al + (size_t)(a0 + sm.row1) * NN + sm.g1 * 8;
  const u16* pa2l = s.Al + (size_t)(a0 + sm.row2) * NN + sm.g2 * 8;
  const u16* pb1h = Sh + (size_t)z * NN * NN + (size_t)(b0 + sm.row1) * NN + sm.g1 * 8;
  const u16* pb2h = Sh + (size_t)z * NN * NN + (size_t)(b0 + sm.row2) * NN + sm.g2 * 8;
  const u16* pb1l = Sl + (size_t)z * NN * NN + (size_t)(b0 + sm.row1) * NN + sm.g1 * 8;
  const u16* pb2l = Sl + (size_t)z * NN * NN + (size_t)(b0 + sm.row2) * NN + sm.g2 * 8;

  f32x16 acc[2][FN];
  #pragma unroll
  for (int i = 0; i < 2; i++)
    #pragma unroll
    for (int j = 0; j < FN; j++)
      #pragma unroll
      for (int e = 0; e < 16; e++) acc[i][j][e] = 0.f;

  auto stage = [&](int buf, int k0) {
    gload16(pa1h + k0, sA + (buf * 2 + 0) * 4096 + tid * 8);
    gload16(pa2h + k0, sA + (buf * 2 + 0) * 4096 + tid * 8 + 2048);
    gload16(pa1l + k0, sA + (buf * 2 + 1) * 4096 + tid * 8);
    gload16(pa2l + k0, sA + (buf * 2 + 1) * 4096 + tid * 8 + 2048);
    gload16(pb1h + k0, sB + (buf * 2 + 0) * (BN * 32) + tid * 8);
    gload16(pb1l + k0, sB + (buf * 2 + 1) * (BN * 32) + tid * 8);
    if (BN == 128) {
      gload16(pb2h + k0, sB + (buf * 2 + 0) * (BN * 32) + tid * 8 + 2048);
      gload16(pb2l + k0, sB + (buf * 2 + 1) * (BN * 32) + tid * 8 + 2048);
    }
  };
  stage(0, 0);
  __syncthreads();
  int cur = 0;
  for (int kt = 0; kt < 32; kt++) {
    if (kt < 31) stage(cur ^ 1, (kt + 1) * 32);
    #pragma unroll
    for (int kh = 0; kh < 2; kh++) {
      sv8 vah[2], vaL[2], vbh[FN], vbL[FN];
      int gsel = (kh << 1) | (lane >> 5);
      #pragma unroll
      for (int f = 0; f < 2; f++) {
        int offa = swz(wc0 + f * 32 + (lane & 31), gsel) * 8;
        vah[f] = *(const sv8*)(sA + (cur * 2 + 0) * 4096 + offa);
        vaL[f] = *(const sv8*)(sA + (cur * 2 + 1) * 4096 + offa);
      }
      #pragma unroll
      for (int f = 0; f < FN; f++) {
        int offb = swz(wn0 + f * 32 + (lane & 31), gsel) * 8;
        vbh[f] = *(const sv8*)(sB + (cur * 2 + 0) * (BN * 32) + offb);
        vbL[f] = *(const sv8*)(sB + (cur * 2 + 1) * (BN * 32) + offb);
      }
      #pragma unroll
      for (int fm = 0; fm < 2; fm++)
        #pragma unroll
        for (int fn = 0; fn < FN; fn++) {
          acc[fm][fn] = __builtin_amdgcn_mfma_f32_32x32x16_bf16(vah[fm], vbh[fn], acc[fm][fn], 0, 0, 0);
          acc[fm][fn] = __builtin_amdgcn_mfma_f32_32x32x16_bf16(vah[fm], vbL[fn], acc[fm][fn], 0, 0, 0);
          acc[fm][fn] = __builtin_amdgcn_mfma_f32_32x32x16_bf16(vaL[fm], vbh[fn], acc[fm][fn], 0, 0, 0);
        }
    }
    __syncthreads();
    cur ^= 1;
  }
  const int blkoff = (1 + ((z & 1) << 1) + (z >> 1)) * DP;
  #pragma unroll
  for (int fm = 0; fm < 2; fm++)
    #pragma unroll
    for (int q = 0; q < 4; q++) {
      int cg4 = a0 + wc0 + fm * 32 + q * 8 + ((lane >> 5) << 2);
      int bq = cg4 / CW, dq = cg4 - bq * CW;
      #pragma unroll
      for (int fn = 0; fn < FN; fn++) {
        int mg = b0 + wn0 + fn * 32 + (lane & 31);
        u16 hi4[4], lo4[4];
        #pragma unroll
        for (int r = 0; r < 4; r++)
          split2(acc[fm][fn][q * 4 + r], hi4[r], lo4[r]);
        size_t hidx = (size_t)((mg << 4) + bq) * STR + blkoff + dq;
        uint2 ph, pl;
        ph.x = (u32)hi4[0] | ((u32)hi4[1] << 16); ph.y = (u32)hi4[2] | ((u32)hi4[3] << 16);
        pl.x = (u32)lo4[0] | ((u32)lo4[1] << 16); pl.y = (u32)lo4[2] | ((u32)lo4[3] << 16);
        *(uint2*)&s.hh[hidx] = ph;
        *(uint2*)&s.hl[hidx] = pl;
      }
    }
}

template<int VA, int VB>
__global__ __launch_bounds__(256) void k_diffM(DiffSeg s0, DiffSeg s1,
    const u16* __restrict__ Sh, const u16* __restrict__ Sl) {
  constexpr int BNA = (VA == 1) ? 128 : 64;
  constexpr int BNB = (VB == 1) ? 128 : 64;
  constexpr int MB = BNA > BNB ? BNA : BNB;
  __shared__ __attribute__((aligned(16))) u16 sA[4 * 4096];
  __shared__ __attribute__((aligned(16))) u16 sB[4 * MB * 32];
  if ((int)blockIdx.x < s0.nblk) {
    diffuse_body<VA>(blockIdx.x, s0, Sh, Sl, sA, sB);
  } else {
    if constexpr (VB >= 0)
      diffuse_body<VB>(blockIdx.x - s0.nblk, s1, Sh, Sl, sA, sB);
  }
}

// ---------- gemm-ru (BN=128, 512 thr) + fused cand-prep ----------
struct G3RuSeg {
  const u16 *Ah, *Al, *Bh, *Bl;
  const float *bias, *stold;
  float *ru;
  u16 *ych, *ycl, *hh, *hl;
  int KTa, STR, nblk;
};
__global__ __launch_bounds__(512) void k_g3ru(G3RuSeg s0, G3RuSeg s1) {
  __shared__ __attribute__((aligned(16))) u16 lAh[64 * 32];
  __shared__ __attribute__((aligned(16))) u16 lAl[64 * 32];
  __shared__ __attribute__((aligned(16))) u16 lBh[128 * 32];
  __shared__ __attribute__((aligned(16))) u16 lBl[128 * 32];
  const bool first = (int)blockIdx.x < s0.nblk;
  const G3RuSeg s = first ? s0 : s1;
  const int bid = first ? blockIdx.x : blockIdx.x - s0.nblk;
  const int tid = threadIdx.x;
  const int lane = tid & 63, wave = tid >> 6;
  const int a0 = bid << 6;
  const int wr0 = (wave & 1) << 5;
  const int wn0 = (wave >> 1) << 5;
  const int gw = lane >> 4, rsel = lane & 15;
  const int sAi = tid & 255;
  int rp = sAi >> 3, jx = (sAi & 7) ^ (rp & 7);
  const int rowA = (rp << 1) | (jx >> 2), gAc = jx & 3;
  rp = tid >> 3; jx = (tid & 7) ^ (rp & 7);
  const int rowB = (rp << 1) | (jx >> 2), gBc = jx & 3;

  f32x4 acc[2][2];
  #pragma unroll
  for (int i = 0; i < 2; i++)
    #pragma unroll
    for (int j = 0; j < 2; j++) acc[i][j] = (f32x4){0.f, 0.f, 0.f, 0.f};

  for (int k0 = 0; k0 < s.KTa; k0 += 32) {
    if (tid < 256) gload16(s.Ah + (size_t)(a0 + rowA) * s.STR + k0 + gAc * 8, &lAh[sAi * 8]);
    else           gload16(s.Al + (size_t)(a0 + rowA) * s.STR + k0 + gAc * 8, &lAl[sAi * 8]);
    gload16(s.Bh + (size_t)rowB * s.KTa + k0 + gBc * 8, &lBh[tid * 8]);
    gload16(s.Bl + (size_t)rowB * s.KTa + k0 + gBc * 8, &lBl[tid * 8]);
    __syncthreads();
    sv8 vah[2], vaL[2], vbh[2], vbL[2];
    #pragma unroll
    for (int f = 0; f < 2; f++) {
      int offa = swz(wr0 + f * 16 + rsel, gw) * 8;
      vah[f] = *(const sv8*)&lAh[offa];
      vaL[f] = *(const sv8*)&lAl[offa];
      int offb = swz(wn0 + f * 16 + rsel, gw) * 8;
      vbh[f] = *(const sv8*)&lBh[offb];
      vbL[f] = *(const sv8*)&lBl[offb];
    }
    #pragma unroll
    for (int fm = 0; fm < 2; fm++)
      #pragma unroll
      for (int fn = 0; fn < 2; fn++) {
        acc[fm][fn] = __builtin_amdgcn_mfma_f32_16x16x32_bf16(vah[fm], vbh[fn], acc[fm][fn], 0, 0, 0);
        acc[fm][fn] = __builtin_amdgcn_mfma_f32_16x16x32_bf16(vah[fm], vbL[fn], acc[fm][fn], 0, 0, 0);
        acc[fm][fn] = __builtin_amdgcn_mfma_f32_16x16x32_bf16(vaL[fm], vbh[fn], acc[fm][fn], 0, 0, 0);
      }
    __syncthreads();
  }

  #pragma unroll
  for (int fm = 0; fm < 2; fm++) {
    #pragma unroll
    for (int r = 0; r < 4; r++) {
      int nb = a0 + wr0 + fm * 16 + ((lane >> 4) << 2) + r;
      #pragma unroll
      for (int fn = 0; fn < 2; fn++) {
        int o = wn0 + fn * 16 + rsel;
        float v = acc[fm][fn][r] + s.bias[o];
        float sig = 1.f / (1.f + expf(-v));
        s.ru[(size_t)nb * 128 + o] = sig;
        if (o < 64) {    // fused cand-prep: r*state -> Yc_cand + h[KTa+o]
          float rv = sig * s.stold[(size_t)nb * HH + o];
          u16 hi, lo; split2(rv, hi, lo);
          int cc = ((nb & 15) << 6) + o;
          s.ych[(size_t)cc * NN + (nb >> 4)] = hi;
          s.ycl[(size_t)cc * NN + (nb >> 4)] = lo;
          s.hh[(size_t)nb * s.STR + s.KTa + o] = hi;
          s.hl[(size_t)nb * s.STR + s.KTa + o] = lo;
        }
      }
    }
  }
}

// ---------- gemm-cand (BN=64, 256 thr) + optional fused projection ----------
struct G3CdSeg {
  const u16 *Ah, *Al, *Bh, *Bl;
  const float *bias, *ru, *stold;
  float *stout;
  const float *ow, *ob;
  float *outg, *decin;
  int t, KTa, STR, nblk;
};
__global__ __launch_bounds__(256) void k_g3cd(G3CdSeg s0, G3CdSeg s1) {
  __shared__ __attribute__((aligned(16))) u16 lAh[64 * 32];
  __shared__ __attribute__((aligned(16))) u16 lAl[64 * 32];
  __shared__ __attribute__((aligned(16))) u16 lBh[64 * 32];
  __shared__ __attribute__((aligned(16))) u16 lBl[64 * 32];
  __shared__ float pst[64][65];
  const bool first = (int)blockIdx.x < s0.nblk;
  const G3CdSeg s = first ? s0 : s1;
  const int bid = first ? blockIdx.x : blockIdx.x - s0.nblk;
  const int tid = threadIdx.x;
  const int lane = tid & 63, wave = tid >> 6;
  const int a0 = bid << 6;
  const int wr0 = (wave & 1) << 5;
  const int wn0 = (wave >> 1) << 5;
  const int gw = lane >> 4, rsel = lane & 15;
  int rp = tid >> 3, jx = (tid & 7) ^ (rp & 7);
  const int rowA = (rp << 1) | (jx >> 2), gAc = jx & 3;

  f32x4 acc[2][2];
  #pragma unroll
  for (int i = 0; i < 2; i++)
    #pragma unroll
    for (int j = 0; j < 2; j++) acc[i][j] = (f32x4){0.f, 0.f, 0.f, 0.f};

  for (int k0 = 0; k0 < s.KTa; k0 += 32) {
    gload16(s.Ah + (size_t)(a0 + rowA) * s.STR + 64 + k0 + gAc * 8, &lAh[tid * 8]);
    gload16(s.Al + (size_t)(a0 + rowA) * s.STR + 64 + k0 + gAc * 8, &lAl[tid * 8]);
    gload16(s.Bh + (size_t)rowA * s.KTa + k0 + gAc * 8, &lBh[tid * 8]);
    gload16(s.Bl + (size_t)rowA * s.KTa + k0 + gAc * 8, &lBl[tid * 8]);
    __syncthreads();
    sv8 vah[2], vaL[2], vbh[2], vbL[2];
    #pragma unroll
    for (int f = 0; f < 2; f++) {
      int offa = swz(wr0 + f * 16 + rsel, gw) * 8;
      vah[f] = *(const sv8*)&lAh[offa];
      vaL[f] = *(const sv8*)&lAl[offa];
      int offb = swz(wn0 + f * 16 + rsel, gw) * 8;
      vbh[f] = *(const sv8*)&lBh[offb];
      vbL[f] = *(const sv8*)&lBl[offb];
    }
    #pragma unroll
    for (int fm = 0; fm < 2; fm++)
      #pragma unroll
      for (int fn = 0; fn < 2; fn++) {
        acc[fm][fn] = __builtin_amdgcn_mfma_f32_16x16x32_bf16(vah[fm], vbh[fn], acc[fm][fn], 0, 0, 0);
        acc[fm][fn] = __builtin_amdgcn_mfma_f32_16x16x32_bf16(vah[fm], vbL[fn], acc[fm][fn], 0, 0, 0);
        acc[fm][fn] = __builtin_amdgcn_mfma_f32_16x16x32_bf16(vaL[fm], vbh[fn], acc[fm][fn], 0, 0, 0);
      }
    __syncthreads();
  }

  #pragma unroll
  for (int fm = 0; fm < 2; fm++) {
    #pragma unroll
    for (int r = 0; r < 4; r++) {
      int nb = a0 + wr0 + fm * 16 + ((lane >> 4) << 2) + r;
      #pragma unroll
      for (int fn = 0; fn < 2; fn++) {
        int o = wn0 + fn * 16 + rsel;
        float v = acc[fm][fn][r] + s.bias[o];
        float u = s.ru[(size_t)nb * 128 + 64 + o];
        float sold = s.stold[(size_t)nb * HH + o];
        float ns = u * sold + (1.f - u) * tanhf(v);
        s.stout[(size_t)nb * HH + o] = ns;
        if (s.ow) pst[nb - a0][o] = ns;
      }
    }
  }
  if (s.ow) {
    __syncthreads();
    if (tid < 64) {
      int nb = a0 + tid;
      float a2 = s.ob[0];
      #pragma unroll
      for (int o = 0; o < HH; o++) a2 += pst[tid][o] * s.ow[o];
      int n = nb >> 4, b = nb & 15;
      s.outg[((size_t)b * TT + s.t) * NN + n] = a2;
      s.decin[nb] = a2;
    }
  }
}

// ---------------- host ----------------
struct LayerH {
  u16 *YcRh, *YcRl, *YcCh, *YcCl, *hh, *hl;
  float *ru;
  u16 *Wrh, *Wrl, *Wch, *Wcl;
  const float *br, *bc;
  int indim, CW, KTa, STR, nfull;
};

extern "C" void kernel_launch(void* const* d_in, const int* in_sizes, int n_in,
                              void* d_out, int out_size, void* d_ws, size_t ws_size,
                              hipStream_t stream) {
  const float* inputs   = (const float*)d_in[0];
  const float* supports = (const float*)d_in[1];
  const float* Wsrc[8] = {(const float*)d_in[2], (const float*)d_in[4],
                          (const float*)d_in[6], (const float*)d_in[8],
                          (const float*)d_in[10], (const float*)d_in[12],
                          (const float*)d_in[14], (const float*)d_in[16]};
  const float* bias[8] = {(const float*)d_in[3], (const float*)d_in[5],
                          (const float*)d_in[7], (const float*)d_in[9],
                          (const float*)d_in[11], (const float*)d_in[13],
                          (const float*)d_in[15], (const float*)d_in[17]};
  const float* outW = (const float*)d_in[18];
  const float* outB = (const float*)d_in[19];
  float* out = (float*)d_out;

  char* cur = (char*)d_ws;
  auto alloc = [&](size_t bytes) -> char* {
    char* p = cur; cur += (bytes + 255) & ~(size_t)255; return p;
  };
  u16* Sh    = (u16*)alloc((size_t)4 * NN * NN * 2);   // S0,S1,S0^2,S1^2
  u16* Sl    = (u16*)alloc((size_t)4 * NN * NN * 2);
  u16* YcR0h = (u16*)alloc((size_t)1152 * NN * 2);
  u16* YcR0l = (u16*)alloc((size_t)1152 * NN * 2);
  u16* YcR1h = (u16*)alloc((size_t)2048 * NN * 2);
  u16* YcR1l = (u16*)alloc((size_t)2048 * NN * 2);
  u16* h0h   = (u16*)alloc((size_t)NB * 448 * 2);
  u16* h0l   = (u16*)alloc((size_t)NB * 448 * 2);
  u16* h1h   = (u16*)alloc((size_t)NB * 704 * 2);
  u16* h1l   = (u16*)alloc((size_t)NB * 704 * 2);
  float* ru0 = (float*)alloc((size_t)NB * 128 * 4);
  float* ru1 = (float*)alloc((size_t)NB * 128 * 4);
  float* P0  = (float*)alloc((size_t)NB * HH * 4);
  float* P1  = (float*)alloc((size_t)NB * HH * 4);
  float* st1 = (float*)alloc((size_t)NB * HH * 4);
  float* decin = (float*)alloc((size_t)NB * 4);
  float* xin = (float*)alloc((size_t)TT * NB * 2 * 4);
  // aliases (lifetime-disjoint): ST (setup only) in h1; Yc_cand in Yc_ru regions
  u16* STh = h1h;
  u16* STl = h1l;
  u16* YcC0h = YcR0h; u16* YcC0l = YcR0l;
  u16* YcC1h = YcR1h; u16* YcC1l = YcR1l;

  const int wKTa[4]  = {384, 640, 384, 640};     // e0, e1, d0, d1
  const int wIndim[4]= {2, 64, 1, 64};
  const int wDp[4]   = {72, 128, 72, 128};
  u16 *Wrh[4], *Wrl[4], *Wch[4], *Wcl[4];
  for (int i = 0; i < 4; i++) {
    Wrh[i] = (u16*)alloc((size_t)128 * wKTa[i] * 2);
    Wrl[i] = (u16*)alloc((size_t)128 * wKTa[i] * 2);
    Wch[i] = (u16*)alloc((size_t)64 * wKTa[i] * 2);
    Wcl[i] = (u16*)alloc((size_t)64 * wKTa[i] * 2);
  }

  auto blocks = [](int n) { return (n + 255) / 256; };
  k_zero<<<blocks(NB * HH), 256, 0, stream>>>(P1, NB * HH);
  k_zero<<<blocks(NB * HH), 256, 0, stream>>>(st1, NB * HH);
  k_zero<<<blocks(NB), 256, 0, stream>>>(decin, NB);
  k_transpose_in<<<blocks(BB * TT * NN * 2), 256, 0, stream>>>(inputs, xin);
  k_splitS<<<blocks(2 * NN * NN), 256, 0, stream>>>(supports, Sh, Sl);
  k_transpS<<<blocks(2 * NN * NN), 256, 0, stream>>>(Sh, Sl, STh, STl);
  k_sq<<<128, 256, 0, stream>>>(Sh, Sl, STh, STl,
                                Sh + (size_t)2 * NN * NN,
                                Sl + (size_t)2 * NN * NN);
  for (int i = 0; i < 4; i++) {
    k_padWt<<<blocks(128 * wKTa[i]), 256, 0, stream>>>(
        Wsrc[2 * i], Wrh[i], Wrl[i], wIndim[i], wDp[i], wKTa[i], 128);
    k_padWtCand<<<blocks(64 * wKTa[i]), 256, 0, stream>>>(
        Wsrc[2 * i + 1], Wch[i], Wcl[i], wIndim[i], wDp[i], wKTa[i], 64);
  }

  LayerH L[4];
  // 0:e0 1:e1 2:d0 3:d1 ; d0 shares buffers with e0, d1 with e1
  for (int i = 0; i < 4; i++) {
    bool lo = (wDp[i] == 72);
    L[i].YcRh = lo ? YcR0h : YcR1h; L[i].YcRl = lo ? YcR0l : YcR1l;
    L[i].YcCh = lo ? YcC0h : YcC1h; L[i].YcCl = lo ? YcC0l : YcC1l;
    L[i].hh = lo ? h0h : h1h; L[i].hl = lo ? h0l : h1l;
    L[i].ru = lo ? ru0 : ru1;
    L[i].Wrh = Wrh[i]; L[i].Wrl = Wrl[i]; L[i].Wch = Wch[i]; L[i].Wcl = Wcl[i];
    L[i].br = bias[2 * i]; L[i].bc = bias[2 * i + 1];
    L[i].indim = wIndim[i];
    L[i].CW = wDp[i]; L[i].KTa = wKTa[i]; L[i].STR = wKTa[i] + 64;
    L[i].nfull = lo ? 576 : 512;
  }

  auto prepSeg = [&](LayerH& Y, const float* inp, const float* st) {
    return PrepSeg{inp, st, Y.YcRh, Y.YcRl, Y.hh, Y.hl, Y.indim, Y.CW, Y.STR, BB * Y.CW};
  };
  auto dRuSeg = [&](LayerH& Y) {
    return DiffSeg{Y.YcRh, Y.YcRl, Y.hh, Y.hl, Y.nfull};
  };
  auto dCdSeg = [&](LayerH& Y) {
    return DiffSeg{Y.YcCh, Y.YcCl, Y.hh, Y.hl, 512};
  };
  auto ruSeg = [&](LayerH& Y, const float* stold) {
    return G3RuSeg{Y.hh, Y.hl, Y.Wrh, Y.Wrl, Y.br, stold, Y.ru,
                   Y.YcCh, Y.YcCl, Y.hh, Y.hl, Y.KTa, Y.STR, NB / 64};
  };
  auto cdSeg = [&](LayerH& Y, const float* stold, float* stout,
                   const float* ow, const float* ob, int t) {
    return G3CdSeg{Y.hh, Y.hl, Y.Wch, Y.Wcl, Y.bc, Y.ru, stold, stout,
                   ow, ob, out, decin, t, Y.KTa, Y.STR, NB / 64};
  };

  // single cell (layer template index LI: 0/2 -> V0/V2 variants, 1/3 -> V1/V3)
  auto cell72 = [&](LayerH& Y, const float* inp, const float* stold, float* stout) {
    PrepSeg p = prepSeg(Y, inp, stold);
    k_prepM<<<p.nblk, 256, 0, stream>>>(p, p);
    DiffSeg dr = dRuSeg(Y);
    k_diffM<0, -1><<<dr.nblk, 256, 0, stream>>>(dr, dr, Sh, Sl);
    G3RuSeg gr = ruSeg(Y, stold);
    k_g3ru<<<gr.nblk, 512, 0, stream>>>(gr, gr);
    DiffSeg dc = dCdSeg(Y);
    k_diffM<2, -1><<<dc.nblk, 256, 0, stream>>>(dc, dc, Sh, Sl);
    G3CdSeg gc = cdSeg(Y, stold, stout, nullptr, nullptr, 0);
    k_g3cd<<<gc.nblk, 256, 0, stream>>>(gc, gc);
  };
  auto cell128 = [&](LayerH& Y, const float* inp, const float* stold, float* stout,
                     const float* ow, const float* ob, int t) {
    PrepSeg p = prepSeg(Y, inp, stold);
    k_prepM<<<p.nblk, 256, 0, stream>>>(p, p);
    DiffSeg dr = dRuSeg(Y);
    k_diffM<1, -1><<<dr.nblk, 256, 0, stream>>>(dr, dr, Sh, Sl);
    G3RuSeg gr = ruSeg(Y, stold);
    k_g3ru<<<gr.nblk, 512, 0, stream>>>(gr, gr);
    DiffSeg dc = dCdSeg(Y);
    k_diffM<3, -1><<<dc.nblk, 256, 0, stream>>>(dc, dc, Sh, Sl);
    G3CdSeg gc = cdSeg(Y, stold, stout, ow, ob, t);
    k_g3cd<<<gc.nblk, 256, 0, stream>>>(gc, gc);
  };

  float* P[2] = {P0, P1};

  // ---- encoder: pipelined l0(t) ∥ l1(t-1) ----
  cell72(L[0], xin, P1, P0);                       // t=0 (stold=P1=zeros)
  for (int t = 1; t < TT; t++) {
    const float* Pold = P[(t - 1) & 1];
    float* Pnew = P[t & 1];
    PrepSeg p0 = prepSeg(L[0], xin + (size_t)t * NB * 2, Pold);
    PrepSeg p1 = prepSeg(L[1], Pold, st1);
    k_prepM<<<p0.nblk + p1.nblk, 256, 0, stream>>>(p0, p1);
    DiffSeg dr0 = dRuSeg(L[0]), dr1 = dRuSeg(L[1]);
    k_diffM<0, 1><<<dr0.nblk + dr1.nblk, 256, 0, stream>>>(dr0, dr1, Sh, Sl);
    G3RuSeg gr0 = ruSeg(L[0], Pold), gr1 = ruSeg(L[1], st1);
    k_g3ru<<<gr0.nblk + gr1.nblk, 512, 0, stream>>>(gr0, gr1);
    DiffSeg dc0 = dCdSeg(L[0]), dc1 = dCdSeg(L[1]);
    k_diffM<2, 3><<<dc0.nblk + dc1.nblk, 256, 0, stream>>>(dc0, dc1, Sh, Sl);
    G3CdSeg gc0 = cdSeg(L[0], Pold, Pnew, nullptr, nullptr, 0);
    G3CdSeg gc1 = cdSeg(L[1], st1, st1, nullptr, nullptr, 0);
    k_g3cd<<<gc0.nblk + gc1.nblk, 256, 0, stream>>>(gc0, gc1);
  }
  cell128(L[1], P[1], st1, st1, nullptr, nullptr, 0);   // l1(t=11), x = P[11&1]=P1

  // ---- decoder: sequential ----
  for (int t = 0; t < TT; t++) {
    cell72(L[2], decin, P1, P1);
    cell128(L[3], P1, st1, st1, outW, outB, t);
  }
}

// Round 9
// 8200.751 us; speedup vs baseline: 3.1348x; 1.0981x over previous
//
#include <hip/hip_runtime.h>
#include <math.h>

// DCRNN on MI355X — round 9: counted-vmcnt pipelines (diffuse NL=6/8, g3ru NL=3,
// g3cd NL=4 with LDS dbuf) + decoder prep fused into g3cd epilogues.
// 3-term bf16 hi/lo split math unchanged (absmax must stay 3.051758e-05).

#define NN 1024
#define BB 16
#define TT 12
#define HH 64
#define NB (NN*BB)      // 16384

typedef unsigned short u16;
typedef unsigned int u32;
typedef __attribute__((ext_vector_type(8))) short sv8;
typedef __attribute__((ext_vector_type(4))) float f32x4;
typedef __attribute__((ext_vector_type(16))) float f32x16;

__device__ __forceinline__ void gload16(const void* g, void* l) {
  __builtin_amdgcn_global_load_lds(
      (const __attribute__((address_space(1))) void*)(unsigned long long)(g),
      (__attribute__((address_space(3))) void*)(l), 16, 0, 0);
}

#define WAIT_BAR(N) asm volatile("s_waitcnt vmcnt(" #N ")\n\ts_barrier" ::: "memory")
#define BAR() asm volatile("s_barrier" ::: "memory")

template<int NX, int NY, int NZ>
__device__ __forceinline__ void xcdmap(int bid, int& x, int& y, int& z) {
  constexpr int ZREP = 8 / NZ;
  constexpr int YH = NY / ZREP;
  int chunk = bid & 7, pos = bid >> 3;
  z = chunk / ZREP;
  int yh = chunk % ZREP;
  x = pos % NX;
  y = yh * YH + pos / NX;
}

__device__ __forceinline__ int swz(int row, int g) {
  int rp = row >> 1;
  int j = ((row & 1) << 2) | g;
  return (rp << 3) | (j ^ (rp & 7));
}

__device__ __forceinline__ u16 bf16_rne(float x) {
  u32 u = __float_as_uint(x);
  return (u16)((u + 0x7FFFu + ((u >> 16) & 1u)) >> 16);
}
__device__ __forceinline__ void split2(float x, u16& h, u16& l) {
  h = bf16_rne(x);
  float hf = __uint_as_float(((u32)h) << 16);
  l = bf16_rne(x - hf);
}

__global__ __launch_bounds__(256) void k_zero(float* p, int n) {
  int i = blockIdx.x * 256 + threadIdx.x;
  if (i < n) p[i] = 0.f;
}

__global__ __launch_bounds__(256) void k_transpose_in(const float* __restrict__ in,
                                                      float* __restrict__ xt) {
  int idx = blockIdx.x * 256 + threadIdx.x;
  if (idx >= BB * TT * NN * 2) return;
  int i = idx & 1;
  int n = (idx >> 1) & (NN - 1);
  int bt = idx >> 11;
  int t = bt % TT, b = bt / TT;
  xt[(size_t)t * (NB * 2) + (size_t)(n * BB + b) * 2 + i] = in[idx];
}

__global__ __launch_bounds__(256) void k_splitS(const float* __restrict__ s,
                                                u16* __restrict__ sh, u16* __restrict__ sl) {
  int idx = blockIdx.x * 256 + threadIdx.x;
  if (idx >= 2 * NN * NN) return;
  u16 h, l; split2(s[idx], h, l);
  sh[idx] = h; sl[idx] = l;
}

__global__ __launch_bounds__(256) void k_transpS(const u16* __restrict__ sh,
        const u16* __restrict__ sl, u16* __restrict__ sth, u16* __restrict__ stl) {
  int idx = blockIdx.x * 256 + threadIdx.x;
  if (idx >= 2 * NN * NN) return;
  int j = idx & (NN - 1);
  int k = (idx >> 10) & (NN - 1);
  int z = idx >> 20;
  size_t src = ((size_t)z << 20) | ((size_t)j << 10) | (size_t)k;
  sth[idx] = sh[src];
  stl[idx] = sl[src];
}

__global__ __launch_bounds__(256) void k_padWt(const float* __restrict__ W,
        u16* __restrict__ Wth, u16* __restrict__ Wtl,
        int indim, int Dp, int KTa, int dout) {
  int idx = blockIdx.x * 256 + threadIdx.x;
  if (idx >= dout * KTa) return;
  int kk = idx % KTa, o = idx / KTa;
  int blk = kk / Dp, d = kk - blk * Dp;
  int Dreal = indim + 64;
  float v = 0.f;
  if (blk < 5) {
    int dorig = -1;
    if (d < 64) dorig = indim + d;
    else if (d - 64 < indim) dorig = d - 64;
    if (dorig >= 0) v = W[(size_t)(blk * Dreal + dorig) * dout + o];
  }
  u16 h, l; split2(v, h, l);
  Wth[idx] = h; Wtl[idx] = l;
}

__global__ __launch_bounds__(256) void k_padWtCand(const float* __restrict__ W,
        u16* __restrict__ Wth, u16* __restrict__ Wtl,
        int indim, int Dp, int KTa, int dout) {
  int idx = blockIdx.x * 256 + threadIdx.x;
  if (idx >= dout * KTa) return;
  int kk = idx % KTa, o = idx / KTa;
  int c = 64 + kk;
  int Dreal = indim + 64;
  float v = 0.f;
  if (c >= KTa) {
    int d = c - KTa;
    v = W[(size_t)(indim + d) * dout + o];
  } else {
    int blk = c / Dp, d = c - blk * Dp;
    if (blk == 0) {
      int di = d - 64;
      if (di < indim) v = W[(size_t)di * dout + o];
    } else {
      if (d < 64) v = W[(size_t)(blk * Dreal + indim + d) * dout + o];
      else if (d - 64 < indim) v = W[(size_t)(blk * Dreal + (d - 64)) * dout + o];
    }
  }
  u16 h, l; split2(v, h, l);
  Wth[idx] = h; Wtl[idx] = l;
}

struct PrepSeg {
  const float *inp, *st;
  u16 *ych, *ycl, *hh, *hl;
  int indim, CW, STR, nblk;
};
__global__ __launch_bounds__(256) void k_prepM(PrepSeg s0, PrepSeg s1) {
  const bool first = (int)blockIdx.x < s0.nblk;
  const PrepSeg s = first ? s0 : s1;
  const int c = first ? blockIdx.x : blockIdx.x - s0.nblk;
  int n0 = threadIdx.x << 2;
  int b = c / s.CW, d = c - b * s.CW;
  u16 h4[4], l4[4];
  #pragma unroll
  for (int r = 0; r < 4; r++) {
    int nb = ((n0 + r) << 4) + b;
    float v = 0.f;
    if (d < 64) v = s.st[(size_t)nb * HH + d];
    else if (d - 64 < s.indim) v = s.inp[(size_t)nb * s.indim + (d - 64)];
    split2(v, h4[r], l4[r]);
    s.hh[(size_t)nb * s.STR + d] = h4[r];
    s.hl[(size_t)nb * s.STR + d] = l4[r];
  }
  uint2 ph, pl;
  ph.x = (u32)h4[0] | ((u32)h4[1] << 16); ph.y = (u32)h4[2] | ((u32)h4[3] << 16);
  pl.x = (u32)l4[0] | ((u32)l4[1] << 16); pl.y = (u32)l4[2] | ((u32)l4[3] << 16);
  *(uint2*)&s.ych[(size_t)c * NN + n0] = ph;
  *(uint2*)&s.ycl[(size_t)c * NN + n0] = pl;
}

struct StageMap {
  int row1, g1, row2, g2;
  __device__ StageMap(int tid) {
    int rp = tid >> 3, jx = (tid & 7) ^ (rp & 7);
    row1 = (rp << 1) | (jx >> 2); g1 = jx & 3;
    int s = tid + 256; rp = s >> 3; jx = (s & 7) ^ (rp & 7);
    row2 = (rp << 1) | (jx >> 2); g2 = jx & 3;
  }
};

// ---------- S^2 (setup, runs once; plain barriers) ----------
__global__ __launch_bounds__(256) void k_sq(
    const u16* __restrict__ Sh, const u16* __restrict__ Sl,
    const u16* __restrict__ STh, const u16* __restrict__ STl,
    u16* __restrict__ Oh, u16* __restrict__ Ol)
{
  __shared__ __attribute__((aligned(16))) u16 lA[2][2][4096];
  __shared__ __attribute__((aligned(16))) u16 lB[2][2][4096];
  const int tid = threadIdx.x;
  const int lane = tid & 63, wave = tid >> 6;
  int bx, by, z;
  xcdmap<8, 8, 2>(blockIdx.x, bx, by, z);
  const int a0 = bx << 7, b0 = by << 7;
  const int wc0 = (wave & 1) << 6, wn0 = (wave >> 1) << 6;
  StageMap sm(tid);
  const u16* pa1h = Sh + (size_t)z * NN * NN + (size_t)(a0 + sm.row1) * NN + sm.g1 * 8;
  const u16* pa2h = Sh + (size_t)z * NN * NN + (size_t)(a0 + sm.row2) * NN + sm.g2 * 8;
  const u16* pa1l = Sl + (size_t)z * NN * NN + (size_t)(a0 + sm.row1) * NN + sm.g1 * 8;
  const u16* pa2l = Sl + (size_t)z * NN * NN + (size_t)(a0 + sm.row2) * NN + sm.g2 * 8;
  const u16* pb1h = STh + (size_t)z * NN * NN + (size_t)(b0 + sm.row1) * NN + sm.g1 * 8;
  const u16* pb2h = STh + (size_t)z * NN * NN + (size_t)(b0 + sm.row2) * NN + sm.g2 * 8;
  const u16* pb1l = STl + (size_t)z * NN * NN + (size_t)(b0 + sm.row1) * NN + sm.g1 * 8;
  const u16* pb2l = STl + (size_t)z * NN * NN + (size_t)(b0 + sm.row2) * NN + sm.g2 * 8;

  f32x16 acc[2][2];
  #pragma unroll
  for (int i = 0; i < 2; i++)
    #pragma unroll
    for (int j = 0; j < 2; j++)
      #pragma unroll
      for (int e = 0; e < 16; e++) acc[i][j][e] = 0.f;

  auto stage = [&](int buf, int k0) {
    gload16(pa1h + k0, &lA[buf][0][tid * 8]);
    gload16(pa2h + k0, &lA[buf][0][tid * 8 + 2048]);
    gload16(pa1l + k0, &lA[buf][1][tid * 8]);
    gload16(pa2l + k0, &lA[buf][1][tid * 8 + 2048]);
    gload16(pb1h + k0, &lB[buf][0][tid * 8]);
    gload16(pb2h + k0, &lB[buf][0][tid * 8 + 2048]);
    gload16(pb1l + k0, &lB[buf][1][tid * 8]);
    gload16(pb2l + k0, &lB[buf][1][tid * 8 + 2048]);
  };
  stage(0, 0);
  __syncthreads();
  int cur = 0;
  for (int kt = 0; kt < 32; kt++) {
    if (kt < 31) stage(cur ^ 1, (kt + 1) * 32);
    #pragma unroll
    for (int kh = 0; kh < 2; kh++) {
      sv8 vah[2], vaL[2], vbh[2], vbL[2];
      int gsel = (kh << 1) | (lane >> 5);
      #pragma unroll
      for (int f = 0; f < 2; f++) {
        int offa = swz(wc0 + f * 32 + (lane & 31), gsel) * 8;
        vah[f] = *(const sv8*)&lA[cur][0][offa];
        vaL[f] = *(const sv8*)&lA[cur][1][offa];
        int offb = swz(wn0 + f * 32 + (lane & 31), gsel) * 8;
        vbh[f] = *(const sv8*)&lB[cur][0][offb];
        vbL[f] = *(const sv8*)&lB[cur][1][offb];
      }
      #pragma unroll
      for (int fm = 0; fm < 2; fm++)
        #pragma unroll
        for (int fn = 0; fn < 2; fn++) {
          acc[fm][fn] = __builtin_amdgcn_mfma_f32_32x32x16_bf16(vah[fm], vbh[fn], acc[fm][fn], 0, 0, 0);
          acc[fm][fn] = __builtin_amdgcn_mfma_f32_32x32x16_bf16(vah[fm], vbL[fn], acc[fm][fn], 0, 0, 0);
          acc[fm][fn] = __builtin_amdgcn_mfma_f32_32x32x16_bf16(vaL[fm], vbh[fn], acc[fm][fn], 0, 0, 0);
        }
    }
    __syncthreads();
    cur ^= 1;
  }
  u16* oh = Oh + (size_t)z * NN * NN;
  u16* ol = Ol + (size_t)z * NN * NN;
  #pragma unroll
  for (int fm = 0; fm < 2; fm++)
    #pragma unroll
    for (int q = 0; q < 4; q++) {
      int m4 = a0 + wc0 + fm * 32 + q * 8 + ((lane >> 5) << 2);
      #pragma unroll
      for (int fn = 0; fn < 2; fn++) {
        int kc = b0 + wn0 + fn * 32 + (lane & 31);
        #pragma unroll
        for (int r = 0; r < 4; r++) {
          u16 hi, lo; split2(acc[fm][fn][q * 4 + r], hi, lo);
          oh[(size_t)(m4 + r) * NN + kc] = hi;
          ol[(size_t)(m4 + r) * NN + kc] = lo;
        }
      }
    }
}

// ---------- diffusion (counted-vmcnt pipeline) ----------
struct DiffSeg { const u16 *Ah, *Al; u16 *hh, *hl; int nblk; };

template<int V>
__device__ __forceinline__ void diffuse_body(int bid, const DiffSeg s,
    const u16* __restrict__ Sh, const u16* __restrict__ Sl,
    u16* sA, u16* sB)
{
  constexpr int BN  = (V == 1) ? 128 : 64;
  constexpr int CW  = (V == 0) ? 72 : ((V == 1) ? 128 : 64);
  constexpr int DP  = (V == 0 || V == 2) ? 72 : 128;
  constexpr int KTA = (V == 0 || V == 2) ? 384 : 640;
  constexpr int STR = KTA + 64;
  constexpr int NX  = (V == 0) ? 9 : ((V == 1) ? 16 : 8);
  constexpr int NY  = (V == 1) ? 8 : 16;
  constexpr int FN  = BN / 64;
  const int tid = threadIdx.x;
  const int lane = tid & 63, wave = tid >> 6;
  int bx, by, z;
  xcdmap<NX, NY, 4>(bid, bx, by, z);
  const int a0 = bx << 7;
  const int b0 = by * BN;
  const int wc0 = (wave & 1) << 6;
  const int wn0 = (wave >> 1) * (BN / 2);
  StageMap sm(tid);
  const u16* pa1h = s.Ah + (size_t)(a0 + sm.row1) * NN + sm.g1 * 8;
  const u16* pa2h = s.Ah + (size_t)(a0 + sm.row2) * NN + sm.g2 * 8;
  const u16* pa1l = s.Al + (size_t)(a0 + sm.row1) * NN + sm.g1 * 8;
  const u16* pa2l = s.Al + (size_t)(a0 + sm.row2) * NN + sm.g2 * 8;
  const u16* pb1h = Sh + (size_t)z * NN * NN + (size_t)(b0 + sm.row1) * NN + sm.g1 * 8;
  const u16* pb2h = Sh + (size_t)z * NN * NN + (size_t)(b0 + sm.row2) * NN + sm.g2 * 8;
  const u16* pb1l = Sl + (size_t)z * NN * NN + (size_t)(b0 + sm.row1) * NN + sm.g1 * 8;
  const u16* pb2l = Sl + (size_t)z * NN * NN + (size_t)(b0 + sm.row2) * NN + sm.g2 * 8;

  f32x16 acc[2][FN];
  #pragma unroll
  for (int i = 0; i < 2; i++)
    #pragma unroll
    for (int j = 0; j < FN; j++)
      #pragma unroll
      for (int e = 0; e < 16; e++) acc[i][j][e] = 0.f;

  auto stage = [&](int buf, int k0) {
    gload16(pa1h + k0, sA + (buf * 2 + 0) * 4096 + tid * 8);
    gload16(pa2h + k0, sA + (buf * 2 + 0) * 4096 + tid * 8 + 2048);
    gload16(pa1l + k0, sA + (buf * 2 + 1) * 4096 + tid * 8);
    gload16(pa2l + k0, sA + (buf * 2 + 1) * 4096 + tid * 8 + 2048);
    gload16(pb1h + k0, sB + (buf * 2 + 0) * (BN * 32) + tid * 8);
    gload16(pb1l + k0, sB + (buf * 2 + 1) * (BN * 32) + tid * 8);
    if (BN == 128) {
      gload16(pb2h + k0, sB + (buf * 2 + 0) * (BN * 32) + tid * 8 + 2048);
      gload16(pb2l + k0, sB + (buf * 2 + 1) * (BN * 32) + tid * 8 + 2048);
    }
  };
  stage(0, 0);
  int cur = 0;
  for (int kt = 0; kt < 32; kt++) {
    if (kt < 31) {
      stage(cur ^ 1, (kt + 1) * 32);
      if constexpr (BN == 128) WAIT_BAR(8); else WAIT_BAR(6);
    } else {
      WAIT_BAR(0);
    }
    #pragma unroll
    for (int kh = 0; kh < 2; kh++) {
      sv8 vah[2], vaL[2], vbh[FN], vbL[FN];
      int gsel = (kh << 1) | (lane >> 5);
      #pragma unroll
      for (int f = 0; f < 2; f++) {
        int offa = swz(wc0 + f * 32 + (lane & 31), gsel) * 8;
        vah[f] = *(const sv8*)(sA + (cur * 2 + 0) * 4096 + offa);
        vaL[f] = *(const sv8*)(sA + (cur * 2 + 1) * 4096 + offa);
      }
      #pragma unroll
      for (int f = 0; f < FN; f++) {
        int offb = swz(wn0 + f * 32 + (lane & 31), gsel) * 8;
        vbh[f] = *(const sv8*)(sB + (cur * 2 + 0) * (BN * 32) + offb);
        vbL[f] = *(const sv8*)(sB + (cur * 2 + 1) * (BN * 32) + offb);
      }
      #pragma unroll
      for (int fm = 0; fm < 2; fm++)
        #pragma unroll
        for (int fn = 0; fn < FN; fn++) {
          acc[fm][fn] = __builtin_amdgcn_mfma_f32_32x32x16_bf16(vah[fm], vbh[fn], acc[fm][fn], 0, 0, 0);
          acc[fm][fn] = __builtin_amdgcn_mfma_f32_32x32x16_bf16(vah[fm], vbL[fn], acc[fm][fn], 0, 0, 0);
          acc[fm][fn] = __builtin_amdgcn_mfma_f32_32x32x16_bf16(vaL[fm], vbh[fn], acc[fm][fn], 0, 0, 0);
        }
    }
    BAR();
    cur ^= 1;
  }
  const int blkoff = (1 + ((z & 1) << 1) + (z >> 1)) * DP;
  #pragma unroll
  for (int fm = 0; fm < 2; fm++)
    #pragma unroll
    for (int q = 0; q < 4; q++) {
      int cg4 = a0 + wc0 + fm * 32 + q * 8 + ((lane >> 5) << 2);
      int bq = cg4 / CW, dq = cg4 - bq * CW;
      #pragma unroll
      for (int fn = 0; fn < FN; fn++) {
        int mg = b0 + wn0 + fn * 32 + (lane & 31);
        u16 hi4[4], lo4[4];
        #pragma unroll
        for (int r = 0; r < 4; r++)
          split2(acc[fm][fn][q * 4 + r], hi4[r], lo4[r]);
        size_t hidx = (size_t)((mg << 4) + bq) * STR + blkoff + dq;
        uint2 ph, pl;
        ph.x = (u32)hi4[0] | ((u32)hi4[1] << 16); ph.y = (u32)hi4[2] | ((u32)hi4[3] << 16);
        pl.x = (u32)lo4[0] | ((u32)lo4[1] << 16); pl.y = (u32)lo4[2] | ((u32)lo4[3] << 16);
        *(uint2*)&s.hh[hidx] = ph;
        *(uint2*)&s.hl[hidx] = pl;
      }
    }
}

template<int VA, int VB>
__global__ __launch_bounds__(256) void k_diffM(DiffSeg s0, DiffSeg s1,
    const u16* __restrict__ Sh, const u16* __restrict__ Sl) {
  constexpr int BNA = (VA == 1) ? 128 : 64;
  constexpr int BNB = (VB == 1) ? 128 : 64;
  constexpr int MB = BNA > BNB ? BNA : BNB;
  __shared__ __attribute__((aligned(16))) u16 sA[4 * 4096];
  __shared__ __attribute__((aligned(16))) u16 sB[4 * MB * 32];
  if ((int)blockIdx.x < s0.nblk) {
    diffuse_body<VA>(blockIdx.x, s0, Sh, Sl, sA, sB);
  } else {
    if constexpr (VB >= 0)
      diffuse_body<VB>(blockIdx.x - s0.nblk, s1, Sh, Sl, sA, sB);
  }
}

// ---------- gemm-ru (dbuf, counted vmcnt NL=3) + fused cand-prep ----------
struct G3RuSeg {
  const u16 *Ah, *Al, *Bh, *Bl;
  const float *bias, *stold;
  float *ru;
  u16 *ych, *ycl, *hh, *hl;
  int KTa, STR, nblk;
};
__global__ __launch_bounds__(512) void k_g3ru(G3RuSeg s0, G3RuSeg s1) {
  __shared__ __attribute__((aligned(16))) u16 lAh[2][2048];
  __shared__ __attribute__((aligned(16))) u16 lAl[2][2048];
  __shared__ __attribute__((aligned(16))) u16 lBh[2][4096];
  __shared__ __attribute__((aligned(16))) u16 lBl[2][4096];
  const bool first = (int)blockIdx.x < s0.nblk;
  const G3RuSeg s = first ? s0 : s1;
  const int bid = first ? blockIdx.x : blockIdx.x - s0.nblk;
  const int tid = threadIdx.x;
  const int lane = tid & 63, wave = tid >> 6;
  const int a0 = bid << 6;
  const int wr0 = (wave & 1) << 5;
  const int wn0 = (wave >> 1) << 5;
  const int gw = lane >> 4, rsel = lane & 15;
  const int sAi = tid & 255;
  int rp = sAi >> 3, jx = (sAi & 7) ^ (rp & 7);
  const int rowA = (rp << 1) | (jx >> 2), gAc = jx & 3;
  rp = tid >> 3; jx = (tid & 7) ^ (rp & 7);
  const int rowB = (rp << 1) | (jx >> 2), gBc = jx & 3;

  f32x4 acc[2][2];
  #pragma unroll
  for (int i = 0; i < 2; i++)
    #pragma unroll
    for (int j = 0; j < 2; j++) acc[i][j] = (f32x4){0.f, 0.f, 0.f, 0.f};

  auto stg = [&](int buf, int k0) {
    if (tid < 256) gload16(s.Ah + (size_t)(a0 + rowA) * s.STR + k0 + gAc * 8, &lAh[buf][sAi * 8]);
    else           gload16(s.Al + (size_t)(a0 + rowA) * s.STR + k0 + gAc * 8, &lAl[buf][sAi * 8]);
    gload16(s.Bh + (size_t)rowB * s.KTa + k0 + gBc * 8, &lBh[buf][tid * 8]);
    gload16(s.Bl + (size_t)rowB * s.KTa + k0 + gBc * 8, &lBl[buf][tid * 8]);
  };
  const int NI = s.KTa >> 5;
  stg(0, 0);
  int cur = 0;
  for (int i = 0; i < NI; i++) {
    if (i < NI - 1) {
      stg(cur ^ 1, (i + 1) * 32);
      WAIT_BAR(3);
    } else {
      WAIT_BAR(0);
    }
    sv8 vah[2], vaL[2], vbh[2], vbL[2];
    #pragma unroll
    for (int f = 0; f < 2; f++) {
      int offa = swz(wr0 + f * 16 + rsel, gw) * 8;
      vah[f] = *(const sv8*)&lAh[cur][offa];
      vaL[f] = *(const sv8*)&lAl[cur][offa];
      int offb = swz(wn0 + f * 16 + rsel, gw) * 8;
      vbh[f] = *(const sv8*)&lBh[cur][offb];
      vbL[f] = *(const sv8*)&lBl[cur][offb];
    }
    #pragma unroll
    for (int fm = 0; fm < 2; fm++)
      #pragma unroll
      for (int fn = 0; fn < 2; fn++) {
        acc[fm][fn] = __builtin_amdgcn_mfma_f32_16x16x32_bf16(vah[fm], vbh[fn], acc[fm][fn], 0, 0, 0);
        acc[fm][fn] = __builtin_amdgcn_mfma_f32_16x16x32_bf16(vah[fm], vbL[fn], acc[fm][fn], 0, 0, 0);
        acc[fm][fn] = __builtin_amdgcn_mfma_f32_16x16x32_bf16(vaL[fm], vbh[fn], acc[fm][fn], 0, 0, 0);
      }
    BAR();
    cur ^= 1;
  }

  #pragma unroll
  for (int fm = 0; fm < 2; fm++) {
    #pragma unroll
    for (int r = 0; r < 4; r++) {
      int nb = a0 + wr0 + fm * 16 + ((lane >> 4) << 2) + r;
      #pragma unroll
      for (int fn = 0; fn < 2; fn++) {
        int o = wn0 + fn * 16 + rsel;
        float v = acc[fm][fn][r] + s.bias[o];
        float sig = 1.f / (1.f + expf(-v));
        s.ru[(size_t)nb * 128 + o] = sig;
        if (o < 64) {
          float rv = sig * s.stold[(size_t)nb * HH + o];
          u16 hi, lo; split2(rv, hi, lo);
          int cc = ((nb & 15) << 6) + o;
          s.ych[(size_t)cc * NN + (nb >> 4)] = hi;
          s.ycl[(size_t)cc * NN + (nb >> 4)] = lo;
          s.hh[(size_t)nb * s.STR + s.KTa + o] = hi;
          s.hl[(size_t)nb * s.STR + s.KTa + o] = lo;
        }
      }
    }
  }
}

// ---------- gemm-cand (dbuf, NL=4) + fused next-cell prep + projection ----------
struct G3CdSeg {
  const u16 *Ah, *Al, *Bh, *Bl;
  const float *bias, *ru, *stold;
  float *stout;
  // epilogue target A (write ns as next-cell state cols)
  u16 *yAh, *yAl, *hAh, *hAl; int cwA, baseA, strA;
  // epilogue target B (write ns as other-layer inp cols)
  u16 *yBh, *yBl, *hBh, *hBl; int cwB, baseB, strB;
  // projection + decoder-input col
  const float *ow, *ob;
  float *outg, *decin;
  u16 *yPh, *yPl, *hPh, *hPl; int cwP, baseP, strP;
  int t, KTa, STR, nblk;
};
__global__ __launch_bounds__(256) void k_g3cd(G3CdSeg s0, G3CdSeg s1) {
  __shared__ __attribute__((aligned(16))) u16 lAh[2][2048];
  __shared__ __attribute__((aligned(16))) u16 lAl[2][2048];
  __shared__ __attribute__((aligned(16))) u16 lBh[2][2048];
  __shared__ __attribute__((aligned(16))) u16 lBl[2][2048];
  __shared__ float pst[64][65];
  const bool first = (int)blockIdx.x < s0.nblk;
  const G3CdSeg s = first ? s0 : s1;
  const int bid = first ? blockIdx.x : blockIdx.x - s0.nblk;
  const int tid = threadIdx.x;
  const int lane = tid & 63, wave = tid >> 6;
  const int a0 = bid << 6;
  const int wr0 = (wave & 1) << 5;
  const int wn0 = (wave >> 1) << 5;
  const int gw = lane >> 4, rsel = lane & 15;
  int rp = tid >> 3, jx = (tid & 7) ^ (rp & 7);
  const int rowA = (rp << 1) | (jx >> 2), gAc = jx & 3;

  f32x4 acc[2][2];
  #pragma unroll
  for (int i = 0; i < 2; i++)
    #pragma unroll
    for (int j = 0; j < 2; j++) acc[i][j] = (f32x4){0.f, 0.f, 0.f, 0.f};

  auto stg = [&](int buf, int k0) {
    gload16(s.Ah + (size_t)(a0 + rowA) * s.STR + 64 + k0 + gAc * 8, &lAh[buf][tid * 8]);
    gload16(s.Al + (size_t)(a0 + rowA) * s.STR + 64 + k0 + gAc * 8, &lAl[buf][tid * 8]);
    gload16(s.Bh + (size_t)rowA * s.KTa + k0 + gAc * 8, &lBh[buf][tid * 8]);
    gload16(s.Bl + (size_t)rowA * s.KTa + k0 + gAc * 8, &lBl[buf][tid * 8]);
  };
  const int NI = s.KTa >> 5;
  stg(0, 0);
  int cur = 0;
  for (int i = 0; i < NI; i++) {
    if (i < NI - 1) {
      stg(cur ^ 1, (i + 1) * 32);
      WAIT_BAR(4);
    } else {
      WAIT_BAR(0);
    }
    sv8 vah[2], vaL[2], vbh[2], vbL[2];
    #pragma unroll
    for (int f = 0; f < 2; f++) {
      int offa = swz(wr0 + f * 16 + rsel, gw) * 8;
      vah[f] = *(const sv8*)&lAh[cur][offa];
      vaL[f] = *(const sv8*)&lAl[cur][offa];
      int offb = swz(wn0 + f * 16 + rsel, gw) * 8;
      vbh[f] = *(const sv8*)&lBh[cur][offb];
      vbL[f] = *(const sv8*)&lBl[cur][offb];
    }
    #pragma unroll
    for (int fm = 0; fm < 2; fm++)
      #pragma unroll
      for (int fn = 0; fn < 2; fn++) {
        acc[fm][fn] = __builtin_amdgcn_mfma_f32_16x16x32_bf16(vah[fm], vbh[fn], acc[fm][fn], 0, 0, 0);
        acc[fm][fn] = __builtin_amdgcn_mfma_f32_16x16x32_bf16(vah[fm], vbL[fn], acc[fm][fn], 0, 0, 0);
        acc[fm][fn] = __builtin_amdgcn_mfma_f32_16x16x32_bf16(vaL[fm], vbh[fn], acc[fm][fn], 0, 0, 0);
      }
    BAR();
    cur ^= 1;
  }

  #pragma unroll
  for (int fm = 0; fm < 2; fm++) {
    #pragma unroll
    for (int r = 0; r < 4; r++) {
      int nb = a0 + wr0 + fm * 16 + ((lane >> 4) << 2) + r;
      #pragma unroll
      for (int fn = 0; fn < 2; fn++) {
        int o = wn0 + fn * 16 + rsel;
        float v = acc[fm][fn][r] + s.bias[o];
        float u = s.ru[(size_t)nb * 128 + 64 + o];
        float sold = s.stold[(size_t)nb * HH + o];
        float ns = u * sold + (1.f - u) * tanhf(v);
        s.stout[(size_t)nb * HH + o] = ns;
        int b = nb & 15, n = nb >> 4;
        if (s.yAh) {
          u16 hi, lo; split2(ns, hi, lo);
          int c = b * s.cwA + s.baseA + o;
          s.yAh[(size_t)c * NN + n] = hi;
          s.yAl[(size_t)c * NN + n] = lo;
          s.hAh[(size_t)nb * s.strA + s.baseA + o] = hi;
          s.hAl[(size_t)nb * s.strA + s.baseA + o] = lo;
        }
        if (s.yBh) {
          u16 hi, lo; split2(ns, hi, lo);
          int c = b * s.cwB + s.baseB + o;
          s.yBh[(size_t)c * NN + n] = hi;
          s.yBl[(size_t)c * NN + n] = lo;
          s.hBh[(size_t)nb * s.strB + s.baseB + o] = hi;
          s.hBl[(size_t)nb * s.strB + s.baseB + o] = lo;
        }
        if (s.ow) pst[nb - a0][o] = ns;
      }
    }
  }
  if (s.ow) {
    __syncthreads();
    if (tid < 64) {
      int nb = a0 + tid;
      float a2 = s.ob[0];
      #pragma unroll
      for (int o = 0; o < HH; o++) a2 += pst[tid][o] * s.ow[o];
      int n = nb >> 4, b = nb & 15;
      s.outg[((size_t)b * TT + s.t) * NN + n] = a2;
      s.decin[nb] = a2;
      if (s.yPh) {
        u16 hi, lo; split2(a2, hi, lo);
        int c = b * s.cwP + s.baseP;
        s.yPh[(size_t)c * NN + n] = hi;
        s.yPl[(size_t)c * NN + n] = lo;
        s.hPh[(size_t)nb * s.strP + s.baseP] = hi;
        s.hPl[(size_t)nb * s.strP + s.baseP] = lo;
      }
    }
  }
}

// ---------------- host ----------------
struct LayerH {
  u16 *YcRh, *YcRl, *YcCh, *YcCl, *hh, *hl;
  float *ru;
  u16 *Wrh, *Wrl, *Wch, *Wcl;
  const float *br, *bc;
  int indim, CW, KTa, STR, nfull;
};

extern "C" void kernel_launch(void* const* d_in, const int* in_sizes, int n_in,
                              void* d_out, int out_size, void* d_ws, size_t ws_size,
                              hipStream_t stream) {
  const float* inputs   = (const float*)d_in[0];
  const float* supports = (const float*)d_in[1];
  const float* Wsrc[8] = {(const float*)d_in[2], (const float*)d_in[4],
                          (const float*)d_in[6], (const float*)d_in[8],
                          (const float*)d_in[10], (const float*)d_in[12],
                          (const float*)d_in[14], (const float*)d_in[16]};
  const float* bias[8] = {(const float*)d_in[3], (const float*)d_in[5],
                          (const float*)d_in[7], (const float*)d_in[9],
                          (const float*)d_in[11], (const float*)d_in[13],
                          (const float*)d_in[15], (const float*)d_in[17]};
  const float* outW = (const float*)d_in[18];
  const float* outB = (const float*)d_in[19];
  float* out = (float*)d_out;

  char* cur = (char*)d_ws;
  auto alloc = [&](size_t bytes) -> char* {
    char* p = cur; cur += (bytes + 255) & ~(size_t)255; return p;
  };
  u16* Sh    = (u16*)alloc((size_t)4 * NN * NN * 2);
  u16* Sl    = (u16*)alloc((size_t)4 * NN * NN * 2);
  u16* YcR0h = (u16*)alloc((size_t)1152 * NN * 2);
  u16* YcR0l = (u16*)alloc((size_t)1152 * NN * 2);
  u16* YcR1h = (u16*)alloc((size_t)2048 * NN * 2);
  u16* YcR1l = (u16*)alloc((size_t)2048 * NN * 2);
  u16* h0h   = (u16*)alloc((size_t)NB * 448 * 2);
  u16* h0l   = (u16*)alloc((size_t)NB * 448 * 2);
  u16* h1h   = (u16*)alloc((size_t)NB * 704 * 2);
  u16* h1l   = (u16*)alloc((size_t)NB * 704 * 2);
  float* ru0 = (float*)alloc((size_t)NB * 128 * 4);
  float* ru1 = (float*)alloc((size_t)NB * 128 * 4);
  float* P0  = (float*)alloc((size_t)NB * HH * 4);
  float* P1  = (float*)alloc((size_t)NB * HH * 4);
  float* st1 = (float*)alloc((size_t)NB * HH * 4);
  float* decin = (float*)alloc((size_t)NB * 4);
  float* xin = (float*)alloc((size_t)TT * NB * 2 * 4);
  u16* STh = h1h;
  u16* STl = h1l;
  u16* YcC0h = YcR0h; u16* YcC0l = YcR0l;
  u16* YcC1h = YcR1h; u16* YcC1l = YcR1l;

  const int wKTa[4]  = {384, 640, 384, 640};
  const int wIndim[4]= {2, 64, 1, 64};
  const int wDp[4]   = {72, 128, 72, 128};
  u16 *Wrh[4], *Wrl[4], *Wch[4], *Wcl[4];
  for (int i = 0; i < 4; i++) {
    Wrh[i] = (u16*)alloc((size_t)128 * wKTa[i] * 2);
    Wrl[i] = (u16*)alloc((size_t)128 * wKTa[i] * 2);
    Wch[i] = (u16*)alloc((size_t)64 * wKTa[i] * 2);
    Wcl[i] = (u16*)alloc((size_t)64 * wKTa[i] * 2);
  }

  auto blocks = [](int n) { return (n + 255) / 256; };
  k_zero<<<blocks(NB * HH), 256, 0, stream>>>(P1, NB * HH);
  k_zero<<<blocks(NB * HH), 256, 0, stream>>>(st1, NB * HH);
  k_zero<<<blocks(NB), 256, 0, stream>>>(decin, NB);
  k_transpose_in<<<blocks(BB * TT * NN * 2), 256, 0, stream>>>(inputs, xin);
  k_splitS<<<blocks(2 * NN * NN), 256, 0, stream>>>(supports, Sh, Sl);
  k_transpS<<<blocks(2 * NN * NN), 256, 0, stream>>>(Sh, Sl, STh, STl);
  k_sq<<<128, 256, 0, stream>>>(Sh, Sl, STh, STl,
                                Sh + (size_t)2 * NN * NN,
                                Sl + (size_t)2 * NN * NN);
  for (int i = 0; i < 4; i++) {
    k_padWt<<<blocks(128 * wKTa[i]), 256, 0, stream>>>(
        Wsrc[2 * i], Wrh[i], Wrl[i], wIndim[i], wDp[i], wKTa[i], 128);
    k_padWtCand<<<blocks(64 * wKTa[i]), 256, 0, stream>>>(
        Wsrc[2 * i + 1], Wch[i], Wcl[i], wIndim[i], wDp[i], wKTa[i], 64);
  }

  LayerH L[4];
  for (int i = 0; i < 4; i++) {
    bool lo = (wDp[i] == 72);
    L[i].YcRh = lo ? YcR0h : YcR1h; L[i].YcRl = lo ? YcR0l : YcR1l;
    L[i].YcCh = lo ? YcC0h : YcC1h; L[i].YcCl = lo ? YcC0l : YcC1l;
    L[i].hh = lo ? h0h : h1h; L[i].hl = lo ? h0l : h1l;
    L[i].ru = lo ? ru0 : ru1;
    L[i].Wrh = Wrh[i]; L[i].Wrl = Wrl[i]; L[i].Wch = Wch[i]; L[i].Wcl = Wcl[i];
    L[i].br = bias[2 * i]; L[i].bc = bias[2 * i + 1];
    L[i].indim = wIndim[i];
    L[i].CW = wDp[i]; L[i].KTa = wKTa[i]; L[i].STR = wKTa[i] + 64;
    L[i].nfull = lo ? 576 : 512;
  }

  auto prepSeg = [&](LayerH& Y, const float* inp, const float* st) {
    return PrepSeg{inp, st, Y.YcRh, Y.YcRl, Y.hh, Y.hl, Y.indim, Y.CW, Y.STR, BB * Y.CW};
  };
  auto dRuSeg = [&](LayerH& Y) {
    return DiffSeg{Y.YcRh, Y.YcRl, Y.hh, Y.hl, Y.nfull};
  };
  auto dCdSeg = [&](LayerH& Y) {
    return DiffSeg{Y.YcCh, Y.YcCl, Y.hh, Y.hl, 512};
  };
  auto ruSeg = [&](LayerH& Y, const float* stold) {
    return G3RuSeg{Y.hh, Y.hl, Y.Wrh, Y.Wrl, Y.br, stold, Y.ru,
                   Y.YcCh, Y.YcCl, Y.hh, Y.hl, Y.KTa, Y.STR, NB / 64};
  };
  auto cdSeg = [&](LayerH& Y, const float* stold, float* stout,
                   const float* ow, const float* ob, int t) {
    G3CdSeg g{};
    g.Ah = Y.hh; g.Al = Y.hl; g.Bh = Y.Wch; g.Bl = Y.Wcl;
    g.bias = Y.bc; g.ru = Y.ru; g.stold = stold; g.stout = stout;
    g.ow = ow; g.ob = ob; g.outg = out; g.decin = decin;
    g.t = t; g.KTa = Y.KTa; g.STR = Y.STR; g.nblk = NB / 64;
    return g;
  };

  auto cell72 = [&](LayerH& Y, const float* inp, const float* stold, float* stout) {
    PrepSeg p = prepSeg(Y, inp, stold);
    k_prepM<<<p.nblk, 256, 0, stream>>>(p, p);
    DiffSeg dr = dRuSeg(Y);
    k_diffM<0, -1><<<dr.nblk, 256, 0, stream>>>(dr, dr, Sh, Sl);
    G3RuSeg gr = ruSeg(Y, stold);
    k_g3ru<<<gr.nblk, 512, 0, stream>>>(gr, gr);
    DiffSeg dc = dCdSeg(Y);
    k_diffM<2, -1><<<dc.nblk, 256, 0, stream>>>(dc, dc, Sh, Sl);
    G3CdSeg gc = cdSeg(Y, stold, stout, nullptr, nullptr, 0);
    k_g3cd<<<gc.nblk, 256, 0, stream>>>(gc, gc);
  };
  auto cell128 = [&](LayerH& Y, const float* inp, const float* stold, float* stout) {
    PrepSeg p = prepSeg(Y, inp, stold);
    k_prepM<<<p.nblk, 256, 0, stream>>>(p, p);
    DiffSeg dr = dRuSeg(Y);
    k_diffM<1, -1><<<dr.nblk, 256, 0, stream>>>(dr, dr, Sh, Sl);
    G3RuSeg gr = ruSeg(Y, stold);
    k_g3ru<<<gr.nblk, 512, 0, stream>>>(gr, gr);
    DiffSeg dc = dCdSeg(Y);
    k_diffM<3, -1><<<dc.nblk, 256, 0, stream>>>(dc, dc, Sh, Sl);
    G3CdSeg gc = cdSeg(Y, stold, stout, nullptr, nullptr, 0);
    k_g3cd<<<gc.nblk, 256, 0, stream>>>(gc, gc);
  };

  float* P[2] = {P0, P1};

  // ---- encoder: pipelined l0(t) ∥ l1(t-1) ----
  cell72(L[0], xin, P1, P0);
  for (int t = 1; t < TT; t++) {
    const float* Pold = P[(t - 1) & 1];
    float* Pnew = P[t & 1];
    PrepSeg p0 = prepSeg(L[0], xin + (size_t)t * NB * 2, Pold);
    PrepSeg p1 = prepSeg(L[1], Pold, st1);
    k_prepM<<<p0.nblk + p1.nblk, 256, 0, stream>>>(p0, p1);
    DiffSeg dr0 = dRuSeg(L[0]), dr1 = dRuSeg(L[1]);
    k_diffM<0, 1><<<dr0.nblk + dr1.nblk, 256, 0, stream>>>(dr0, dr1, Sh, Sl);
    G3RuSeg gr0 = ruSeg(L[0], Pold), gr1 = ruSeg(L[1], st1);
    k_g3ru<<<gr0.nblk + gr1.nblk, 512, 0, stream>>>(gr0, gr1);
    DiffSeg dc0 = dCdSeg(L[0]), dc1 = dCdSeg(L[1]);
    k_diffM<2, 3><<<dc0.nblk + dc1.nblk, 256, 0, stream>>>(dc0, dc1, Sh, Sl);
    G3CdSeg gc0 = cdSeg(L[0], Pold, Pnew, nullptr, nullptr, 0);
    G3CdSeg gc1 = cdSeg(L[1], st1, st1, nullptr, nullptr, 0);
    k_g3cd<<<gc0.nblk + gc1.nblk, 256, 0, stream>>>(gc0, gc1);
  }
  cell128(L[1], P[1], st1, st1);

  // ---- decoder: sequential, prep fused into g3cd epilogues ----
  {
    PrepSeg pd0 = prepSeg(L[2], decin, P1);
    PrepSeg pd1 = prepSeg(L[3], P1, st1);   // inp cols stale; overwritten by gcd0(t=0)
    k_prepM<<<pd0.nblk + pd1.nblk, 256, 0, stream>>>(pd0, pd1);
  }
  for (int t = 0; t < TT; t++) {
    // l0
    DiffSeg dr0 = dRuSeg(L[2]);
    k_diffM<0, -1><<<dr0.nblk, 256, 0, stream>>>(dr0, dr0, Sh, Sl);
    G3RuSeg gr0 = ruSeg(L[2], P1);
    k_g3ru<<<gr0.nblk, 512, 0, stream>>>(gr0, gr0);
    DiffSeg dc0 = dCdSeg(L[2]);
    k_diffM<2, -1><<<dc0.nblk, 256, 0, stream>>>(dc0, dc0, Sh, Sl);
    G3CdSeg g0 = cdSeg(L[2], P1, P1, nullptr, nullptr, 0);
    g0.yAh = L[2].YcRh; g0.yAl = L[2].YcRl; g0.hAh = L[2].hh; g0.hAl = L[2].hl;
    g0.cwA = 72; g0.baseA = 0; g0.strA = 448;
    g0.yBh = L[3].YcRh; g0.yBl = L[3].YcRl; g0.hBh = L[3].hh; g0.hBl = L[3].hl;
    g0.cwB = 128; g0.baseB = 64; g0.strB = 704;
    k_g3cd<<<g0.nblk, 256, 0, stream>>>(g0, g0);
    // l1
    DiffSeg dr1 = dRuSeg(L[3]);
    k_diffM<1, -1><<<dr1.nblk, 256, 0, stream>>>(dr1, dr1, Sh, Sl);
    G3RuSeg gr1 = ruSeg(L[3], st1);
    k_g3ru<<<gr1.nblk, 512, 0, stream>>>(gr1, gr1);
    DiffSeg dc1 = dCdSeg(L[3]);
    k_diffM<3, -1><<<dc1.nblk, 256, 0, stream>>>(dc1, dc1, Sh, Sl);
    G3CdSeg g1 = cdSeg(L[3], st1, st1, outW, outB, t);
    g1.yAh = L[3].YcRh; g1.yAl = L[3].YcRl; g1.hAh = L[3].hh; g1.hAl = L[3].hl;
    g1.cwA = 128; g1.baseA = 0; g1.strA = 704;
    g1.yPh = L[2].YcRh; g1.yPl = L[2].YcRl; g1.hPh = L[2].hh; g1.hPl = L[2].hl;
    g1.cwP = 72; g1.baseP = 64; g1.strP = 448;
    k_g3cd<<<g1.nblk, 256, 0, stream>>>(g1, g1);
  }
}